// Round 6
// baseline (1428.797 us; speedup 1.0000x reference)
//
#include <hip/hip_runtime.h>
#include <math.h>

#define NN 50000
#define NE 120000
#define FN 64
#define NEA 16
#define NR 4
#define NH 4
#define HID 128
#define NL 3
#define IDE 32
#define RED 8
#define NG 64
#define NC 10
#define KH 128
#define FFH 256
#define NBIN (NR * NN)
#define SCAN_BLK ((NBIN + 1023) / 1024)
// per-rel compacted-row capacities (actual ~22.6K src / ~6.1K hot per rel)
#define CAPS 32768
#define CAPH 9216

typedef short bf16x8 __attribute__((ext_vector_type(8)));
typedef float f32x4 __attribute__((ext_vector_type(4)));

__device__ __forceinline__ unsigned short f2b(float f) {
  unsigned u = __float_as_uint(f);
  unsigned r = (u + 0x7FFFu + ((u >> 16) & 1u)) >> 16;
  return (unsigned short)r;
}
__device__ __forceinline__ float b2f(unsigned short b) {
  return __uint_as_float((unsigned)b << 16);
}

__global__ void cvt_bf16(const float* __restrict__ s, unsigned short* __restrict__ d, int n4) {
  int i = blockIdx.x * blockDim.x + threadIdx.x;
  if (i >= n4) return;
  float4 v = ((const float4*)s)[i];
  ushort4 o;
  o.x = f2b(v.x); o.y = f2b(v.y); o.z = f2b(v.z); o.w = f2b(v.w);
  ((ushort4*)d)[i] = o;
}

// ---- GEMM core: 64x128 tile, NO-LDS streaming main loop (round-3/4 design).
template <int KT>
__device__ __forceinline__ void gemm_direct(
    const unsigned short* __restrict__ A, const int* __restrict__ rowlist,
    const unsigned short* __restrict__ W, const float* __restrict__ bias,
    float* __restrict__ Cf, unsigned short* __restrict__ Cb,
    int nrows, int mout, int act, int rowBase, int colBase) {
  constexpr int NK = KT / 32;
  __shared__ unsigned short Es[64][136];
  int t = threadIdx.x;
  int lane = t & 63, w = t >> 6;
  int wm = w >> 1, wn = w & 1;
  int q = lane >> 4, mr = lane & 15;

  const unsigned short* ap[2];
#pragma unroll
  for (int mt = 0; mt < 2; ++mt) {
    int gr = rowBase + wm * 32 + mt * 16 + mr;
    int cg = (gr < nrows) ? gr : 0;
    int ar = rowlist ? rowlist[cg] : cg;
    ap[mt] = A + (size_t)ar * KT + q * 8;
  }
  const unsigned short* wp[4];
#pragma unroll
  for (int nt = 0; nt < 4; ++nt)
    wp[nt] = W + (size_t)(colBase + wn * 64 + nt * 16 + mr) * KT + q * 8;

  f32x4 acc[2][4] = {};
#pragma unroll
  for (int k = 0; k < NK; ++k) {
    bf16x8 af[2], bfr[4];
#pragma unroll
    for (int mt = 0; mt < 2; ++mt) af[mt] = *(const bf16x8*)(ap[mt] + k * 32);
#pragma unroll
    for (int nt = 0; nt < 4; ++nt) bfr[nt] = *(const bf16x8*)(wp[nt] + k * 32);
#pragma unroll
    for (int mt = 0; mt < 2; ++mt)
#pragma unroll
      for (int nt = 0; nt < 4; ++nt)
        acc[mt][nt] = __builtin_amdgcn_mfma_f32_16x16x32_bf16(af[mt], bfr[nt], acc[mt][nt], 0, 0, 0);
  }

  float bv[4];
#pragma unroll
  for (int nt = 0; nt < 4; ++nt) bv[nt] = bias[colBase + wn * 64 + nt * 16 + mr];

  if (Cf) {
#pragma unroll
    for (int mt = 0; mt < 2; ++mt)
#pragma unroll
      for (int nt = 0; nt < 4; ++nt)
#pragma unroll
        for (int r = 0; r < 4; ++r) {
          int row = rowBase + wm * 32 + mt * 16 + q * 4 + r;
          int col = colBase + wn * 64 + nt * 16 + mr;
          if (row < nrows) {
            float v = acc[mt][nt][r] + bv[nt];
            if (act) v = v / (1.f + expf(-v));
            Cf[(size_t)row * mout + col] = v;
            if (Cb) Cb[(size_t)row * mout + col] = f2b(v);
          }
        }
  } else {
#pragma unroll
    for (int mt = 0; mt < 2; ++mt)
#pragma unroll
      for (int nt = 0; nt < 4; ++nt)
#pragma unroll
        for (int r = 0; r < 4; ++r) {
          float v = acc[mt][nt][r] + bv[nt];
          if (act) v = v / (1.f + expf(-v));
          Es[wm * 32 + mt * 16 + q * 4 + r][wn * 64 + nt * 16 + mr] = f2b(v);
        }
    __syncthreads();
    int rl = t >> 2, co = (t & 3) * 32;
    int grow = rowBase + rl;
    if (grow < nrows) {
      unsigned short* dst = Cb + (size_t)grow * mout + colBase + co;
#pragma unroll
      for (int j = 0; j < 4; ++j)
        *(bf16x8*)(dst + j * 8) = *(const bf16x8*)&Es[rl][co + j * 8];
    }
  }
}

// XCD-aware full GEMM (dispatch is round-robin over 8 XCDs: bid&7 = XCD)
template <int KT>
__global__ __launch_bounds__(256, 2) void gemm_bf16_t(
    const unsigned short* __restrict__ A, const unsigned short* __restrict__ W,
    const float* __restrict__ bias, float* __restrict__ Cf, unsigned short* __restrict__ Cb,
    int nrows, int mout, int act, int ncol) {
  int nbr = (nrows + 63) >> 6;
  int rpx = (nbr + 7) >> 3;
  int xcd = blockIdx.x & 7, j = blockIdx.x >> 3;
  int rowT = xcd * rpx + j / ncol;
  int cy = j - (j / ncol) * ncol;
  if (rowT >= nbr) return;
  gemm_direct<KT>(A, nullptr, W, bias, Cf, Cb, nrows, mout, act, rowT * 64, cy * 128);
}

// ---- merged conv GEMM: xl for all 4 rels' srclists + xr for all 4 rels' hotlists,
// one launch. Grid-stride over a device-decoded tile table (8 segments).
// Replaces 4x gemm_rows2 dispatches/layer -> 1 (removes 3 boundary drains + ramps).
__global__ __launch_bounds__(256, 2) void conv_xl_all(
    const unsigned short* __restrict__ hbf,
    const int* __restrict__ srclist, const int* __restrict__ hotlist,
    const int* __restrict__ cnts,  // nsrc @ [128 + r*16], nhot @ [64 + r*16]
    const unsigned short* __restrict__ Wl, const float* __restrict__ bl,
    const unsigned short* __restrict__ Wr, const float* __restrict__ br,
    unsigned short* __restrict__ xlb, unsigned short* __restrict__ xrh) {
  for (int tid = blockIdx.x;; tid += gridDim.x) {
    int rem = tid, seg = 0, nrows = 0;
    for (; seg < 8; ++seg) {
      int r = seg >> 1;
      int n = (seg & 1) ? cnts[64 + r * 16] : cnts[128 + r * 16];
      int cap = (seg & 1) ? CAPH : CAPS;
      if (n > cap) n = cap;
      int tseg = ((n + 63) >> 6) * 4;
      if (rem < tseg) { nrows = n; break; }
      rem -= tseg;
    }
    if (seg == 8) return;
    int r = seg >> 1, sel = seg & 1;
    int rt = rem >> 2, ct = rem & 3;
    const int* list = (sel ? hotlist : srclist) + r * NN;
    const unsigned short* W = (sel ? Wr : Wl) + (size_t)r * 512 * 128;
    const float* bias = (sel ? br : bl) + (size_t)r * 512;
    unsigned short* C = sel ? (xrh + (size_t)r * CAPH * 512) : (xlb + (size_t)r * CAPS * 512);
    gemm_direct<128>(hbf, list, W, bias, nullptr, C, nrows, 512, 0, rt * 64, ct * 128);
    __syncthreads();  // LDS WAR between tiles
  }
}

// ---- fused FFN: f1=silu(h@W1^T+b1) -> LDS; f2=f1@W2^T+b2; h=LN(h+f2); emits hbf.
__global__ __launch_bounds__(256, 2) void ffn_fused(
    const unsigned short* __restrict__ hbf, float* __restrict__ h,
    const unsigned short* __restrict__ W1, const float* __restrict__ b1,
    const unsigned short* __restrict__ W2, const float* __restrict__ b2,
    const float* __restrict__ lnw, const float* __restrict__ lnb,
    unsigned short* __restrict__ hbfout) {
  __shared__ __align__(16) char smem[64 * 264 * 2];
  unsigned short (*F1)[264] = (unsigned short (*)[264])smem;
  float (*Ef)[132] = (float (*)[132])smem;
  int nbr = (NN + 63) >> 6;
  int rpx = (nbr + 7) >> 3;
  int xcd = blockIdx.x & 7, j = blockIdx.x >> 3;
  int rowT = xcd * rpx + j;
  if (rowT >= nbr) return;
  int rowBase = rowT * 64;

  int t = threadIdx.x;
  int lane = t & 63, w = t >> 6;
  int wm = w >> 1, wn = w & 1;
  int q = lane >> 4, mr = lane & 15;

  const unsigned short* ap[2];
#pragma unroll
  for (int mt = 0; mt < 2; ++mt) {
    int gr = rowBase + wm * 32 + mt * 16 + mr;
    int cg = (gr < NN) ? gr : 0;
    ap[mt] = hbf + (size_t)cg * HID + q * 8;
  }
  bf16x8 a[2][4];
#pragma unroll
  for (int mt = 0; mt < 2; ++mt)
#pragma unroll
    for (int k = 0; k < 4; ++k) a[mt][k] = *(const bf16x8*)(ap[mt] + k * 32);

#pragma unroll
  for (int ph = 0; ph < 2; ++ph) {
    const unsigned short* wp[4];
#pragma unroll
    for (int nt = 0; nt < 4; ++nt)
      wp[nt] = W1 + (size_t)(ph * 128 + wn * 64 + nt * 16 + mr) * HID + q * 8;
    f32x4 acc[2][4] = {};
#pragma unroll
    for (int k = 0; k < 4; ++k) {
      bf16x8 bfr[4];
#pragma unroll
      for (int nt = 0; nt < 4; ++nt) bfr[nt] = *(const bf16x8*)(wp[nt] + k * 32);
#pragma unroll
      for (int mt = 0; mt < 2; ++mt)
#pragma unroll
        for (int nt = 0; nt < 4; ++nt)
          acc[mt][nt] = __builtin_amdgcn_mfma_f32_16x16x32_bf16(a[mt][k], bfr[nt], acc[mt][nt], 0, 0, 0);
    }
    float bv[4];
#pragma unroll
    for (int nt = 0; nt < 4; ++nt) bv[nt] = b1[ph * 128 + wn * 64 + nt * 16 + mr];
#pragma unroll
    for (int mt = 0; mt < 2; ++mt)
#pragma unroll
      for (int nt = 0; nt < 4; ++nt)
#pragma unroll
        for (int r = 0; r < 4; ++r) {
          float v = acc[mt][nt][r] + bv[nt];
          v = v / (1.f + expf(-v));
          F1[wm * 32 + mt * 16 + q * 4 + r][ph * 128 + wn * 64 + nt * 16 + mr] = f2b(v);
        }
  }
  __syncthreads();

  const unsigned short* wp2[4];
#pragma unroll
  for (int nt = 0; nt < 4; ++nt)
    wp2[nt] = W2 + (size_t)(wn * 64 + nt * 16 + mr) * FFH + q * 8;
  f32x4 acc2[2][4] = {};
#pragma unroll
  for (int k = 0; k < 8; ++k) {
    bf16x8 af[2], bfr[4];
#pragma unroll
    for (int mt = 0; mt < 2; ++mt)
      af[mt] = *(const bf16x8*)&F1[wm * 32 + mt * 16 + mr][k * 32 + q * 8];
#pragma unroll
    for (int nt = 0; nt < 4; ++nt) bfr[nt] = *(const bf16x8*)(wp2[nt] + k * 32);
#pragma unroll
    for (int mt = 0; mt < 2; ++mt)
#pragma unroll
      for (int nt = 0; nt < 4; ++nt)
        acc2[mt][nt] = __builtin_amdgcn_mfma_f32_16x16x32_bf16(af[mt], bfr[nt], acc2[mt][nt], 0, 0, 0);
  }
  __syncthreads();

  float bv2[4];
#pragma unroll
  for (int nt = 0; nt < 4; ++nt) bv2[nt] = b2[wn * 64 + nt * 16 + mr];
#pragma unroll
  for (int mt = 0; mt < 2; ++mt)
#pragma unroll
    for (int nt = 0; nt < 4; ++nt)
#pragma unroll
      for (int r = 0; r < 4; ++r)
        Ef[wm * 32 + mt * 16 + q * 4 + r][wn * 64 + nt * 16 + mr] = acc2[mt][nt][r] + bv2[nt];
  __syncthreads();

  float w0 = lnw[lane], w1 = lnw[64 + lane];
  float bb0 = lnb[lane], bb1 = lnb[64 + lane];
  for (int rr = w; rr < 64; rr += 4) {
    int grow = rowBase + rr;
    if (grow >= NN) continue;
    size_t base = (size_t)grow * HID;
    float x0 = h[base + lane] + Ef[rr][lane];
    float x1 = h[base + 64 + lane] + Ef[rr][64 + lane];
    float s = x0 + x1;
#pragma unroll
    for (int o = 32; o > 0; o >>= 1) s += __shfl_xor(s, o, 64);
    float mean = s * (1.f / 128.f);
    float d0 = x0 - mean, d1 = x1 - mean;
    float v = d0 * d0 + d1 * d1;
#pragma unroll
    for (int o = 32; o > 0; o >>= 1) v += __shfl_xor(v, o, 64);
    float inv = 1.f / sqrtf(v * (1.f / 128.f) + 1e-5f);
    float y0 = d0 * inv * w0 + bb0;
    float y1 = d1 * inv * w1 + bb1;
    h[base + lane] = y0;
    h[base + 64 + lane] = y1;
    hbfout[base + lane] = f2b(y0);
    hbfout[base + 64 + lane] = f2b(y1);
  }
}

__global__ void build_xin_bf(const float* __restrict__ x, const int* __restrict__ idtok,
                             const float* __restrict__ emb, unsigned short* __restrict__ xin) {
  int i = blockIdx.x * blockDim.x + threadIdx.x;
  if (i >= NN * 96) return;
  int n = i / 96, k = i - n * 96;
  float v = (k < FN) ? x[(size_t)n * FN + k] : emb[(size_t)idtok[n] * IDE + (k - FN)];
  xin[i] = f2b(v);
}

// ---- CSR by (rel, dst) ----
__global__ void hist_bin(const int* __restrict__ ei, const int* __restrict__ et,
                         int* __restrict__ bcnt) {
  int e = blockIdx.x * blockDim.x + threadIdx.x;
  if (e >= NE) return;
  atomicAdd(&bcnt[et[e] * NN + ei[NE + e]], 1);
}
__global__ __launch_bounds__(256) void scan1(const int* __restrict__ cnt,
                                             int* __restrict__ pos, int* __restrict__ bsum) {
  __shared__ int lds[256];
  int b = blockIdx.x, t = threadIdx.x;
  int base = b * 1024 + t * 4;
  int v[4];
#pragma unroll
  for (int j = 0; j < 4; ++j) v[j] = (base + j < NBIN) ? cnt[base + j] : 0;
  int tot = v[0] + v[1] + v[2] + v[3];
  lds[t] = tot;
  __syncthreads();
  for (int off = 1; off < 256; off <<= 1) {
    int x = (t >= off) ? lds[t - off] : 0;
    __syncthreads();
    lds[t] += x;
    __syncthreads();
  }
  if (t == 255) bsum[b] = lds[255];
  int run = lds[t] - tot;
#pragma unroll
  for (int j = 0; j < 4; ++j) {
    if (base + j < NBIN) pos[base + j] = run;
    run += v[j];
  }
}
__global__ __launch_bounds__(256) void scan2(int* __restrict__ bsum) {
  __shared__ int lds[256];
  int t = threadIdx.x;
  int v = (t < SCAN_BLK) ? bsum[t] : 0;
  lds[t] = v;
  __syncthreads();
  for (int off = 1; off < 256; off <<= 1) {
    int x = (t >= off) ? lds[t - off] : 0;
    __syncthreads();
    lds[t] += x;
    __syncthreads();
  }
  if (t < SCAN_BLK) bsum[t] = lds[t] - v;
}
__global__ void scan3(int* __restrict__ pos, const int* __restrict__ bsum,
                      const int* __restrict__ cnt) {
  int i = blockIdx.x * blockDim.x + threadIdx.x;
  if (i >= NBIN) return;
  pos[i] += bsum[i >> 10];
  if (i == NBIN - 1) pos[NBIN] = pos[i] + cnt[i];
}
__global__ void scatter_bin(const int* __restrict__ ei, const int* __restrict__ et,
                            const int* __restrict__ csroff, int* __restrict__ cur,
                            int* __restrict__ elist) {
  int e = blockIdx.x * blockDim.x + threadIdx.x;
  if (e >= NE) return;
  int bin = et[e] * NN + ei[NE + e];
  int p = atomicAdd(&cur[bin], 1);
  elist[csroff[bin] + p] = e;
}
// DETERMINISM: atomic scatter order varies call-to-call; sort each bin.
__global__ void sort_bins(const int* __restrict__ csroff, int* __restrict__ elist) {
  int b = blockIdx.x * blockDim.x + threadIdx.x;
  if (b >= NBIN) return;
  int s = csroff[b], e = csroff[b + 1];
  for (int i = s + 1; i < e; ++i) {
    int key = elist[i];
    int j = i - 1;
    while (j >= s && elist[j] > key) { elist[j + 1] = elist[j]; --j; }
    elist[j + 1] = key;
  }
}
__global__ void gather_edge(const int* __restrict__ ei, const int* __restrict__ elist,
                            const float* __restrict__ eattr,
                            int* __restrict__ rsrc, float* __restrict__ eacsr) {
  int p = blockIdx.x * blockDim.x + threadIdx.x;
  if (p >= NE) return;
  int e = elist[p];
  rsrc[p] = ei[e];
  const float4* s = (const float4*)(eattr + (size_t)e * NEA);
  float4* d = (float4*)(eacsr + (size_t)p * NEA);
#pragma unroll
  for (int j = 0; j < 4; ++j) d[j] = s[j];
}
__global__ void mark_src(const int* __restrict__ ei, const int* __restrict__ et,
                         int* __restrict__ srcflag) {
  int e = blockIdx.x * blockDim.x + threadIdx.x;
  if (e >= NE) return;
  srcflag[et[e] * NN + ei[e]] = 1;
}
// ORDERED src compaction from scan positions (deterministic + sequential gather)
__global__ void build_src_o(const int* __restrict__ srcflag, const int* __restrict__ srcpos,
                            int* __restrict__ srclist, int* __restrict__ srcmap) {
  int b = blockIdx.x * blockDim.x + threadIdx.x;
  if (b >= NBIN) return;
  if (srcflag[b]) {
    int rel = b / NN;
    int pos = srcpos[b] - srcpos[rel * NN];
    srcmap[b] = pos;
    srclist[rel * NN + pos] = b - rel * NN;
  }
}
__global__ void fincnt(const int* __restrict__ srcpos, int* __restrict__ nsrc) {
  int r = threadIdx.x;
  if (r < NR) nsrc[r * 16] = srcpos[(r + 1) * NN] - srcpos[r * NN];
}
__global__ void remap_rsrc(const int* __restrict__ csroff, const int* __restrict__ rsrc,
                           const int* __restrict__ srcmap, int* __restrict__ rsrcx) {
  int p = blockIdx.x * blockDim.x + threadIdx.x;
  if (p >= NE) return;
  int rel = (p >= csroff[NN]) + (p >= csroff[2 * NN]) + (p >= csroff[3 * NN]);
  rsrcx[p] = srcmap[rel * NN + rsrc[p]];
}
// per-rel hot (deg>=2) list + inverse map hotpos[rel*NN+dst] = row in xrh slice.
__global__ __launch_bounds__(256) void build_hot2(
    const int* __restrict__ csroff, int* __restrict__ nhot,
    int* __restrict__ hotlist, int* __restrict__ hotpos) {
  __shared__ int whc[4][4];
  __shared__ int hbase[4];
  int t = threadIdx.x, wave = t >> 6, lane = t & 63;
  int b = blockIdx.x * 256 + t;
  bool valid = b < NBIN;
  int cnt = 0, rel = 0;
  if (valid) { cnt = csroff[b + 1] - csroff[b]; rel = b / NN; }
  bool hot = valid && cnt >= 2;
#pragma unroll
  for (int rr = 0; rr < 4; ++rr) {
    unsigned long long mh = __ballot(hot && rel == rr);
    if (lane == 0) whc[wave][rr] = __popcll(mh);
  }
  __syncthreads();
  if (t < 4) {
    int hsum = whc[0][t] + whc[1][t] + whc[2][t] + whc[3][t];
    hbase[t] = hsum ? atomicAdd(&nhot[t * 16], hsum) : 0;
  }
  __syncthreads();
#pragma unroll
  for (int rr = 0; rr < 4; ++rr) {
    unsigned long long mh = __ballot(hot && rel == rr);
    if (hot && rel == rr) {
      int before = 0;
#pragma unroll
      for (int wv = 0; wv < 4; ++wv) if (wv < wave) before += whc[wv][rr];
      int pos = hbase[rr] + before + __popcll(mh & ((1ull << lane) - 1ull));
      int d = b - rr * NN;
      hotlist[rr * NN + pos] = d;
      hotpos[rr * NN + d] = pos;
    }
  }
}
// dsts with >=1 edge in any rel (order-independent: each dst processed identically)
__global__ void build_dstlist(const int* __restrict__ csroff, int* __restrict__ dstlist,
                              int* __restrict__ ndst) {
  int d = blockIdx.x * blockDim.x + threadIdx.x;
  if (d >= NN) return;
  int tot = 0;
#pragma unroll
  for (int r = 0; r < NR; ++r) tot += csroff[r * NN + d + 1] - csroff[r * NN + d];
  if (tot > 0) {
    int p = atomicAdd(ndst, 1);
    dstlist[p] = d;
  }
}

// all-layers gate softmax + gated conv bias in one launch (block = layer)
__global__ void gate_cb_all(const float* __restrict__ rg, const float* __restrict__ cbias,
                            float* __restrict__ gate, float* __restrict__ cb) {
  __shared__ float g[NR];
  int l = blockIdx.x, t = threadIdx.x;
  const float* rgl = rg + l * NR;
  if (t == 0) {
    float mx = rgl[0];
    for (int r = 1; r < NR; ++r) mx = fmaxf(mx, rgl[r]);
    float s = 0.f, tmp[NR];
    for (int r = 0; r < NR; ++r) { tmp[r] = expf(rgl[r] - mx); s += tmp[r]; }
    for (int r = 0; r < NR; ++r) { g[r] = tmp[r] / s; gate[l * NR + r] = g[r]; }
  }
  __syncthreads();
  float c = 0.f;
  for (int r = 0; r < NR; ++r) c += g[r] * cbias[(size_t)l * NR * HID + r * HID + t];
  cb[l * HID + t] = c;
}

// ---- merged dst-centric edge pass: one launch per layer, all 4 rels.
// Block owns a dst (grid-stride over dstlist); loops rels (rel-outer so the
// 50-float wedge regs load once per rel per block). deg==1: direct add (softmax
// over 1 edge == 1). deg>=2: online-softmax attention. Single owner per dst ->
// no cross-rel races; fixed rel order -> bitwise-deterministic hmsg.
__global__ __launch_bounds__(256) void edge_dst_all(
    const int* __restrict__ csroff, const int* __restrict__ rsrcx,
    const float* __restrict__ eacsr,
    const float* __restrict__ relembL, const float* __restrict__ wedgeL,
    const float* __restrict__ attwL,
    const unsigned short* __restrict__ xlb, const unsigned short* __restrict__ xrh,
    const int* __restrict__ hotpos,
    const int* __restrict__ dstlist, const int* __restrict__ ndstp,
    float* __restrict__ hmsg, const float* __restrict__ gate) {
  __shared__ float lds[4][128];
  int wave = threadIdx.x >> 6, lane = threadIdx.x & 63;
  int ndst = *ndstp;
  for (int r = 0; r < NR; ++r) {
    float g4 = gate[r] * 0.25f;
    float wreg[2][24], areg[2];
#pragma unroll
    for (int j = 0; j < 2; ++j) {
      int col = wave * 128 + j * 64 + lane;
      const float* wp = wedgeL + ((size_t)r * 512 + col) * 24;
#pragma unroll
      for (int k = 0; k < 24; ++k) wreg[j][k] = wp[k];
      areg[j] = attwL[r * 512 + col];
    }
    float evr0 = 0.f, evr1 = 0.f;
#pragma unroll
    for (int k = 0; k < 8; ++k) {
      float rk = relembL[r * RED + k];
      evr0 += rk * wreg[0][NEA + k];
      evr1 += rk * wreg[1][NEA + k];
    }
    const unsigned short* xlbase = xlb + (size_t)r * CAPS * 512;
    const unsigned short* xrbase = xrh + (size_t)r * CAPH * 512;
    for (int i = blockIdx.x; i < ndst; i += gridDim.x) {
      int d = dstlist[i];
      int s = csroff[r * NN + d], e = csroff[r * NN + d + 1];
      int deg = e - s;
      if (deg == 0) continue;  // uniform across block
      float o0, o1;
      if (deg == 1) {
        int src = rsrcx[s];
        const unsigned short* xp = xlbase + (size_t)src * 512 + wave * 128;
        o0 = g4 * b2f(xp[lane]);
        o1 = g4 * b2f(xp[64 + lane]);
      } else {
        int wi = hotpos[r * NN + d];
        const unsigned short* xrp = xrbase + (size_t)wi * 512 + wave * 128;
        float xr0 = b2f(xrp[lane]), xr1 = b2f(xrp[64 + lane]);
        float m = -3.4e38f, den = 0.f, a0 = 0.f, a1 = 0.f;
        for (int p = s; p < e; ++p) {
          int src = rsrcx[p];
          const float* eap = eacsr + (size_t)p * NEA;
          float eev0 = evr0, eev1 = evr1;
#pragma unroll
          for (int k = 0; k < NEA; ++k) {
            float er = eap[k];
            eev0 += er * wreg[0][k];
            eev1 += er * wreg[1][k];
          }
          const unsigned short* xp = xlbase + (size_t)src * 512 + wave * 128;
          float xl0 = b2f(xp[lane]), xl1 = b2f(xp[64 + lane]);
          float s0 = xl0 + xr0 + eev0; s0 = (s0 > 0.f) ? s0 : 0.2f * s0;
          float s1 = xl1 + xr1 + eev1; s1 = (s1 > 0.f) ? s1 : 0.2f * s1;
          float lg = s0 * areg[0] + s1 * areg[1];
#pragma unroll
          for (int o = 32; o > 0; o >>= 1) lg += __shfl_xor(lg, o, 64);
          float mn = fmaxf(m, lg);
          float sc = expf(m - mn);
          float ex = expf(lg - mn);
          den = den * sc + ex;
          a0 = a0 * sc + ex * xl0;
          a1 = a1 * sc + ex * xl1;
          m = mn;
        }
        float wgt = g4 / den;
        o0 = a0 * wgt;
        o1 = a1 * wgt;
      }
      lds[wave][lane] = o0;
      lds[wave][64 + lane] = o1;
      __syncthreads();
      if (wave < 2) {
        int c = wave * 64 + lane;
        float v = lds[0][c] + lds[1][c] + lds[2][c] + lds[3][c];
        hmsg[(size_t)d * HID + c] += v;
      }
      __syncthreads();
    }
  }
}

// ---- h = layernorm(h + add (+ cb)); also emits bf16 copy ----
__global__ __launch_bounds__(256) void add_ln(
    float* __restrict__ h, const float* __restrict__ add, const float* __restrict__ cb,
    const float* __restrict__ w, const float* __restrict__ b,
    unsigned short* __restrict__ hbf, int nrows) {
  int wave = threadIdx.x >> 6, lane = threadIdx.x & 63;
  int row = blockIdx.x * 4 + wave;
  if (row >= nrows) return;
  size_t base = (size_t)row * HID;
  float x0 = h[base + lane] + add[base + lane];
  float x1 = h[base + 64 + lane] + add[base + 64 + lane];
  if (cb) { x0 += cb[lane]; x1 += cb[64 + lane]; }
  float s = x0 + x1;
#pragma unroll
  for (int o = 32; o > 0; o >>= 1) s += __shfl_xor(s, o, 64);
  float mean = s * (1.f / 128.f);
  float d0 = x0 - mean, d1 = x1 - mean;
  float v = d0 * d0 + d1 * d1;
#pragma unroll
  for (int o = 32; o > 0; o >>= 1) v += __shfl_xor(v, o, 64);
  float inv = 1.f / sqrtf(v * (1.f / 128.f) + 1e-5f);
  float y0 = d0 * inv * w[lane] + b[lane];
  float y1 = d1 * inv * w[64 + lane] + b[64 + lane];
  h[base + lane] = y0;
  h[base + 64 + lane] = y1;
  hbf[base + lane] = f2b(y0);
  hbf[base + 64 + lane] = f2b(y1);
}

// ---- readout: deterministic ----
__global__ void group_bounds(const int* __restrict__ batch, int* __restrict__ gstart) {
  int g = threadIdx.x + blockIdx.x * blockDim.x;
  if (g > NG) return;
  int lo = 0, hi = NN;
  while (lo < hi) {
    int mid = (lo + hi) >> 1;
    if (batch[mid] < g) lo = mid + 1; else hi = mid;
  }
  gstart[g] = lo;
}
__global__ __launch_bounds__(128) void readout_part2(
    const float* __restrict__ h, const int* __restrict__ gstart,
    float* __restrict__ psum, float* __restrict__ pmax) {
  int g = blockIdx.x, s = blockIdx.y, t = threadIdx.x;
  int r0 = gstart[g], r1 = gstart[g + 1];
  float acc = 0.f, mx = -3.4e38f;
  for (int row = r0 + s; row < r1; row += 8) {
    float v = h[(size_t)row * HID + t];
    acc += v;
    mx = fmaxf(mx, v);
  }
  psum[((size_t)g * 8 + s) * HID + t] = acc;
  pmax[((size_t)g * 8 + s) * HID + t] = mx;
}
__global__ __launch_bounds__(256) void readout_final(
    const int* __restrict__ gstart, const float* __restrict__ psum,
    const float* __restrict__ pmax, const float* __restrict__ w,
    const float* __restrict__ b, float* __restrict__ g) {
  int bg = blockIdx.x, t = threadIdx.x;
  __shared__ float red[256];
  float c = fmaxf((float)(gstart[bg + 1] - gstart[bg]), 1.f);
  float x;
  if (t < HID) {
    float ssum = 0.f;
    for (int s = 0; s < 8; ++s) ssum += psum[((size_t)bg * 8 + s) * HID + t];
    x = ssum / c;
  } else {
    float mx = -3.4e38f;
    for (int s = 0; s < 8; ++s) mx = fmaxf(mx, pmax[((size_t)bg * 8 + s) * HID + (t - HID)]);
    x = mx;
  }
  red[t] = x;
  __syncthreads();
  for (int s = 128; s > 0; s >>= 1) {
    if (t < s) red[t] += red[t + s];
    __syncthreads();
  }
  float mean = red[0] * (1.f / 256.f);
  __syncthreads();
  float d = x - mean;
  red[t] = d * d;
  __syncthreads();
  for (int s = 128; s > 0; s >>= 1) {
    if (t < s) red[t] += red[t + s];
    __syncthreads();
  }
  float inv = 1.f / sqrtf(red[0] * (1.f / 256.f) + 1e-5f);
  g[(size_t)bg * 256 + t] = d * inv * w[t] + b[t];
}

__device__ __forceinline__ void bspline8(float x, const float* __restrict__ t,
                                         float* __restrict__ out) {
  float bs[11];
#pragma unroll
  for (int j = 0; j < 11; ++j) bs[j] = (x >= t[j] && x < t[j + 1]) ? 1.f : 0.f;
#pragma unroll
  for (int k = 1; k <= 3; ++k) {
    for (int j = 0; j < 11 - k; ++j) {
      bs[j] = (x - t[j]) / (t[j + k] - t[j]) * bs[j] +
              (t[j + k + 1] - x) / (t[j + k + 1] - t[j + 1]) * bs[j + 1];
    }
  }
#pragma unroll
  for (int j = 0; j < 8; ++j) out[j] = bs[j];
}

// ---- KAN1, K-chunked into fixed partial slots (deterministic) ----
__global__ __launch_bounds__(128) void kan1_part(
    const float* __restrict__ g, const float* __restrict__ bw,
    const float* __restrict__ sw, const float* __restrict__ sc,
    const float* __restrict__ grid, float* __restrict__ zpart) {
  int bg = blockIdx.x, ch = blockIdx.y, t = threadIdx.x;
  int base = ch * 32;
  __shared__ float B[32][8];
  __shared__ float sg[32];
  if (t < 32) {
    float x = g[(size_t)bg * 256 + base + t];
    sg[t] = x / (1.f + expf(-x));
    bspline8(x, grid + (size_t)(base + t) * 12, B[t]);
  }
  __syncthreads();
  float acc = 0.f;
  for (int i = 0; i < 32; ++i) {
    int col = base + i;
    acc += sg[i] * bw[(size_t)t * 256 + col];
    const float* swp = sw + ((size_t)t * 256 + col) * 8;
    float sp = 0.f;
#pragma unroll
    for (int k = 0; k < 8; ++k) sp += B[i][k] * swp[k];
    acc += sp * sc[(size_t)t * 256 + col];
  }
  zpart[((size_t)ch * NG + bg) * KH + t] = acc;
}

__global__ __launch_bounds__(128) void kan2(
    const float* __restrict__ zpart, const float* __restrict__ bw,
    const float* __restrict__ sw, const float* __restrict__ sc,
    const float* __restrict__ grid, float* __restrict__ out) {
  int bg = blockIdx.x, t = threadIdx.x;
  __shared__ float B[128][8];
  __shared__ float sz[128];
  float x = 0.f;
  for (int ch = 0; ch < 8; ++ch) x += zpart[((size_t)ch * NG + bg) * KH + t];
  sz[t] = x / (1.f + expf(-x));
  bspline8(x, grid + (size_t)t * 12, B[t]);
  __syncthreads();
  if (t < NC) {
    float acc = 0.f;
    for (int i = 0; i < 128; ++i) {
      acc += sz[i] * bw[(size_t)t * 128 + i];
      const float* swp = sw + ((size_t)t * 128 + i) * 8;
      float sp = 0.f;
#pragma unroll
      for (int k = 0; k < 8; ++k) sp += B[i][k] * swp[k];
      acc += sp * sc[(size_t)t * 128 + i];
    }
    out[(size_t)bg * NC + t] = acc;
  }
}

extern "C" void kernel_launch(void* const* d_in, const int* in_sizes, int n_in,
                              void* d_out, int out_size, void* d_ws, size_t ws_size,
                              hipStream_t stream) {
  const float* x       = (const float*)d_in[0];
  const float* eattr   = (const float*)d_in[1];
  const int*   idtok   = (const int*)d_in[2];
  const int*   ei      = (const int*)d_in[3];
  const int*   etype   = (const int*)d_in[4];
  const int*   batch   = (const int*)d_in[5];
  const float* idemb   = (const float*)d_in[6];
  const float* inw     = (const float*)d_in[7];
  const float* inb     = (const float*)d_in[8];
  const float* relemb  = (const float*)d_in[9];
  const float* linlw   = (const float*)d_in[10];
  const float* linlb   = (const float*)d_in[11];
  const float* linrw   = (const float*)d_in[12];
  const float* linrb   = (const float*)d_in[13];
  const float* linew   = (const float*)d_in[14];
  const float* attw    = (const float*)d_in[15];
  const float* convb   = (const float*)d_in[16];
  const float* relgate = (const float*)d_in[17];
  const float* n1w     = (const float*)d_in[18];
  const float* n1b     = (const float*)d_in[19];
  const float* n2w     = (const float*)d_in[20];
  const float* n2b     = (const float*)d_in[21];
  const float* f1w     = (const float*)d_in[22];
  const float* f1bias  = (const float*)d_in[23];
  const float* f2w     = (const float*)d_in[24];
  const float* f2bias  = (const float*)d_in[25];
  const float* rnw     = (const float*)d_in[26];
  const float* rnb     = (const float*)d_in[27];
  const float* bw1     = (const float*)d_in[28];
  const float* sw1     = (const float*)d_in[29];
  const float* sc1     = (const float*)d_in[30];
  const float* grid1   = (const float*)d_in[31];
  const float* bw2     = (const float*)d_in[32];
  const float* sw2     = (const float*)d_in[33];
  const float* sc2     = (const float*)d_in[34];
  const float* grid2   = (const float*)d_in[35];
  float* out = (float*)d_out;
  (void)in_sizes; (void)n_in; (void)out_size; (void)ws_size;

  char* p = (char*)d_ws;
  auto alloc = [&](size_t bytes) { void* q = (void*)p; p += (bytes + 255) & ~(size_t)255; return q; };
  float* h    = (float*)alloc((size_t)NN * HID * 4);
  float* hmsg = (float*)alloc((size_t)NN * HID * 4);
  unsigned short* hbf = (unsigned short*)alloc((size_t)NN * HID * 2);
  unsigned short* xlb = (unsigned short*)alloc((size_t)NR * CAPS * 512 * 2);  // 134.2MB
  unsigned short* xrh = (unsigned short*)alloc((size_t)NR * CAPH * 512 * 2);  // 37.7MB
  int* elist = (int*)alloc((size_t)NE * 4);
  int* rsrc  = (int*)alloc((size_t)NE * 4);
  int* rsrcx = (int*)alloc((size_t)NE * 4);
  float* eacsr = (float*)alloc((size_t)NE * NEA * 4);
  int* bcnt  = (int*)alloc((size_t)NBIN * 8 + 8);
  int* cur   = bcnt + NBIN;
  int* csroff = (int*)alloc((size_t)(NBIN + 1) * 4);
  int* srcpos = (int*)alloc((size_t)(NBIN + 1) * 4);
  int* bsum  = (int*)alloc((size_t)SCAN_BLK * 4);
  int* hotlist = (int*)alloc((size_t)NR * NN * 4);
  int* hotpos  = (int*)alloc((size_t)NBIN * 4);
  int* srclist = (int*)alloc((size_t)NR * NN * 4);
  int* srcflag = (int*)alloc((size_t)NBIN * 4);
  int* srcmap  = (int*)alloc((size_t)NBIN * 4);
  int* dstlist = (int*)alloc((size_t)NN * 4);
  int* cnts    = (int*)alloc(1024);
  int* nhot    = cnts + 64;
  int* nsrc    = cnts + 128;
  int* ndst    = cnts + 192;
  unsigned short* linlwb = (unsigned short*)alloc((size_t)NL * NR * 512 * 128 * 2);
  unsigned short* linrwb = (unsigned short*)alloc((size_t)NL * NR * 512 * 128 * 2);
  unsigned short* f1wb   = (unsigned short*)alloc((size_t)NL * 256 * 128 * 2);
  unsigned short* f2wb   = (unsigned short*)alloc((size_t)NL * 128 * 256 * 2);
  unsigned short* inwb   = (unsigned short*)alloc((size_t)128 * 96 * 2);
  float* gate = (float*)alloc(NL * NR * 4);
  float* cb   = (float*)alloc(NL * HID * 4);
  int* gstart = (int*)alloc((size_t)(NG + 1) * 4);
  float* psum = (float*)alloc((size_t)NG * 8 * HID * 4);
  float* pmax = (float*)alloc((size_t)NG * 8 * HID * 4);
  float* zpart = (float*)alloc((size_t)8 * NG * KH * 4);
  float* g = (float*)alloc((size_t)NG * 256 * 4);
  unsigned short* xinbf = xlb;  // aliased: in-proj input staged before layer loop

  const int NB64 = (NN + 63) / 64;
  const int RPX = (NB64 + 7) / 8;

  {
    int n;
    n = NL * NR * 512 * 128 / 4;
    cvt_bf16<<<(n + 255) / 256, 256, 0, stream>>>(linlw, linlwb, n);
    cvt_bf16<<<(n + 255) / 256, 256, 0, stream>>>(linrw, linrwb, n);
    n = NL * 256 * 128 / 4;
    cvt_bf16<<<(n + 255) / 256, 256, 0, stream>>>(f1w, f1wb, n);
    cvt_bf16<<<(n + 255) / 256, 256, 0, stream>>>(f2w, f2wb, n);
    n = 128 * 96 / 4;
    cvt_bf16<<<(n + 255) / 256, 256, 0, stream>>>(inw, inwb, n);
  }

  hipMemsetAsync(bcnt, 0, (size_t)NBIN * 8 + 8, stream);
  hipMemsetAsync(srcflag, 0, (size_t)NBIN * 4, stream);
  hipMemsetAsync(cnts, 0, 1024, stream);
  hist_bin<<<(NE + 255) / 256, 256, 0, stream>>>(ei, etype, bcnt);
  scan1<<<SCAN_BLK, 256, 0, stream>>>(bcnt, csroff, bsum);
  scan2<<<1, 256, 0, stream>>>(bsum);
  scan3<<<(NBIN + 255) / 256, 256, 0, stream>>>(csroff, bsum, bcnt);
  scatter_bin<<<(NE + 255) / 256, 256, 0, stream>>>(ei, etype, csroff, cur, elist);
  sort_bins<<<(NBIN + 255) / 256, 256, 0, stream>>>(csroff, elist);
  gather_edge<<<(NE + 255) / 256, 256, 0, stream>>>(ei, elist, eattr, rsrc, eacsr);
  mark_src<<<(NE + 255) / 256, 256, 0, stream>>>(ei, etype, srcflag);
  scan1<<<SCAN_BLK, 256, 0, stream>>>(srcflag, srcpos, bsum);
  scan2<<<1, 256, 0, stream>>>(bsum);
  scan3<<<(NBIN + 255) / 256, 256, 0, stream>>>(srcpos, bsum, srcflag);
  build_src_o<<<(NBIN + 255) / 256, 256, 0, stream>>>(srcflag, srcpos, srclist, srcmap);
  fincnt<<<1, 64, 0, stream>>>(srcpos, nsrc);
  remap_rsrc<<<(NE + 255) / 256, 256, 0, stream>>>(csroff, rsrc, srcmap, rsrcx);
  build_hot2<<<(NBIN + 255) / 256, 256, 0, stream>>>(csroff, nhot, hotlist, hotpos);
  build_dstlist<<<(NN + 255) / 256, 256, 0, stream>>>(csroff, dstlist, ndst);
  gate_cb_all<<<NL, 128, 0, stream>>>(relgate, convb, gate, cb);

  build_xin_bf<<<(NN * 96 + 255) / 256, 256, 0, stream>>>(x, idtok, idemb, xinbf);
  gemm_bf16_t<96><<<8 * RPX, 256, 0, stream>>>(xinbf, inwb, inb, h, hbf, NN, 128, 1, 1);

  for (int l = 0; l < NL; ++l) {
    hipMemsetAsync(hmsg, 0, (size_t)NN * HID * 4, stream);
    conv_xl_all<<<4096, 256, 0, stream>>>(
        hbf, srclist, hotlist, cnts,
        linlwb + (size_t)l * NR * 512 * 128, linlb + (size_t)l * NR * 512,
        linrwb + (size_t)l * NR * 512 * 128, linrb + (size_t)l * NR * 512,
        xlb, xrh);
    edge_dst_all<<<6144, 256, 0, stream>>>(
        csroff, rsrcx, eacsr,
        relemb + (size_t)l * NR * RED,
        linew + (size_t)l * NR * 512 * 24,
        attw + (size_t)l * NR * 512,
        xlb, xrh, hotpos, dstlist, ndst, hmsg, gate + l * NR);
    add_ln<<<(NN + 3) / 4, 256, 0, stream>>>(h, hmsg, cb + l * HID, n1w + l * HID, n1b + l * HID,
                                             hbf, NN);
    ffn_fused<<<8 * RPX, 256, 0, stream>>>(
        hbf, h, f1wb + (size_t)l * 256 * 128, f1bias + (size_t)l * 256,
        f2wb + (size_t)l * 128 * 256, f2bias + (size_t)l * 128,
        n2w + l * HID, n2b + l * HID, hbf);
  }

  group_bounds<<<1, 128, 0, stream>>>(batch, gstart);
  readout_part2<<<dim3(NG, 8), 128, 0, stream>>>(h, gstart, psum, pmax);
  readout_final<<<NG, 256, 0, stream>>>(gstart, psum, pmax, rnw, rnb, g);
  kan1_part<<<dim3(NG, 8), 128, 0, stream>>>(g, bw1, sw1, sc1, grid1, zpart);
  kan2<<<NG, 128, 0, stream>>>(zpart, bw2, sw2, sc2, grid2, out);
}

// Round 7
// 1213.002 us; speedup vs baseline: 1.1779x; 1.1779x over previous
//
#include <hip/hip_runtime.h>
#include <math.h>

#define NN 50000
#define NE 120000
#define FN 64
#define NEA 16
#define NR 4
#define NH 4
#define HID 128
#define NL 3
#define IDE 32
#define RED 8
#define NG 64
#define NC 10
#define KH 128
#define FFH 256
#define NBIN (NR * NN)
#define SCAN_BLK ((NBIN + 1023) / 1024)
// per-rel compacted-row capacities (actual ~22.6K src / ~6.1K hot per rel)
#define CAPS 32768
#define CAPH 9216

typedef short bf16x8 __attribute__((ext_vector_type(8)));
typedef float f32x4 __attribute__((ext_vector_type(4)));

__device__ __forceinline__ unsigned short f2b(float f) {
  unsigned u = __float_as_uint(f);
  unsigned r = (u + 0x7FFFu + ((u >> 16) & 1u)) >> 16;
  return (unsigned short)r;
}
__device__ __forceinline__ float b2f(unsigned short b) {
  return __uint_as_float((unsigned)b << 16);
}

__global__ void cvt_bf16(const float* __restrict__ s, unsigned short* __restrict__ d, int n4) {
  int i = blockIdx.x * blockDim.x + threadIdx.x;
  if (i >= n4) return;
  float4 v = ((const float4*)s)[i];
  ushort4 o;
  o.x = f2b(v.x); o.y = f2b(v.y); o.z = f2b(v.z); o.w = f2b(v.w);
  ((ushort4*)d)[i] = o;
}

// ---- GEMM core: 64x128 tile, NO-LDS streaming main loop (round-3/4 design).
template <int KT>
__device__ __forceinline__ void gemm_direct(
    const unsigned short* __restrict__ A, const int* __restrict__ rowlist,
    const unsigned short* __restrict__ W, const float* __restrict__ bias,
    float* __restrict__ Cf, unsigned short* __restrict__ Cb,
    int nrows, int mout, int act, int rowBase, int colBase) {
  constexpr int NK = KT / 32;
  __shared__ unsigned short Es[64][136];
  int t = threadIdx.x;
  int lane = t & 63, w = t >> 6;
  int wm = w >> 1, wn = w & 1;
  int q = lane >> 4, mr = lane & 15;

  const unsigned short* ap[2];
#pragma unroll
  for (int mt = 0; mt < 2; ++mt) {
    int gr = rowBase + wm * 32 + mt * 16 + mr;
    int cg = (gr < nrows) ? gr : 0;
    int ar = rowlist ? rowlist[cg] : cg;
    ap[mt] = A + (size_t)ar * KT + q * 8;
  }
  const unsigned short* wp[4];
#pragma unroll
  for (int nt = 0; nt < 4; ++nt)
    wp[nt] = W + (size_t)(colBase + wn * 64 + nt * 16 + mr) * KT + q * 8;

  f32x4 acc[2][4] = {};
#pragma unroll
  for (int k = 0; k < NK; ++k) {
    bf16x8 af[2], bfr[4];
#pragma unroll
    for (int mt = 0; mt < 2; ++mt) af[mt] = *(const bf16x8*)(ap[mt] + k * 32);
#pragma unroll
    for (int nt = 0; nt < 4; ++nt) bfr[nt] = *(const bf16x8*)(wp[nt] + k * 32);
#pragma unroll
    for (int mt = 0; mt < 2; ++mt)
#pragma unroll
      for (int nt = 0; nt < 4; ++nt)
        acc[mt][nt] = __builtin_amdgcn_mfma_f32_16x16x32_bf16(af[mt], bfr[nt], acc[mt][nt], 0, 0, 0);
  }

  float bv[4];
#pragma unroll
  for (int nt = 0; nt < 4; ++nt) bv[nt] = bias[colBase + wn * 64 + nt * 16 + mr];

  if (Cf) {
#pragma unroll
    for (int mt = 0; mt < 2; ++mt)
#pragma unroll
      for (int nt = 0; nt < 4; ++nt)
#pragma unroll
        for (int r = 0; r < 4; ++r) {
          int row = rowBase + wm * 32 + mt * 16 + q * 4 + r;
          int col = colBase + wn * 64 + nt * 16 + mr;
          if (row < nrows) {
            float v = acc[mt][nt][r] + bv[nt];
            if (act) v = v / (1.f + expf(-v));
            Cf[(size_t)row * mout + col] = v;
            if (Cb) Cb[(size_t)row * mout + col] = f2b(v);
          }
        }
  } else {
#pragma unroll
    for (int mt = 0; mt < 2; ++mt)
#pragma unroll
      for (int nt = 0; nt < 4; ++nt)
#pragma unroll
        for (int r = 0; r < 4; ++r) {
          float v = acc[mt][nt][r] + bv[nt];
          if (act) v = v / (1.f + expf(-v));
          Es[wm * 32 + mt * 16 + q * 4 + r][wn * 64 + nt * 16 + mr] = f2b(v);
        }
    __syncthreads();
    int rl = t >> 2, co = (t & 3) * 32;
    int grow = rowBase + rl;
    if (grow < nrows) {
      unsigned short* dst = Cb + (size_t)grow * mout + colBase + co;
#pragma unroll
      for (int j = 0; j < 4; ++j)
        *(bf16x8*)(dst + j * 8) = *(const bf16x8*)&Es[rl][co + j * 8];
    }
  }
}

// XCD-aware full GEMM (dispatch is round-robin over 8 XCDs: bid&7 = XCD)
template <int KT>
__global__ __launch_bounds__(256, 2) void gemm_bf16_t(
    const unsigned short* __restrict__ A, const unsigned short* __restrict__ W,
    const float* __restrict__ bias, float* __restrict__ Cf, unsigned short* __restrict__ Cb,
    int nrows, int mout, int act, int ncol) {
  int nbr = (nrows + 63) >> 6;
  int rpx = (nbr + 7) >> 3;
  int xcd = blockIdx.x & 7, j = blockIdx.x >> 3;
  int rowT = xcd * rpx + j / ncol;
  int cy = j - (j / ncol) * ncol;
  if (rowT >= nbr) return;
  gemm_direct<KT>(A, nullptr, W, bias, Cf, Cb, nrows, mout, act, rowT * 64, cy * 128);
}

// ---- merged conv GEMM: xl for all 4 rels' srclists + xr for all 4 rels' hotlists,
// one launch (replaces 4 gemm_rows2 dispatches/layer).
__global__ __launch_bounds__(256, 2) void conv_xl_all(
    const unsigned short* __restrict__ hbf,
    const int* __restrict__ srclist, const int* __restrict__ hotlist,
    const int* __restrict__ cnts,  // nsrc @ [128 + r*16], nhot @ [64 + r*16]
    const unsigned short* __restrict__ Wl, const float* __restrict__ bl,
    const unsigned short* __restrict__ Wr, const float* __restrict__ br,
    unsigned short* __restrict__ xlb, unsigned short* __restrict__ xrh) {
  for (int tid = blockIdx.x;; tid += gridDim.x) {
    int rem = tid, seg = 0, nrows = 0;
    for (; seg < 8; ++seg) {
      int r = seg >> 1;
      int n = (seg & 1) ? cnts[64 + r * 16] : cnts[128 + r * 16];
      int cap = (seg & 1) ? CAPH : CAPS;
      if (n > cap) n = cap;
      int tseg = ((n + 63) >> 6) * 4;
      if (rem < tseg) { nrows = n; break; }
      rem -= tseg;
    }
    if (seg == 8) return;
    int r = seg >> 1, sel = seg & 1;
    int rt = rem >> 2, ct = rem & 3;
    const int* list = (sel ? hotlist : srclist) + r * NN;
    const unsigned short* W = (sel ? Wr : Wl) + (size_t)r * 512 * 128;
    const float* bias = (sel ? br : bl) + (size_t)r * 512;
    unsigned short* C = sel ? (xrh + (size_t)r * CAPH * 512) : (xlb + (size_t)r * CAPS * 512);
    gemm_direct<128>(hbf, list, W, bias, nullptr, C, nrows, 512, 0, rt * 64, ct * 128);
    __syncthreads();  // LDS WAR between tiles
  }
}

// ---- layer tail: LN1(h+hmsg+cb) -> y; f1=silu(y@W1^T+b1); f2=f1@W2^T+b2;
// h=LN2(y+f2); emits hbf (post-LN2). Fuses add_ln into ffn_fused: the FFN block
// only reads its OWN 64 rows' post-LN1 values, so LN1 runs as a front phase and
// stages y as bf16 A-frags in LDS (identical f32 math/order as the split kernels;
// post-LN1 hbf round-trip eliminated). LDS: Y 64x136 bf16 + F1 64x264 bf16 = 51.2KB.
__global__ __launch_bounds__(256, 2) void layer_tail(
    float* __restrict__ h, const float* __restrict__ hmsg, const float* __restrict__ cb,
    const float* __restrict__ n1w, const float* __restrict__ n1b,
    const unsigned short* __restrict__ W1, const float* __restrict__ b1,
    const unsigned short* __restrict__ W2, const float* __restrict__ b2,
    const float* __restrict__ n2w, const float* __restrict__ n2b,
    unsigned short* __restrict__ hbfout) {
  __shared__ __align__(16) char smem[64 * 136 * 2 + 64 * 264 * 2];
  unsigned short (*Y)[136] = (unsigned short (*)[136])smem;
  unsigned short (*F1)[264] = (unsigned short (*)[264])(smem + 64 * 136 * 2);
  float (*Ef)[132] = (float (*)[132])(smem + 64 * 136 * 2);
  int nbr = (NN + 63) >> 6;
  int rpx = (nbr + 7) >> 3;
  int xcd = blockIdx.x & 7, j = blockIdx.x >> 3;
  int rowT = xcd * rpx + j;
  if (rowT >= nbr) return;
  int rowBase = rowT * 64;

  int t = threadIdx.x;
  int lane = t & 63, w = t >> 6;
  int wm = w >> 1, wn = w & 1;
  int q = lane >> 4, mr = lane & 15;

  // ---- phase 0: LN1 over own 64 rows (wave-per-row, identical math to add_ln)
  {
    float w0 = n1w[lane], w1 = n1w[64 + lane];
    float bb0 = n1b[lane], bb1 = n1b[64 + lane];
    float c0 = cb[lane], c1 = cb[64 + lane];
    for (int rr = w; rr < 64; rr += 4) {
      int grow = rowBase + rr;
      if (grow < NN) {
        size_t base = (size_t)grow * HID;
        float x0 = h[base + lane] + hmsg[base + lane] + c0;
        float x1 = h[base + 64 + lane] + hmsg[base + 64 + lane] + c1;
        float s = x0 + x1;
#pragma unroll
        for (int o = 32; o > 0; o >>= 1) s += __shfl_xor(s, o, 64);
        float mean = s * (1.f / 128.f);
        float d0 = x0 - mean, d1 = x1 - mean;
        float v = d0 * d0 + d1 * d1;
#pragma unroll
        for (int o = 32; o > 0; o >>= 1) v += __shfl_xor(v, o, 64);
        float inv = 1.f / sqrtf(v * (1.f / 128.f) + 1e-5f);
        float y0 = d0 * inv * w0 + bb0;
        float y1 = d1 * inv * w1 + bb1;
        h[base + lane] = y0;
        h[base + 64 + lane] = y1;
        Y[rr][lane] = f2b(y0);
        Y[rr][64 + lane] = f2b(y1);
      } else {
        Y[rr][lane] = 0;
        Y[rr][64 + lane] = 0;
      }
    }
  }
  __syncthreads();

  // ---- phase A: f1 = silu(y @ W1^T + b1), A-frags from Y LDS
  bf16x8 a[2][4];
#pragma unroll
  for (int mt = 0; mt < 2; ++mt)
#pragma unroll
    for (int k = 0; k < 4; ++k)
      a[mt][k] = *(const bf16x8*)&Y[wm * 32 + mt * 16 + mr][k * 32 + q * 8];

#pragma unroll
  for (int ph = 0; ph < 2; ++ph) {
    const unsigned short* wp[4];
#pragma unroll
    for (int nt = 0; nt < 4; ++nt)
      wp[nt] = W1 + (size_t)(ph * 128 + wn * 64 + nt * 16 + mr) * HID + q * 8;
    f32x4 acc[2][4] = {};
#pragma unroll
    for (int k = 0; k < 4; ++k) {
      bf16x8 bfr[4];
#pragma unroll
      for (int nt = 0; nt < 4; ++nt) bfr[nt] = *(const bf16x8*)(wp[nt] + k * 32);
#pragma unroll
      for (int mt = 0; mt < 2; ++mt)
#pragma unroll
        for (int nt = 0; nt < 4; ++nt)
          acc[mt][nt] = __builtin_amdgcn_mfma_f32_16x16x32_bf16(a[mt][k], bfr[nt], acc[mt][nt], 0, 0, 0);
    }
    float bv[4];
#pragma unroll
    for (int nt = 0; nt < 4; ++nt) bv[nt] = b1[ph * 128 + wn * 64 + nt * 16 + mr];
#pragma unroll
    for (int mt = 0; mt < 2; ++mt)
#pragma unroll
      for (int nt = 0; nt < 4; ++nt)
#pragma unroll
        for (int r = 0; r < 4; ++r) {
          float v = acc[mt][nt][r] + bv[nt];
          v = v / (1.f + expf(-v));
          F1[wm * 32 + mt * 16 + q * 4 + r][ph * 128 + wn * 64 + nt * 16 + mr] = f2b(v);
        }
  }
  __syncthreads();

  // ---- phase B: f2 = f1 @ W2^T (K=256), A from LDS, W2 from L2
  const unsigned short* wp2[4];
#pragma unroll
  for (int nt = 0; nt < 4; ++nt)
    wp2[nt] = W2 + (size_t)(wn * 64 + nt * 16 + mr) * FFH + q * 8;
  f32x4 acc2[2][4] = {};
#pragma unroll
  for (int k = 0; k < 8; ++k) {
    bf16x8 af[2], bfr[4];
#pragma unroll
    for (int mt = 0; mt < 2; ++mt)
      af[mt] = *(const bf16x8*)&F1[wm * 32 + mt * 16 + mr][k * 32 + q * 8];
#pragma unroll
    for (int nt = 0; nt < 4; ++nt) bfr[nt] = *(const bf16x8*)(wp2[nt] + k * 32);
#pragma unroll
    for (int mt = 0; mt < 2; ++mt)
#pragma unroll
      for (int nt = 0; nt < 4; ++nt)
        acc2[mt][nt] = __builtin_amdgcn_mfma_f32_16x16x32_bf16(af[mt], bfr[nt], acc2[mt][nt], 0, 0, 0);
  }
  __syncthreads();  // all F1 reads done before overwriting as Ef

  // ---- phase C: stage f2+b2 in LDS (f32), then LN2(y + f2) -> h, hbf
  float bv2[4];
#pragma unroll
  for (int nt = 0; nt < 4; ++nt) bv2[nt] = b2[wn * 64 + nt * 16 + mr];
#pragma unroll
  for (int mt = 0; mt < 2; ++mt)
#pragma unroll
    for (int nt = 0; nt < 4; ++nt)
#pragma unroll
      for (int r = 0; r < 4; ++r)
        Ef[wm * 32 + mt * 16 + q * 4 + r][wn * 64 + nt * 16 + mr] = acc2[mt][nt][r] + bv2[nt];
  __syncthreads();

  float w0 = n2w[lane], w1 = n2w[64 + lane];
  float bb0 = n2b[lane], bb1 = n2b[64 + lane];
  for (int rr = w; rr < 64; rr += 4) {
    int grow = rowBase + rr;
    if (grow >= NN) continue;
    size_t base = (size_t)grow * HID;
    float x0 = h[base + lane] + Ef[rr][lane];          // h holds y (phase 0), L2-hot
    float x1 = h[base + 64 + lane] + Ef[rr][64 + lane];
    float s = x0 + x1;
#pragma unroll
    for (int o = 32; o > 0; o >>= 1) s += __shfl_xor(s, o, 64);
    float mean = s * (1.f / 128.f);
    float d0 = x0 - mean, d1 = x1 - mean;
    float v = d0 * d0 + d1 * d1;
#pragma unroll
    for (int o = 32; o > 0; o >>= 1) v += __shfl_xor(v, o, 64);
    float inv = 1.f / sqrtf(v * (1.f / 128.f) + 1e-5f);
    float y0 = d0 * inv * w0 + bb0;
    float y1 = d1 * inv * w1 + bb1;
    h[base + lane] = y0;
    h[base + 64 + lane] = y1;
    hbfout[base + lane] = f2b(y0);
    hbfout[base + 64 + lane] = f2b(y1);
  }
}

__global__ void build_xin_bf(const float* __restrict__ x, const int* __restrict__ idtok,
                             const float* __restrict__ emb, unsigned short* __restrict__ xin) {
  int i = blockIdx.x * blockDim.x + threadIdx.x;
  if (i >= NN * 96) return;
  int n = i / 96, k = i - n * 96;
  float v = (k < FN) ? x[(size_t)n * FN + k] : emb[(size_t)idtok[n] * IDE + (k - FN)];
  xin[i] = f2b(v);
}

// ---- CSR by (rel, dst) ----
__global__ void hist_bin(const int* __restrict__ ei, const int* __restrict__ et,
                         int* __restrict__ bcnt) {
  int e = blockIdx.x * blockDim.x + threadIdx.x;
  if (e >= NE) return;
  atomicAdd(&bcnt[et[e] * NN + ei[NE + e]], 1);
}
__global__ __launch_bounds__(256) void scan1(const int* __restrict__ cnt,
                                             int* __restrict__ pos, int* __restrict__ bsum) {
  __shared__ int lds[256];
  int b = blockIdx.x, t = threadIdx.x;
  int base = b * 1024 + t * 4;
  int v[4];
#pragma unroll
  for (int j = 0; j < 4; ++j) v[j] = (base + j < NBIN) ? cnt[base + j] : 0;
  int tot = v[0] + v[1] + v[2] + v[3];
  lds[t] = tot;
  __syncthreads();
  for (int off = 1; off < 256; off <<= 1) {
    int x = (t >= off) ? lds[t - off] : 0;
    __syncthreads();
    lds[t] += x;
    __syncthreads();
  }
  if (t == 255) bsum[b] = lds[255];
  int run = lds[t] - tot;
#pragma unroll
  for (int j = 0; j < 4; ++j) {
    if (base + j < NBIN) pos[base + j] = run;
    run += v[j];
  }
}
__global__ __launch_bounds__(256) void scan2(int* __restrict__ bsum) {
  __shared__ int lds[256];
  int t = threadIdx.x;
  int v = (t < SCAN_BLK) ? bsum[t] : 0;
  lds[t] = v;
  __syncthreads();
  for (int off = 1; off < 256; off <<= 1) {
    int x = (t >= off) ? lds[t - off] : 0;
    __syncthreads();
    lds[t] += x;
    __syncthreads();
  }
  if (t < SCAN_BLK) bsum[t] = lds[t] - v;
}
__global__ void scan3(int* __restrict__ pos, const int* __restrict__ bsum,
                      const int* __restrict__ cnt) {
  int i = blockIdx.x * blockDim.x + threadIdx.x;
  if (i >= NBIN) return;
  pos[i] += bsum[i >> 10];
  if (i == NBIN - 1) pos[NBIN] = pos[i] + cnt[i];
}
__global__ void scatter_bin(const int* __restrict__ ei, const int* __restrict__ et,
                            const int* __restrict__ csroff, int* __restrict__ cur,
                            int* __restrict__ elist) {
  int e = blockIdx.x * blockDim.x + threadIdx.x;
  if (e >= NE) return;
  int bin = et[e] * NN + ei[NE + e];
  int p = atomicAdd(&cur[bin], 1);
  elist[csroff[bin] + p] = e;
}
// DETERMINISM: atomic scatter order varies call-to-call; sort each bin.
__global__ void sort_bins(const int* __restrict__ csroff, int* __restrict__ elist) {
  int b = blockIdx.x * blockDim.x + threadIdx.x;
  if (b >= NBIN) return;
  int s = csroff[b], e = csroff[b + 1];
  for (int i = s + 1; i < e; ++i) {
    int key = elist[i];
    int j = i - 1;
    while (j >= s && elist[j] > key) { elist[j + 1] = elist[j]; --j; }
    elist[j + 1] = key;
  }
}
__global__ void gather_edge(const int* __restrict__ ei, const int* __restrict__ elist,
                            const float* __restrict__ eattr,
                            int* __restrict__ rsrc, float* __restrict__ eacsr) {
  int p = blockIdx.x * blockDim.x + threadIdx.x;
  if (p >= NE) return;
  int e = elist[p];
  rsrc[p] = ei[e];
  const float4* s = (const float4*)(eattr + (size_t)e * NEA);
  float4* d = (float4*)(eacsr + (size_t)p * NEA);
#pragma unroll
  for (int j = 0; j < 4; ++j) d[j] = s[j];
}
__global__ void mark_src(const int* __restrict__ ei, const int* __restrict__ et,
                         int* __restrict__ srcflag) {
  int e = blockIdx.x * blockDim.x + threadIdx.x;
  if (e >= NE) return;
  srcflag[et[e] * NN + ei[e]] = 1;
}
// ORDERED src compaction from scan positions (deterministic + sequential gather)
__global__ void build_src_o(const int* __restrict__ srcflag, const int* __restrict__ srcpos,
                            int* __restrict__ srclist, int* __restrict__ srcmap) {
  int b = blockIdx.x * blockDim.x + threadIdx.x;
  if (b >= NBIN) return;
  if (srcflag[b]) {
    int rel = b / NN;
    int pos = srcpos[b] - srcpos[rel * NN];
    srcmap[b] = pos;
    srclist[rel * NN + pos] = b - rel * NN;
  }
}
__global__ void fincnt(const int* __restrict__ srcpos, int* __restrict__ nsrc) {
  int r = threadIdx.x;
  if (r < NR) nsrc[r * 16] = srcpos[(r + 1) * NN] - srcpos[r * NN];
}
__global__ void remap_rsrc(const int* __restrict__ csroff, const int* __restrict__ rsrc,
                           const int* __restrict__ srcmap, int* __restrict__ rsrcx) {
  int p = blockIdx.x * blockDim.x + threadIdx.x;
  if (p >= NE) return;
  int rel = (p >= csroff[NN]) + (p >= csroff[2 * NN]) + (p >= csroff[3 * NN]);
  rsrcx[p] = srcmap[rel * NN + rsrc[p]];
}
// per-rel solo (deg==1: mapped src + dst) + hot (deg>=2) lists.
__global__ __launch_bounds__(256) void build_hot(
    const int* __restrict__ csroff, const int* __restrict__ rsrc,
    const int* __restrict__ srcmap,
    int* __restrict__ nsolo, int* __restrict__ nhot,
    int* __restrict__ solosrc, int* __restrict__ solodst, int* __restrict__ hotlist) {
  __shared__ int wsc[4][4], whc[4][4];
  __shared__ int sbase[4], hbase[4];
  int t = threadIdx.x, wave = t >> 6, lane = t & 63;
  int b = blockIdx.x * 256 + t;
  bool valid = b < NBIN;
  int cnt = 0, rel = 0, s = 0;
  if (valid) { s = csroff[b]; cnt = csroff[b + 1] - s; rel = b / NN; }
  bool solo = valid && cnt == 1;
  bool hot = valid && cnt >= 2;
#pragma unroll
  for (int rr = 0; rr < 4; ++rr) {
    unsigned long long ms = __ballot(solo && rel == rr);
    unsigned long long mh = __ballot(hot && rel == rr);
    if (lane == 0) { wsc[wave][rr] = __popcll(ms); whc[wave][rr] = __popcll(mh); }
  }
  __syncthreads();
  if (t < 4) {
    int ssum = wsc[0][t] + wsc[1][t] + wsc[2][t] + wsc[3][t];
    int hsum = whc[0][t] + whc[1][t] + whc[2][t] + whc[3][t];
    sbase[t] = ssum ? atomicAdd(&nsolo[t * 16], ssum) : 0;
    hbase[t] = hsum ? atomicAdd(&nhot[t * 16], hsum) : 0;
  }
  __syncthreads();
#pragma unroll
  for (int rr = 0; rr < 4; ++rr) {
    unsigned long long ms = __ballot(solo && rel == rr);
    if (solo && rel == rr) {
      int before = 0;
#pragma unroll
      for (int wv = 0; wv < 4; ++wv) if (wv < wave) before += wsc[wv][rr];
      int pos = sbase[rr] + before + __popcll(ms & ((1ull << lane) - 1ull));
      solosrc[rr * NN + pos] = srcmap[rr * NN + rsrc[s]];
      solodst[rr * NN + pos] = b - rr * NN;
    }
    unsigned long long mh = __ballot(hot && rel == rr);
    if (hot && rel == rr) {
      int before = 0;
#pragma unroll
      for (int wv = 0; wv < 4; ++wv) if (wv < wave) before += whc[wv][rr];
      int pos = hbase[rr] + before + __popcll(mh & ((1ull << lane) - 1ull));
      hotlist[rr * NN + pos] = b - rr * NN;
    }
  }
}

// all-layers gate softmax + gated conv bias in one launch (block = layer)
__global__ void gate_cb_all(const float* __restrict__ rg, const float* __restrict__ cbias,
                            float* __restrict__ gate, float* __restrict__ cb) {
  __shared__ float g[NR];
  int l = blockIdx.x, t = threadIdx.x;
  const float* rgl = rg + l * NR;
  if (t == 0) {
    float mx = rgl[0];
    for (int r = 1; r < NR; ++r) mx = fmaxf(mx, rgl[r]);
    float s = 0.f, tmp[NR];
    for (int r = 0; r < NR; ++r) { tmp[r] = expf(rgl[r] - mx); s += tmp[r]; }
    for (int r = 0; r < NR; ++r) { g[r] = tmp[r] / s; gate[l * NR + r] = g[r]; }
  }
  __syncthreads();
  float c = 0.f;
  for (int r = 0; r < NR; ++r) c += g[r] * cbias[(size_t)l * NR * HID + r * HID + t];
  cb[l * HID + t] = c;
}

// ---- fused edge pass (round-5 proven structure): blocks [0,soloB) deg-1
// (wave/dst, barrier-free); rest deg>=2 (block/dst, online softmax) ----
__global__ __launch_bounds__(256) void edge_all(
    const int* __restrict__ solosrc, const int* __restrict__ solodst,
    const int* __restrict__ nsolo,
    const int* __restrict__ csroff, const int* __restrict__ rsrcx,
    const float* __restrict__ eacsr, const float* __restrict__ relembp,
    const float* __restrict__ wedgep, const float* __restrict__ attwp,
    const unsigned short* __restrict__ xlb, const unsigned short* __restrict__ xrh,
    const int* __restrict__ hotlist, const int* __restrict__ nhot,
    float* __restrict__ hmsg, const float* __restrict__ gate,
    int rel, int soloB) {
  __shared__ float lds[4][128];
  int wave = threadIdx.x >> 6, lane = threadIdx.x & 63;
  float g4 = gate[rel] * 0.25f;
  if ((int)blockIdx.x < soloB) {
    int nw = nsolo[rel * 16];
    for (int i = (int)blockIdx.x * 4 + wave; i < nw; i += soloB * 4) {
      int src = solosrc[rel * NN + i];
      int dst = solodst[rel * NN + i];
      const unsigned short* xp = xlb + (size_t)src * 512;
      float v0 = 0.f, v1 = 0.f;
#pragma unroll
      for (int h = 0; h < NH; ++h) {
        v0 += b2f(xp[h * 128 + lane]);
        v1 += b2f(xp[h * 128 + 64 + lane]);
      }
      hmsg[(size_t)dst * HID + lane] += g4 * v0;
      hmsg[(size_t)dst * HID + 64 + lane] += g4 * v1;
    }
    return;
  }
  int hotB = gridDim.x - soloB;
  int hb = (int)blockIdx.x - soloB;
  int hh = wave;
  float wreg[2][24], areg[2];
#pragma unroll
  for (int j = 0; j < 2; ++j) {
    int col = hh * 128 + j * 64 + lane;
    const float* wp = wedgep + (size_t)col * 24;
#pragma unroll
    for (int k = 0; k < 24; ++k) wreg[j][k] = wp[k];
    areg[j] = attwp[col];
  }
  float evr0 = 0.f, evr1 = 0.f;
#pragma unroll
  for (int k = 0; k < 8; ++k) {
    float rk = relembp[k];
    evr0 += rk * wreg[0][NEA + k];
    evr1 += rk * wreg[1][NEA + k];
  }
  int nh = nhot[rel * 16];
  for (int wi = hb; wi < nh; wi += hotB) {
    int dst = hotlist[rel * NN + wi];
    int s = csroff[rel * NN + dst], e = csroff[rel * NN + dst + 1];
    {
      const unsigned short* xrp = xrh + (size_t)wi * 512;
      float xr0 = b2f(xrp[hh * 128 + lane]);
      float xr1 = b2f(xrp[hh * 128 + 64 + lane]);
      float m = -3.4e38f, den = 0.f, acc0 = 0.f, acc1 = 0.f;
      for (int p = s; p < e; ++p) {
        int src = rsrcx[p];
        const float* eap = eacsr + (size_t)p * NEA;
        float eev0 = evr0, eev1 = evr1;
#pragma unroll
        for (int k = 0; k < NEA; ++k) {
          float er = eap[k];
          eev0 += er * wreg[0][k];
          eev1 += er * wreg[1][k];
        }
        float xl0 = b2f(xlb[(size_t)src * 512 + hh * 128 + lane]);
        float xl1 = b2f(xlb[(size_t)src * 512 + hh * 128 + 64 + lane]);
        float s0 = xl0 + xr0 + eev0; s0 = (s0 > 0.f) ? s0 : 0.2f * s0;
        float s1 = xl1 + xr1 + eev1; s1 = (s1 > 0.f) ? s1 : 0.2f * s1;
        float lg = s0 * areg[0] + s1 * areg[1];
#pragma unroll
        for (int o = 32; o > 0; o >>= 1) lg += __shfl_xor(lg, o, 64);
        float mn = fmaxf(m, lg);
        float sc = expf(m - mn);
        float ex = expf(lg - mn);
        den = den * sc + ex;
        acc0 = acc0 * sc + ex * xl0;
        acc1 = acc1 * sc + ex * xl1;
        m = mn;
      }
      float wgt = g4 / den;
      lds[wave][lane] = acc0 * wgt;
      lds[wave][64 + lane] = acc1 * wgt;
    }
    __syncthreads();
    if (wave < 2) {
      int d = wave * 64 + lane;
      float v = lds[0][d] + lds[1][d] + lds[2][d] + lds[3][d];
      hmsg[(size_t)dst * HID + d] += v;
    }
    __syncthreads();
  }
}

// ---- readout: deterministic ----
__global__ void group_bounds(const int* __restrict__ batch, int* __restrict__ gstart) {
  int g = threadIdx.x + blockIdx.x * blockDim.x;
  if (g > NG) return;
  int lo = 0, hi = NN;
  while (lo < hi) {
    int mid = (lo + hi) >> 1;
    if (batch[mid] < g) lo = mid + 1; else hi = mid;
  }
  gstart[g] = lo;
}
__global__ __launch_bounds__(128) void readout_part2(
    const float* __restrict__ h, const int* __restrict__ gstart,
    float* __restrict__ psum, float* __restrict__ pmax) {
  int g = blockIdx.x, s = blockIdx.y, t = threadIdx.x;
  int r0 = gstart[g], r1 = gstart[g + 1];
  float acc = 0.f, mx = -3.4e38f;
  for (int row = r0 + s; row < r1; row += 8) {
    float v = h[(size_t)row * HID + t];
    acc += v;
    mx = fmaxf(mx, v);
  }
  psum[((size_t)g * 8 + s) * HID + t] = acc;
  pmax[((size_t)g * 8 + s) * HID + t] = mx;
}
__global__ __launch_bounds__(256) void readout_final(
    const int* __restrict__ gstart, const float* __restrict__ psum,
    const float* __restrict__ pmax, const float* __restrict__ w,
    const float* __restrict__ b, float* __restrict__ g) {
  int bg = blockIdx.x, t = threadIdx.x;
  __shared__ float red[256];
  float c = fmaxf((float)(gstart[bg + 1] - gstart[bg]), 1.f);
  float x;
  if (t < HID) {
    float ssum = 0.f;
    for (int s = 0; s < 8; ++s) ssum += psum[((size_t)bg * 8 + s) * HID + t];
    x = ssum / c;
  } else {
    float mx = -3.4e38f;
    for (int s = 0; s < 8; ++s) mx = fmaxf(mx, pmax[((size_t)bg * 8 + s) * HID + (t - HID)]);
    x = mx;
  }
  red[t] = x;
  __syncthreads();
  for (int s = 128; s > 0; s >>= 1) {
    if (t < s) red[t] += red[t + s];
    __syncthreads();
  }
  float mean = red[0] * (1.f / 256.f);
  __syncthreads();
  float d = x - mean;
  red[t] = d * d;
  __syncthreads();
  for (int s = 128; s > 0; s >>= 1) {
    if (t < s) red[t] += red[t + s];
    __syncthreads();
  }
  float inv = 1.f / sqrtf(red[0] * (1.f / 256.f) + 1e-5f);
  g[(size_t)bg * 256 + t] = d * inv * w[t] + b[t];
}

__device__ __forceinline__ void bspline8(float x, const float* __restrict__ t,
                                         float* __restrict__ out) {
  float bs[11];
#pragma unroll
  for (int j = 0; j < 11; ++j) bs[j] = (x >= t[j] && x < t[j + 1]) ? 1.f : 0.f;
#pragma unroll
  for (int k = 1; k <= 3; ++k) {
    for (int j = 0; j < 11 - k; ++j) {
      bs[j] = (x - t[j]) / (t[j + k] - t[j]) * bs[j] +
              (t[j + k + 1] - x) / (t[j + k + 1] - t[j + 1]) * bs[j + 1];
    }
  }
#pragma unroll
  for (int j = 0; j < 8; ++j) out[j] = bs[j];
}

// ---- KAN1, K-chunked into fixed partial slots (deterministic) ----
__global__ __launch_bounds__(128) void kan1_part(
    const float* __restrict__ g, const float* __restrict__ bw,
    const float* __restrict__ sw, const float* __restrict__ sc,
    const float* __restrict__ grid, float* __restrict__ zpart) {
  int bg = blockIdx.x, ch = blockIdx.y, t = threadIdx.x;
  int base = ch * 32;
  __shared__ float B[32][8];
  __shared__ float sg[32];
  if (t < 32) {
    float x = g[(size_t)bg * 256 + base + t];
    sg[t] = x / (1.f + expf(-x));
    bspline8(x, grid + (size_t)(base + t) * 12, B[t]);
  }
  __syncthreads();
  float acc = 0.f;
  for (int i = 0; i < 32; ++i) {
    int col = base + i;
    acc += sg[i] * bw[(size_t)t * 256 + col];
    const float* swp = sw + ((size_t)t * 256 + col) * 8;
    float sp = 0.f;
#pragma unroll
    for (int k = 0; k < 8; ++k) sp += B[i][k] * swp[k];
    acc += sp * sc[(size_t)t * 256 + col];
  }
  zpart[((size_t)ch * NG + bg) * KH + t] = acc;
}

__global__ __launch_bounds__(128) void kan2(
    const float* __restrict__ zpart, const float* __restrict__ bw,
    const float* __restrict__ sw, const float* __restrict__ sc,
    const float* __restrict__ grid, float* __restrict__ out) {
  int bg = blockIdx.x, t = threadIdx.x;
  __shared__ float B[128][8];
  __shared__ float sz[128];
  float x = 0.f;
  for (int ch = 0; ch < 8; ++ch) x += zpart[((size_t)ch * NG + bg) * KH + t];
  sz[t] = x / (1.f + expf(-x));
  bspline8(x, grid + (size_t)t * 12, B[t]);
  __syncthreads();
  if (t < NC) {
    float acc = 0.f;
    for (int i = 0; i < 128; ++i) {
      acc += sz[i] * bw[(size_t)t * 128 + i];
      const float* swp = sw + ((size_t)t * 128 + i) * 8;
      float sp = 0.f;
#pragma unroll
      for (int k = 0; k < 8; ++k) sp += B[i][k] * swp[k];
      acc += sp * sc[(size_t)t * 128 + i];
    }
    out[(size_t)bg * NC + t] = acc;
  }
}

extern "C" void kernel_launch(void* const* d_in, const int* in_sizes, int n_in,
                              void* d_out, int out_size, void* d_ws, size_t ws_size,
                              hipStream_t stream) {
  const float* x       = (const float*)d_in[0];
  const float* eattr   = (const float*)d_in[1];
  const int*   idtok   = (const int*)d_in[2];
  const int*   ei      = (const int*)d_in[3];
  const int*   etype   = (const int*)d_in[4];
  const int*   batch   = (const int*)d_in[5];
  const float* idemb   = (const float*)d_in[6];
  const float* inw     = (const float*)d_in[7];
  const float* inb     = (const float*)d_in[8];
  const float* relemb  = (const float*)d_in[9];
  const float* linlw   = (const float*)d_in[10];
  const float* linlb   = (const float*)d_in[11];
  const float* linrw   = (const float*)d_in[12];
  const float* linrb   = (const float*)d_in[13];
  const float* linew   = (const float*)d_in[14];
  const float* attw    = (const float*)d_in[15];
  const float* convb   = (const float*)d_in[16];
  const float* relgate = (const float*)d_in[17];
  const float* n1w     = (const float*)d_in[18];
  const float* n1b     = (const float*)d_in[19];
  const float* n2w     = (const float*)d_in[20];
  const float* n2b     = (const float*)d_in[21];
  const float* f1w     = (const float*)d_in[22];
  const float* f1bias  = (const float*)d_in[23];
  const float* f2w     = (const float*)d_in[24];
  const float* f2bias  = (const float*)d_in[25];
  const float* rnw     = (const float*)d_in[26];
  const float* rnb     = (const float*)d_in[27];
  const float* bw1     = (const float*)d_in[28];
  const float* sw1     = (const float*)d_in[29];
  const float* sc1     = (const float*)d_in[30];
  const float* grid1   = (const float*)d_in[31];
  const float* bw2     = (const float*)d_in[32];
  const float* sw2     = (const float*)d_in[33];
  const float* sc2     = (const float*)d_in[34];
  const float* grid2   = (const float*)d_in[35];
  float* out = (float*)d_out;
  (void)in_sizes; (void)n_in; (void)out_size; (void)ws_size;

  char* p = (char*)d_ws;
  auto alloc = [&](size_t bytes) { void* q = (void*)p; p += (bytes + 255) & ~(size_t)255; return q; };
  float* h    = (float*)alloc((size_t)NN * HID * 4);
  float* hmsg = (float*)alloc((size_t)NN * HID * 4);
  unsigned short* hbf = (unsigned short*)alloc((size_t)NN * HID * 2);
  unsigned short* xlb = (unsigned short*)alloc((size_t)NR * CAPS * 512 * 2);  // 134.2MB
  unsigned short* xrh = (unsigned short*)alloc((size_t)NR * CAPH * 512 * 2);  // 37.7MB
  int* elist = (int*)alloc((size_t)NE * 4);
  int* rsrc  = (int*)alloc((size_t)NE * 4);
  int* rsrcx = (int*)alloc((size_t)NE * 4);
  float* eacsr = (float*)alloc((size_t)NE * NEA * 4);
  int* bcnt  = (int*)alloc((size_t)NBIN * 8 + 8);
  int* cur   = bcnt + NBIN;
  int* csroff = (int*)alloc((size_t)(NBIN + 1) * 4);
  int* srcpos = (int*)alloc((size_t)(NBIN + 1) * 4);
  int* bsum  = (int*)alloc((size_t)SCAN_BLK * 4);
  int* hotlist = (int*)alloc((size_t)NR * NN * 4);
  int* solosrc = (int*)alloc((size_t)NR * NN * 4);
  int* solodst = (int*)alloc((size_t)NR * NN * 4);
  int* srclist = (int*)alloc((size_t)NR * NN * 4);
  int* srcflag = (int*)alloc((size_t)NBIN * 4);
  int* srcmap  = (int*)alloc((size_t)NBIN * 4);
  int* cnts    = (int*)alloc(1024);
  int* nsolo   = cnts;
  int* nhot    = cnts + 64;
  int* nsrc    = cnts + 128;
  unsigned short* linlwb = (unsigned short*)alloc((size_t)NL * NR * 512 * 128 * 2);
  unsigned short* linrwb = (unsigned short*)alloc((size_t)NL * NR * 512 * 128 * 2);
  unsigned short* f1wb   = (unsigned short*)alloc((size_t)NL * 256 * 128 * 2);
  unsigned short* f2wb   = (unsigned short*)alloc((size_t)NL * 128 * 256 * 2);
  unsigned short* inwb   = (unsigned short*)alloc((size_t)128 * 96 * 2);
  float* gate = (float*)alloc(NL * NR * 4);
  float* cb   = (float*)alloc(NL * HID * 4);
  int* gstart = (int*)alloc((size_t)(NG + 1) * 4);
  float* psum = (float*)alloc((size_t)NG * 8 * HID * 4);
  float* pmax = (float*)alloc((size_t)NG * 8 * HID * 4);
  float* zpart = (float*)alloc((size_t)8 * NG * KH * 4);
  float* g = (float*)alloc((size_t)NG * 256 * 4);
  unsigned short* xinbf = xlb;  // aliased: in-proj input staged before layer loop

  const int NB64 = (NN + 63) / 64;
  const int RPX = (NB64 + 7) / 8;

  {
    int n;
    n = NL * NR * 512 * 128 / 4;
    cvt_bf16<<<(n + 255) / 256, 256, 0, stream>>>(linlw, linlwb, n);
    cvt_bf16<<<(n + 255) / 256, 256, 0, stream>>>(linrw, linrwb, n);
    n = NL * 256 * 128 / 4;
    cvt_bf16<<<(n + 255) / 256, 256, 0, stream>>>(f1w, f1wb, n);
    cvt_bf16<<<(n + 255) / 256, 256, 0, stream>>>(f2w, f2wb, n);
    n = 128 * 96 / 4;
    cvt_bf16<<<(n + 255) / 256, 256, 0, stream>>>(inw, inwb, n);
  }

  hipMemsetAsync(bcnt, 0, (size_t)NBIN * 8 + 8, stream);
  hipMemsetAsync(srcflag, 0, (size_t)NBIN * 4, stream);
  hipMemsetAsync(cnts, 0, 1024, stream);
  hist_bin<<<(NE + 255) / 256, 256, 0, stream>>>(ei, etype, bcnt);
  scan1<<<SCAN_BLK, 256, 0, stream>>>(bcnt, csroff, bsum);
  scan2<<<1, 256, 0, stream>>>(bsum);
  scan3<<<(NBIN + 255) / 256, 256, 0, stream>>>(csroff, bsum, bcnt);
  scatter_bin<<<(NE + 255) / 256, 256, 0, stream>>>(ei, etype, csroff, cur, elist);
  sort_bins<<<(NBIN + 255) / 256, 256, 0, stream>>>(csroff, elist);
  gather_edge<<<(NE + 255) / 256, 256, 0, stream>>>(ei, elist, eattr, rsrc, eacsr);
  mark_src<<<(NE + 255) / 256, 256, 0, stream>>>(ei, etype, srcflag);
  scan1<<<SCAN_BLK, 256, 0, stream>>>(srcflag, srcpos, bsum);
  scan2<<<1, 256, 0, stream>>>(bsum);
  scan3<<<(NBIN + 255) / 256, 256, 0, stream>>>(srcpos, bsum, srcflag);
  build_src_o<<<(NBIN + 255) / 256, 256, 0, stream>>>(srcflag, srcpos, srclist, srcmap);
  fincnt<<<1, 64, 0, stream>>>(srcpos, nsrc);
  remap_rsrc<<<(NE + 255) / 256, 256, 0, stream>>>(csroff, rsrc, srcmap, rsrcx);
  build_hot<<<(NBIN + 255) / 256, 256, 0, stream>>>(csroff, rsrc, srcmap, nsolo, nhot,
                                                    solosrc, solodst, hotlist);
  gate_cb_all<<<NL, 128, 0, stream>>>(relgate, convb, gate, cb);

  build_xin_bf<<<(NN * 96 + 255) / 256, 256, 0, stream>>>(x, idtok, idemb, xinbf);
  gemm_bf16_t<96><<<8 * RPX, 256, 0, stream>>>(xinbf, inwb, inb, h, hbf, NN, 128, 1, 1);

  for (int l = 0; l < NL; ++l) {
    hipMemsetAsync(hmsg, 0, (size_t)NN * HID * 4, stream);
    conv_xl_all<<<4096, 256, 0, stream>>>(
        hbf, srclist, hotlist, cnts,
        linlwb + (size_t)l * NR * 512 * 128, linlb + (size_t)l * NR * 512,
        linrwb + (size_t)l * NR * 512 * 128, linrb + (size_t)l * NR * 512,
        xlb, xrh);
    for (int r = 0; r < NR; ++r) {
      int lr = l * NR + r;
      edge_all<<<6144, 256, 0, stream>>>(
          solosrc, solodst, nsolo,
          csroff, rsrcx, eacsr, relemb + (size_t)lr * RED,
          linew + (size_t)lr * 512 * 24,
          attw + (size_t)lr * 512,
          xlb + (size_t)r * CAPS * 512, xrh + (size_t)r * CAPH * 512,
          hotlist, nhot, hmsg, gate + l * NR, r, 2048);
    }
    layer_tail<<<8 * RPX, 256, 0, stream>>>(
        h, hmsg, cb + l * HID, n1w + l * HID, n1b + l * HID,
        f1wb + (size_t)l * 256 * 128, f1bias + (size_t)l * 256,
        f2wb + (size_t)l * 128 * 256, f2bias + (size_t)l * 128,
        n2w + l * HID, n2b + l * HID, hbf);
  }

  group_bounds<<<1, 128, 0, stream>>>(batch, gstart);
  readout_part2<<<dim3(NG, 8), 128, 0, stream>>>(h, gstart, psum, pmax);
  readout_final<<<NG, 256, 0, stream>>>(gstart, psum, pmax, rnw, rnb, g);
  kan1_part<<<dim3(NG, 8), 128, 0, stream>>>(g, bw1, sw1, sc1, grid1, zpart);
  kan2<<<NG, 128, 0, stream>>>(zpart, bw2, sw2, sc2, grid2, out);
}

// Round 8
// 1156.401 us; speedup vs baseline: 1.2356x; 1.0489x over previous
//
#include <hip/hip_runtime.h>
#include <math.h>

#define NN 50000
#define NE 120000
#define FN 64
#define NEA 16
#define NR 4
#define NH 4
#define HID 128
#define NL 3
#define IDE 32
#define RED 8
#define NG 64
#define NC 10
#define KH 128
#define FFH 256
#define NBIN (NR * NN)
#define SCAN_BLK ((NBIN + 1023) / 1024)
// per-rel compacted-row capacities (hot-srcs ~13K, hot-dsts ~6.1K per rel)
#define CAPS 32768
#define CAPH 9216

typedef short bf16x8 __attribute__((ext_vector_type(8)));
typedef float f32x4 __attribute__((ext_vector_type(4)));

__device__ __forceinline__ unsigned short f2b(float f) {
  unsigned u = __float_as_uint(f);
  unsigned r = (u + 0x7FFFu + ((u >> 16) & 1u)) >> 16;
  return (unsigned short)r;
}
__device__ __forceinline__ float b2f(unsigned short b) {
  return __uint_as_float((unsigned)b << 16);
}

__global__ void cvt_bf16(const float* __restrict__ s, unsigned short* __restrict__ d, int n4) {
  int i = blockIdx.x * blockDim.x + threadIdx.x;
  if (i >= n4) return;
  float4 v = ((const float4*)s)[i];
  ushort4 o;
  o.x = f2b(v.x); o.y = f2b(v.y); o.z = f2b(v.z); o.w = f2b(v.w);
  ((ushort4*)d)[i] = o;
}

// ---- GEMM core: 64x128 tile, NO-LDS streaming main loop (round-3/4 design).
template <int KT>
__device__ __forceinline__ void gemm_direct(
    const unsigned short* __restrict__ A, const int* __restrict__ rowlist,
    const unsigned short* __restrict__ W, const float* __restrict__ bias,
    float* __restrict__ Cf, unsigned short* __restrict__ Cb,
    int nrows, int mout, int act, int rowBase, int colBase) {
  constexpr int NK = KT / 32;
  __shared__ unsigned short Es[64][136];
  int t = threadIdx.x;
  int lane = t & 63, w = t >> 6;
  int wm = w >> 1, wn = w & 1;
  int q = lane >> 4, mr = lane & 15;

  const unsigned short* ap[2];
#pragma unroll
  for (int mt = 0; mt < 2; ++mt) {
    int gr = rowBase + wm * 32 + mt * 16 + mr;
    int cg = (gr < nrows) ? gr : 0;
    int ar = rowlist ? rowlist[cg] : cg;
    ap[mt] = A + (size_t)ar * KT + q * 8;
  }
  const unsigned short* wp[4];
#pragma unroll
  for (int nt = 0; nt < 4; ++nt)
    wp[nt] = W + (size_t)(colBase + wn * 64 + nt * 16 + mr) * KT + q * 8;

  f32x4 acc[2][4] = {};
#pragma unroll
  for (int k = 0; k < NK; ++k) {
    bf16x8 af[2], bfr[4];
#pragma unroll
    for (int mt = 0; mt < 2; ++mt) af[mt] = *(const bf16x8*)(ap[mt] + k * 32);
#pragma unroll
    for (int nt = 0; nt < 4; ++nt) bfr[nt] = *(const bf16x8*)(wp[nt] + k * 32);
#pragma unroll
    for (int mt = 0; mt < 2; ++mt)
#pragma unroll
      for (int nt = 0; nt < 4; ++nt)
        acc[mt][nt] = __builtin_amdgcn_mfma_f32_16x16x32_bf16(af[mt], bfr[nt], acc[mt][nt], 0, 0, 0);
  }

  float bv[4];
#pragma unroll
  for (int nt = 0; nt < 4; ++nt) bv[nt] = bias[colBase + wn * 64 + nt * 16 + mr];

  if (Cf) {
#pragma unroll
    for (int mt = 0; mt < 2; ++mt)
#pragma unroll
      for (int nt = 0; nt < 4; ++nt)
#pragma unroll
        for (int r = 0; r < 4; ++r) {
          int row = rowBase + wm * 32 + mt * 16 + q * 4 + r;
          int col = colBase + wn * 64 + nt * 16 + mr;
          if (row < nrows) {
            float v = acc[mt][nt][r] + bv[nt];
            if (act) v = v / (1.f + expf(-v));
            Cf[(size_t)row * mout + col] = v;
            if (Cb) Cb[(size_t)row * mout + col] = f2b(v);
          }
        }
  } else {
#pragma unroll
    for (int mt = 0; mt < 2; ++mt)
#pragma unroll
      for (int nt = 0; nt < 4; ++nt)
#pragma unroll
        for (int r = 0; r < 4; ++r) {
          float v = acc[mt][nt][r] + bv[nt];
          if (act) v = v / (1.f + expf(-v));
          Es[wm * 32 + mt * 16 + q * 4 + r][wn * 64 + nt * 16 + mr] = f2b(v);
        }
    __syncthreads();
    int rl = t >> 2, co = (t & 3) * 32;
    int grow = rowBase + rl;
    if (grow < nrows) {
      unsigned short* dst = Cb + (size_t)grow * mout + colBase + co;
#pragma unroll
      for (int j = 0; j < 4; ++j)
        *(bf16x8*)(dst + j * 8) = *(const bf16x8*)&Es[rl][co + j * 8];
    }
  }
}

// XCD-aware full GEMM (dispatch is round-robin over 8 XCDs: bid&7 = XCD)
template <int KT>
__global__ __launch_bounds__(256, 2) void gemm_bf16_t(
    const unsigned short* __restrict__ A, const unsigned short* __restrict__ W,
    const float* __restrict__ bias, float* __restrict__ Cf, unsigned short* __restrict__ Cb,
    int nrows, int mout, int act, int ncol) {
  int nbr = (nrows + 63) >> 6;
  int rpx = (nbr + 7) >> 3;
  int xcd = blockIdx.x & 7, j = blockIdx.x >> 3;
  int rowT = xcd * rpx + j / ncol;
  int cy = j - (j / ncol) * ncol;
  if (rowT >= nbr) return;
  gemm_direct<KT>(A, nullptr, W, bias, Cf, Cb, nrows, mout, act, rowT * 64, cy * 128);
}

// ---- merged conv GEMM: xl for all 4 rels' HOT-src lists + xr for hot-dst lists,
// one launch (solo srcs no longer staged: handled by solo_gemm).
__global__ __launch_bounds__(256, 2) void conv_xl_all(
    const unsigned short* __restrict__ hbf,
    const int* __restrict__ srclist, const int* __restrict__ hotlist,
    const int* __restrict__ cnts,  // nsrc @ [128 + r*16], nhot @ [64 + r*16]
    const unsigned short* __restrict__ Wl, const float* __restrict__ bl,
    const unsigned short* __restrict__ Wr, const float* __restrict__ br,
    unsigned short* __restrict__ xlb, unsigned short* __restrict__ xrh) {
  for (int tid = blockIdx.x;; tid += gridDim.x) {
    int rem = tid, seg = 0, nrows = 0;
    for (; seg < 8; ++seg) {
      int r = seg >> 1;
      int n = (seg & 1) ? cnts[64 + r * 16] : cnts[128 + r * 16];
      int cap = (seg & 1) ? CAPH : CAPS;
      if (n > cap) n = cap;
      int tseg = ((n + 63) >> 6) * 4;
      if (rem < tseg) { nrows = n; break; }
      rem -= tseg;
    }
    if (seg == 8) return;
    int r = seg >> 1, sel = seg & 1;
    int rt = rem >> 2, ct = rem & 3;
    const int* list = (sel ? hotlist : srclist) + r * NN;
    const unsigned short* W = (sel ? Wr : Wl) + (size_t)r * 512 * 128;
    const float* bias = (sel ? br : bl) + (size_t)r * 512;
    unsigned short* C = sel ? (xrh + (size_t)r * CAPH * 512) : (xlb + (size_t)r * CAPS * 512);
    gemm_direct<128>(hbf, list, W, bias, nullptr, C, nrows, 512, 0, rt * 64, ct * 128);
    __syncthreads();  // LDS WAR between tiles
  }
}

// ---- solo-edge GEMM: for deg-1 dsts, softmax==1 and output = g/4 * sum_h xl_h
// = g/4 * (hbf[src] @ Wsum^T + bsum). One launch over all 4 rels; scatter-adds
// straight into hmsg (atomicAdd; <=1 add per (dst,rel), base is zeroed -> 2-rel
// collisions commutatively exact, >=3-rel ulp-level vs 2e-3 tolerance).
__global__ __launch_bounds__(256, 2) void solo_gemm(
    const unsigned short* __restrict__ hbf,
    const int* __restrict__ solosrc, const int* __restrict__ solodst,
    const int* __restrict__ nsolo,
    const unsigned short* __restrict__ wsum, const float* __restrict__ bsum,
    const float* __restrict__ gate, float* __restrict__ hmsg) {
  int t = threadIdx.x, lane = t & 63, w = t >> 6;
  int wm = w >> 1, wn = w & 1, q = lane >> 4, mr = lane & 15;
  for (int tid = blockIdx.x;; tid += gridDim.x) {
    int rem = tid, r = 0, n = 0;
    for (; r < NR; ++r) {
      n = nsolo[r * 16];
      int ts = (n + 63) >> 6;
      if (rem < ts) break;
      rem -= ts;
    }
    if (r == NR) return;
    int rowBase = rem * 64;
    const unsigned short* ap[2];
#pragma unroll
    for (int mt = 0; mt < 2; ++mt) {
      int gr = rowBase + wm * 32 + mt * 16 + mr;
      int idx = (gr < n) ? solosrc[r * NN + gr] : 0;
      ap[mt] = hbf + (size_t)idx * HID + q * 8;
    }
    const unsigned short* wp[4];
#pragma unroll
    for (int nt = 0; nt < 4; ++nt)
      wp[nt] = wsum + (size_t)r * 16384 + (size_t)(wn * 64 + nt * 16 + mr) * HID + q * 8;
    f32x4 acc[2][4] = {};
#pragma unroll
    for (int k = 0; k < 4; ++k) {
      bf16x8 af[2], bfr[4];
#pragma unroll
      for (int mt = 0; mt < 2; ++mt) af[mt] = *(const bf16x8*)(ap[mt] + k * 32);
#pragma unroll
      for (int nt = 0; nt < 4; ++nt) bfr[nt] = *(const bf16x8*)(wp[nt] + k * 32);
#pragma unroll
      for (int mt = 0; mt < 2; ++mt)
#pragma unroll
        for (int nt = 0; nt < 4; ++nt)
          acc[mt][nt] = __builtin_amdgcn_mfma_f32_16x16x32_bf16(af[mt], bfr[nt], acc[mt][nt], 0, 0, 0);
    }
    float g4 = gate[r] * 0.25f;
    float bv[4];
#pragma unroll
    for (int nt = 0; nt < 4; ++nt) bv[nt] = bsum[r * 128 + wn * 64 + nt * 16 + mr];
#pragma unroll
    for (int mt = 0; mt < 2; ++mt)
#pragma unroll
      for (int rr = 0; rr < 4; ++rr) {
        int row = rowBase + wm * 32 + mt * 16 + q * 4 + rr;
        if (row < n) {
          int dst = solodst[r * NN + row];
#pragma unroll
          for (int nt = 0; nt < 4; ++nt) {
            int col = wn * 64 + nt * 16 + mr;
            atomicAdd(&hmsg[(size_t)dst * HID + col], g4 * (acc[mt][nt][rr] + bv[nt]));
          }
        }
      }
  }
}

// head-summed lin_l weights/bias per (layer,rel): Wsum[o][k] = sum_h Wl[h*128+o][k]
__global__ void wsum_build(const float* __restrict__ linlw, const float* __restrict__ linlb,
                           unsigned short* __restrict__ wsum, float* __restrict__ bsum) {
  int i = blockIdx.x * blockDim.x + threadIdx.x;
  if (i >= NL * NR * 128 * 128) return;
  int k = i & 127, o = (i >> 7) & 127, lr = i >> 14;
  float s = 0.f;
#pragma unroll
  for (int h = 0; h < NH; ++h) s += linlw[((size_t)lr * 512 + h * 128 + o) * 128 + k];
  wsum[i] = f2b(s);
  if (k == 0) {
    float b = 0.f;
#pragma unroll
    for (int h = 0; h < NH; ++h) b += linlb[(size_t)lr * 512 + h * 128 + o];
    bsum[lr * 128 + o] = b;
  }
}

// ---- layer tail: LN1(h+hmsg+cb) -> y; f1=silu(y@W1^T+b1); f2=f1@W2^T+b2;
// h=LN2(y+f2); emits hbf (post-LN2).
__global__ __launch_bounds__(256, 2) void layer_tail(
    float* __restrict__ h, const float* __restrict__ hmsg, const float* __restrict__ cb,
    const float* __restrict__ n1w, const float* __restrict__ n1b,
    const unsigned short* __restrict__ W1, const float* __restrict__ b1,
    const unsigned short* __restrict__ W2, const float* __restrict__ b2,
    const float* __restrict__ n2w, const float* __restrict__ n2b,
    unsigned short* __restrict__ hbfout) {
  __shared__ __align__(16) char smem[64 * 136 * 2 + 64 * 264 * 2];
  unsigned short (*Y)[136] = (unsigned short (*)[136])smem;
  unsigned short (*F1)[264] = (unsigned short (*)[264])(smem + 64 * 136 * 2);
  float (*Ef)[132] = (float (*)[132])(smem + 64 * 136 * 2);
  int nbr = (NN + 63) >> 6;
  int rpx = (nbr + 7) >> 3;
  int xcd = blockIdx.x & 7, j = blockIdx.x >> 3;
  int rowT = xcd * rpx + j;
  if (rowT >= nbr) return;
  int rowBase = rowT * 64;

  int t = threadIdx.x;
  int lane = t & 63, w = t >> 6;
  int wm = w >> 1, wn = w & 1;
  int q = lane >> 4, mr = lane & 15;

  // ---- phase 0: LN1 over own 64 rows (wave-per-row)
  {
    float w0 = n1w[lane], w1 = n1w[64 + lane];
    float bb0 = n1b[lane], bb1 = n1b[64 + lane];
    float c0 = cb[lane], c1 = cb[64 + lane];
    for (int rr = w; rr < 64; rr += 4) {
      int grow = rowBase + rr;
      if (grow < NN) {
        size_t base = (size_t)grow * HID;
        float x0 = h[base + lane] + hmsg[base + lane] + c0;
        float x1 = h[base + 64 + lane] + hmsg[base + 64 + lane] + c1;
        float s = x0 + x1;
#pragma unroll
        for (int o = 32; o > 0; o >>= 1) s += __shfl_xor(s, o, 64);
        float mean = s * (1.f / 128.f);
        float d0 = x0 - mean, d1 = x1 - mean;
        float v = d0 * d0 + d1 * d1;
#pragma unroll
        for (int o = 32; o > 0; o >>= 1) v += __shfl_xor(v, o, 64);
        float inv = 1.f / sqrtf(v * (1.f / 128.f) + 1e-5f);
        float y0 = d0 * inv * w0 + bb0;
        float y1 = d1 * inv * w1 + bb1;
        h[base + lane] = y0;
        h[base + 64 + lane] = y1;
        Y[rr][lane] = f2b(y0);
        Y[rr][64 + lane] = f2b(y1);
      } else {
        Y[rr][lane] = 0;
        Y[rr][64 + lane] = 0;
      }
    }
  }
  __syncthreads();

  // ---- phase A: f1 = silu(y @ W1^T + b1), A-frags from Y LDS
  bf16x8 a[2][4];
#pragma unroll
  for (int mt = 0; mt < 2; ++mt)
#pragma unroll
    for (int k = 0; k < 4; ++k)
      a[mt][k] = *(const bf16x8*)&Y[wm * 32 + mt * 16 + mr][k * 32 + q * 8];

#pragma unroll
  for (int ph = 0; ph < 2; ++ph) {
    const unsigned short* wp[4];
#pragma unroll
    for (int nt = 0; nt < 4; ++nt)
      wp[nt] = W1 + (size_t)(ph * 128 + wn * 64 + nt * 16 + mr) * HID + q * 8;
    f32x4 acc[2][4] = {};
#pragma unroll
    for (int k = 0; k < 4; ++k) {
      bf16x8 bfr[4];
#pragma unroll
      for (int nt = 0; nt < 4; ++nt) bfr[nt] = *(const bf16x8*)(wp[nt] + k * 32);
#pragma unroll
      for (int mt = 0; mt < 2; ++mt)
#pragma unroll
        for (int nt = 0; nt < 4; ++nt)
          acc[mt][nt] = __builtin_amdgcn_mfma_f32_16x16x32_bf16(a[mt][k], bfr[nt], acc[mt][nt], 0, 0, 0);
    }
    float bv[4];
#pragma unroll
    for (int nt = 0; nt < 4; ++nt) bv[nt] = b1[ph * 128 + wn * 64 + nt * 16 + mr];
#pragma unroll
    for (int mt = 0; mt < 2; ++mt)
#pragma unroll
      for (int nt = 0; nt < 4; ++nt)
#pragma unroll
        for (int r = 0; r < 4; ++r) {
          float v = acc[mt][nt][r] + bv[nt];
          v = v / (1.f + expf(-v));
          F1[wm * 32 + mt * 16 + q * 4 + r][ph * 128 + wn * 64 + nt * 16 + mr] = f2b(v);
        }
  }
  __syncthreads();

  // ---- phase B: f2 = f1 @ W2^T (K=256), A from LDS, W2 from L2
  const unsigned short* wp2[4];
#pragma unroll
  for (int nt = 0; nt < 4; ++nt)
    wp2[nt] = W2 + (size_t)(wn * 64 + nt * 16 + mr) * FFH + q * 8;
  f32x4 acc2[2][4] = {};
#pragma unroll
  for (int k = 0; k < 8; ++k) {
    bf16x8 af[2], bfr[4];
#pragma unroll
    for (int mt = 0; mt < 2; ++mt)
      af[mt] = *(const bf16x8*)&F1[wm * 32 + mt * 16 + mr][k * 32 + q * 8];
#pragma unroll
    for (int nt = 0; nt < 4; ++nt) bfr[nt] = *(const bf16x8*)(wp2[nt] + k * 32);
#pragma unroll
    for (int mt = 0; mt < 2; ++mt)
#pragma unroll
      for (int nt = 0; nt < 4; ++nt)
        acc2[mt][nt] = __builtin_amdgcn_mfma_f32_16x16x32_bf16(af[mt], bfr[nt], acc2[mt][nt], 0, 0, 0);
  }
  __syncthreads();  // all F1 reads done before overwriting as Ef

  // ---- phase C: stage f2+b2 in LDS (f32), then LN2(y + f2) -> h, hbf
  float bv2[4];
#pragma unroll
  for (int nt = 0; nt < 4; ++nt) bv2[nt] = b2[wn * 64 + nt * 16 + mr];
#pragma unroll
  for (int mt = 0; mt < 2; ++mt)
#pragma unroll
    for (int nt = 0; nt < 4; ++nt)
#pragma unroll
      for (int r = 0; r < 4; ++r)
        Ef[wm * 32 + mt * 16 + q * 4 + r][wn * 64 + nt * 16 + mr] = acc2[mt][nt][r] + bv2[nt];
  __syncthreads();

  float w0 = n2w[lane], w1 = n2w[64 + lane];
  float bb0 = n2b[lane], bb1 = n2b[64 + lane];
  for (int rr = w; rr < 64; rr += 4) {
    int grow = rowBase + rr;
    if (grow >= NN) continue;
    size_t base = (size_t)grow * HID;
    float x0 = h[base + lane] + Ef[rr][lane];          // h holds y (phase 0), L2-hot
    float x1 = h[base + 64 + lane] + Ef[rr][64 + lane];
    float s = x0 + x1;
#pragma unroll
    for (int o = 32; o > 0; o >>= 1) s += __shfl_xor(s, o, 64);
    float mean = s * (1.f / 128.f);
    float d0 = x0 - mean, d1 = x1 - mean;
    float v = d0 * d0 + d1 * d1;
#pragma unroll
    for (int o = 32; o > 0; o >>= 1) v += __shfl_xor(v, o, 64);
    float inv = 1.f / sqrtf(v * (1.f / 128.f) + 1e-5f);
    float y0 = d0 * inv * w0 + bb0;
    float y1 = d1 * inv * w1 + bb1;
    h[base + lane] = y0;
    h[base + 64 + lane] = y1;
    hbfout[base + lane] = f2b(y0);
    hbfout[base + 64 + lane] = f2b(y1);
  }
}

__global__ void build_xin_bf(const float* __restrict__ x, const int* __restrict__ idtok,
                             const float* __restrict__ emb, unsigned short* __restrict__ xin) {
  int i = blockIdx.x * blockDim.x + threadIdx.x;
  if (i >= NN * 96) return;
  int n = i / 96, k = i - n * 96;
  float v = (k < FN) ? x[(size_t)n * FN + k] : emb[(size_t)idtok[n] * IDE + (k - FN)];
  xin[i] = f2b(v);
}

// ---- CSR by (rel, dst) ----
__global__ void hist_bin(const int* __restrict__ ei, const int* __restrict__ et,
                         int* __restrict__ bcnt) {
  int e = blockIdx.x * blockDim.x + threadIdx.x;
  if (e >= NE) return;
  atomicAdd(&bcnt[et[e] * NN + ei[NE + e]], 1);
}
__global__ __launch_bounds__(256) void scan1(const int* __restrict__ cnt,
                                             int* __restrict__ pos, int* __restrict__ bsum) {
  __shared__ int lds[256];
  int b = blockIdx.x, t = threadIdx.x;
  int base = b * 1024 + t * 4;
  int v[4];
#pragma unroll
  for (int j = 0; j < 4; ++j) v[j] = (base + j < NBIN) ? cnt[base + j] : 0;
  int tot = v[0] + v[1] + v[2] + v[3];
  lds[t] = tot;
  __syncthreads();
  for (int off = 1; off < 256; off <<= 1) {
    int x = (t >= off) ? lds[t - off] : 0;
    __syncthreads();
    lds[t] += x;
    __syncthreads();
  }
  if (t == 255) bsum[b] = lds[255];
  int run = lds[t] - tot;
#pragma unroll
  for (int j = 0; j < 4; ++j) {
    if (base + j < NBIN) pos[base + j] = run;
    run += v[j];
  }
}
__global__ __launch_bounds__(256) void scan2(int* __restrict__ bsum) {
  __shared__ int lds[256];
  int t = threadIdx.x;
  int v = (t < SCAN_BLK) ? bsum[t] : 0;
  lds[t] = v;
  __syncthreads();
  for (int off = 1; off < 256; off <<= 1) {
    int x = (t >= off) ? lds[t - off] : 0;
    __syncthreads();
    lds[t] += x;
    __syncthreads();
  }
  if (t < SCAN_BLK) bsum[t] = lds[t] - v;
}
__global__ void scan3(int* __restrict__ pos, const int* __restrict__ bsum,
                      const int* __restrict__ cnt) {
  int i = blockIdx.x * blockDim.x + threadIdx.x;
  if (i >= NBIN) return;
  pos[i] += bsum[i >> 10];
  if (i == NBIN - 1) pos[NBIN] = pos[i] + cnt[i];
}
__global__ void scatter_bin(const int* __restrict__ ei, const int* __restrict__ et,
                            const int* __restrict__ csroff, int* __restrict__ cur,
                            int* __restrict__ elist) {
  int e = blockIdx.x * blockDim.x + threadIdx.x;
  if (e >= NE) return;
  int bin = et[e] * NN + ei[NE + e];
  int p = atomicAdd(&cur[bin], 1);
  elist[csroff[bin] + p] = e;
}
// DETERMINISM: atomic scatter order varies call-to-call; sort each bin.
__global__ void sort_bins(const int* __restrict__ csroff, int* __restrict__ elist) {
  int b = blockIdx.x * blockDim.x + threadIdx.x;
  if (b >= NBIN) return;
  int s = csroff[b], e = csroff[b + 1];
  for (int i = s + 1; i < e; ++i) {
    int key = elist[i];
    int j = i - 1;
    while (j >= s && elist[j] > key) { elist[j + 1] = elist[j]; --j; }
    elist[j + 1] = key;
  }
}
__global__ void gather_edge(const int* __restrict__ ei, const int* __restrict__ elist,
                            const float* __restrict__ eattr,
                            int* __restrict__ rsrc, float* __restrict__ eacsr) {
  int p = blockIdx.x * blockDim.x + threadIdx.x;
  if (p >= NE) return;
  int e = elist[p];
  rsrc[p] = ei[e];
  const float4* s = (const float4*)(eattr + (size_t)e * NEA);
  float4* d = (float4*)(eacsr + (size_t)p * NEA);
#pragma unroll
  for (int j = 0; j < 4; ++j) d[j] = s[j];
}
// flag srcs that appear in deg>=2 (hot) bins: only these need per-head xl staging
__global__ void mark_hotsrc(const int* __restrict__ csroff, const int* __restrict__ rsrc,
                            int* __restrict__ srcflag) {
  int b = blockIdx.x * blockDim.x + threadIdx.x;
  if (b >= NBIN) return;
  int s = csroff[b], e = csroff[b + 1];
  if (e - s < 2) return;
  int rel = b / NN;
  for (int p = s; p < e; ++p) srcflag[rel * NN + rsrc[p]] = 1;
}
// ORDERED hot-src compaction from scan positions (deterministic + sequential gather)
__global__ void build_src_o(const int* __restrict__ srcflag, const int* __restrict__ srcpos,
                            int* __restrict__ srclist, int* __restrict__ srcmap) {
  int b = blockIdx.x * blockDim.x + threadIdx.x;
  if (b >= NBIN) return;
  if (srcflag[b]) {
    int rel = b / NN;
    int pos = srcpos[b] - srcpos[rel * NN];
    srcmap[b] = pos;
    srclist[rel * NN + pos] = b - rel * NN;
  }
}
__global__ void fincnt(const int* __restrict__ srcpos, int* __restrict__ nsrc) {
  int r = threadIdx.x;
  if (r < NR) nsrc[r * 16] = srcpos[(r + 1) * NN] - srcpos[r * NN];
}
// rsrcx: hot-src row index per edge position (garbage for solo positions, unread)
__global__ void remap_rsrc(const int* __restrict__ csroff, const int* __restrict__ rsrc,
                           const int* __restrict__ srcmap, int* __restrict__ rsrcx) {
  int p = blockIdx.x * blockDim.x + threadIdx.x;
  if (p >= NE) return;
  int rel = (p >= csroff[NN]) + (p >= csroff[2 * NN]) + (p >= csroff[3 * NN]);
  rsrcx[p] = srcmap[rel * NN + rsrc[p]];
}
// per-rel solo (deg==1: ORIGINAL src id + dst) + hot (deg>=2) lists.
__global__ __launch_bounds__(256) void build_hot(
    const int* __restrict__ csroff, const int* __restrict__ rsrc,
    int* __restrict__ nsolo, int* __restrict__ nhot,
    int* __restrict__ solosrc, int* __restrict__ solodst, int* __restrict__ hotlist) {
  __shared__ int wsc[4][4], whc[4][4];
  __shared__ int sbase[4], hbase[4];
  int t = threadIdx.x, wave = t >> 6, lane = t & 63;
  int b = blockIdx.x * 256 + t;
  bool valid = b < NBIN;
  int cnt = 0, rel = 0, s = 0;
  if (valid) { s = csroff[b]; cnt = csroff[b + 1] - s; rel = b / NN; }
  bool solo = valid && cnt == 1;
  bool hot = valid && cnt >= 2;
#pragma unroll
  for (int rr = 0; rr < 4; ++rr) {
    unsigned long long ms = __ballot(solo && rel == rr);
    unsigned long long mh = __ballot(hot && rel == rr);
    if (lane == 0) { wsc[wave][rr] = __popcll(ms); whc[wave][rr] = __popcll(mh); }
  }
  __syncthreads();
  if (t < 4) {
    int ssum = wsc[0][t] + wsc[1][t] + wsc[2][t] + wsc[3][t];
    int hsum = whc[0][t] + whc[1][t] + whc[2][t] + whc[3][t];
    sbase[t] = ssum ? atomicAdd(&nsolo[t * 16], ssum) : 0;
    hbase[t] = hsum ? atomicAdd(&nhot[t * 16], hsum) : 0;
  }
  __syncthreads();
#pragma unroll
  for (int rr = 0; rr < 4; ++rr) {
    unsigned long long ms = __ballot(solo && rel == rr);
    if (solo && rel == rr) {
      int before = 0;
#pragma unroll
      for (int wv = 0; wv < 4; ++wv) if (wv < wave) before += wsc[wv][rr];
      int pos = sbase[rr] + before + __popcll(ms & ((1ull << lane) - 1ull));
      solosrc[rr * NN + pos] = rsrc[s];
      solodst[rr * NN + pos] = b - rr * NN;
    }
    unsigned long long mh = __ballot(hot && rel == rr);
    if (hot && rel == rr) {
      int before = 0;
#pragma unroll
      for (int wv = 0; wv < 4; ++wv) if (wv < wave) before += whc[wv][rr];
      int pos = hbase[rr] + before + __popcll(mh & ((1ull << lane) - 1ull));
      hotlist[rr * NN + pos] = b - rr * NN;
    }
  }
}

// all-layers gate softmax + gated conv bias in one launch (block = layer)
__global__ void gate_cb_all(const float* __restrict__ rg, const float* __restrict__ cbias,
                            float* __restrict__ gate, float* __restrict__ cb) {
  __shared__ float g[NR];
  int l = blockIdx.x, t = threadIdx.x;
  const float* rgl = rg + l * NR;
  if (t == 0) {
    float mx = rgl[0];
    for (int r = 1; r < NR; ++r) mx = fmaxf(mx, rgl[r]);
    float s = 0.f, tmp[NR];
    for (int r = 0; r < NR; ++r) { tmp[r] = expf(rgl[r] - mx); s += tmp[r]; }
    for (int r = 0; r < NR; ++r) { g[r] = tmp[r] / s; gate[l * NR + r] = g[r]; }
  }
  __syncthreads();
  float c = 0.f;
  for (int r = 0; r < NR; ++r) c += g[r] * cbias[(size_t)l * NR * HID + r * HID + t];
  cb[l * HID + t] = c;
}

// ---- hot-only edge pass: block/dst, online softmax (solo handled by solo_gemm)
__global__ __launch_bounds__(256) void edge_all(
    const int* __restrict__ csroff, const int* __restrict__ rsrcx,
    const float* __restrict__ eacsr, const float* __restrict__ relembp,
    const float* __restrict__ wedgep, const float* __restrict__ attwp,
    const unsigned short* __restrict__ xlb, const unsigned short* __restrict__ xrh,
    const int* __restrict__ hotlist, const int* __restrict__ nhot,
    float* __restrict__ hmsg, const float* __restrict__ gate, int rel) {
  __shared__ float lds[4][128];
  int wave = threadIdx.x >> 6, lane = threadIdx.x & 63;
  float g4 = gate[rel] * 0.25f;
  int hh = wave;
  float wreg[2][24], areg[2];
#pragma unroll
  for (int j = 0; j < 2; ++j) {
    int col = hh * 128 + j * 64 + lane;
    const float* wp = wedgep + (size_t)col * 24;
#pragma unroll
    for (int k = 0; k < 24; ++k) wreg[j][k] = wp[k];
    areg[j] = attwp[col];
  }
  float evr0 = 0.f, evr1 = 0.f;
#pragma unroll
  for (int k = 0; k < 8; ++k) {
    float rk = relembp[k];
    evr0 += rk * wreg[0][NEA + k];
    evr1 += rk * wreg[1][NEA + k];
  }
  int nh = nhot[rel * 16];
  for (int wi = blockIdx.x; wi < nh; wi += gridDim.x) {
    int dst = hotlist[rel * NN + wi];
    int s = csroff[rel * NN + dst], e = csroff[rel * NN + dst + 1];
    {
      const unsigned short* xrp = xrh + (size_t)wi * 512;
      float xr0 = b2f(xrp[hh * 128 + lane]);
      float xr1 = b2f(xrp[hh * 128 + 64 + lane]);
      float m = -3.4e38f, den = 0.f, acc0 = 0.f, acc1 = 0.f;
      for (int p = s; p < e; ++p) {
        int src = rsrcx[p];
        const float* eap = eacsr + (size_t)p * NEA;
        float eev0 = evr0, eev1 = evr1;
#pragma unroll
        for (int k = 0; k < NEA; ++k) {
          float er = eap[k];
          eev0 += er * wreg[0][k];
          eev1 += er * wreg[1][k];
        }
        float xl0 = b2f(xlb[(size_t)src * 512 + hh * 128 + lane]);
        float xl1 = b2f(xlb[(size_t)src * 512 + hh * 128 + 64 + lane]);
        float s0 = xl0 + xr0 + eev0; s0 = (s0 > 0.f) ? s0 : 0.2f * s0;
        float s1 = xl1 + xr1 + eev1; s1 = (s1 > 0.f) ? s1 : 0.2f * s1;
        float lg = s0 * areg[0] + s1 * areg[1];
#pragma unroll
        for (int o = 32; o > 0; o >>= 1) lg += __shfl_xor(lg, o, 64);
        float mn = fmaxf(m, lg);
        float sc = expf(m - mn);
        float ex = expf(lg - mn);
        den = den * sc + ex;
        acc0 = acc0 * sc + ex * xl0;
        acc1 = acc1 * sc + ex * xl1;
        m = mn;
      }
      float wgt = g4 / den;
      lds[wave][lane] = acc0 * wgt;
      lds[wave][64 + lane] = acc1 * wgt;
    }
    __syncthreads();
    if (wave < 2) {
      int d = wave * 64 + lane;
      float v = lds[0][d] + lds[1][d] + lds[2][d] + lds[3][d];
      hmsg[(size_t)dst * HID + d] += v;
    }
    __syncthreads();
  }
}

// ---- readout: deterministic ----
__global__ void group_bounds(const int* __restrict__ batch, int* __restrict__ gstart) {
  int g = threadIdx.x + blockIdx.x * blockDim.x;
  if (g > NG) return;
  int lo = 0, hi = NN;
  while (lo < hi) {
    int mid = (lo + hi) >> 1;
    if (batch[mid] < g) lo = mid + 1; else hi = mid;
  }
  gstart[g] = lo;
}
__global__ __launch_bounds__(128) void readout_part2(
    const float* __restrict__ h, const int* __restrict__ gstart,
    float* __restrict__ psum, float* __restrict__ pmax) {
  int g = blockIdx.x, s = blockIdx.y, t = threadIdx.x;
  int r0 = gstart[g], r1 = gstart[g + 1];
  float acc = 0.f, mx = -3.4e38f;
  for (int row = r0 + s; row < r1; row += 8) {
    float v = h[(size_t)row * HID + t];
    acc += v;
    mx = fmaxf(mx, v);
  }
  psum[((size_t)g * 8 + s) * HID + t] = acc;
  pmax[((size_t)g * 8 + s) * HID + t] = mx;
}
__global__ __launch_bounds__(256) void readout_final(
    const int* __restrict__ gstart, const float* __restrict__ psum,
    const float* __restrict__ pmax, const float* __restrict__ w,
    const float* __restrict__ b, float* __restrict__ g) {
  int bg = blockIdx.x, t = threadIdx.x;
  __shared__ float red[256];
  float c = fmaxf((float)(gstart[bg + 1] - gstart[bg]), 1.f);
  float x;
  if (t < HID) {
    float ssum = 0.f;
    for (int s = 0; s < 8; ++s) ssum += psum[((size_t)bg * 8 + s) * HID + t];
    x = ssum / c;
  } else {
    float mx = -3.4e38f;
    for (int s = 0; s < 8; ++s) mx = fmaxf(mx, pmax[((size_t)bg * 8 + s) * HID + (t - HID)]);
    x = mx;
  }
  red[t] = x;
  __syncthreads();
  for (int s = 128; s > 0; s >>= 1) {
    if (t < s) red[t] += red[t + s];
    __syncthreads();
  }
  float mean = red[0] * (1.f / 256.f);
  __syncthreads();
  float d = x - mean;
  red[t] = d * d;
  __syncthreads();
  for (int s = 128; s > 0; s >>= 1) {
    if (t < s) red[t] += red[t + s];
    __syncthreads();
  }
  float inv = 1.f / sqrtf(red[0] * (1.f / 256.f) + 1e-5f);
  g[(size_t)bg * 256 + t] = d * inv * w[t] + b[t];
}

__device__ __forceinline__ void bspline8(float x, const float* __restrict__ t,
                                         float* __restrict__ out) {
  float bs[11];
#pragma unroll
  for (int j = 0; j < 11; ++j) bs[j] = (x >= t[j] && x < t[j + 1]) ? 1.f : 0.f;
#pragma unroll
  for (int k = 1; k <= 3; ++k) {
    for (int j = 0; j < 11 - k; ++j) {
      bs[j] = (x - t[j]) / (t[j + k] - t[j]) * bs[j] +
              (t[j + k + 1] - x) / (t[j + k + 1] - t[j + 1]) * bs[j + 1];
    }
  }
#pragma unroll
  for (int j = 0; j < 8; ++j) out[j] = bs[j];
}

// ---- KAN1, K-chunked into fixed partial slots (deterministic) ----
__global__ __launch_bounds__(128) void kan1_part(
    const float* __restrict__ g, const float* __restrict__ bw,
    const float* __restrict__ sw, const float* __restrict__ sc,
    const float* __restrict__ grid, float* __restrict__ zpart) {
  int bg = blockIdx.x, ch = blockIdx.y, t = threadIdx.x;
  int base = ch * 32;
  __shared__ float B[32][8];
  __shared__ float sg[32];
  if (t < 32) {
    float x = g[(size_t)bg * 256 + base + t];
    sg[t] = x / (1.f + expf(-x));
    bspline8(x, grid + (size_t)(base + t) * 12, B[t]);
  }
  __syncthreads();
  float acc = 0.f;
  for (int i = 0; i < 32; ++i) {
    int col = base + i;
    acc += sg[i] * bw[(size_t)t * 256 + col];
    const float* swp = sw + ((size_t)t * 256 + col) * 8;
    float sp = 0.f;
#pragma unroll
    for (int k = 0; k < 8; ++k) sp += B[i][k] * swp[k];
    acc += sp * sc[(size_t)t * 256 + col];
  }
  zpart[((size_t)ch * NG + bg) * KH + t] = acc;
}

__global__ __launch_bounds__(128) void kan2(
    const float* __restrict__ zpart, const float* __restrict__ bw,
    const float* __restrict__ sw, const float* __restrict__ sc,
    const float* __restrict__ grid, float* __restrict__ out) {
  int bg = blockIdx.x, t = threadIdx.x;
  __shared__ float B[128][8];
  __shared__ float sz[128];
  float x = 0.f;
  for (int ch = 0; ch < 8; ++ch) x += zpart[((size_t)ch * NG + bg) * KH + t];
  sz[t] = x / (1.f + expf(-x));
  bspline8(x, grid + (size_t)t * 12, B[t]);
  __syncthreads();
  if (t < NC) {
    float acc = 0.f;
    for (int i = 0; i < 128; ++i) {
      acc += sz[i] * bw[(size_t)t * 128 + i];
      const float* swp = sw + ((size_t)t * 128 + i) * 8;
      float sp = 0.f;
#pragma unroll
      for (int k = 0; k < 8; ++k) sp += B[i][k] * swp[k];
      acc += sp * sc[(size_t)t * 128 + i];
    }
    out[(size_t)bg * NC + t] = acc;
  }
}

extern "C" void kernel_launch(void* const* d_in, const int* in_sizes, int n_in,
                              void* d_out, int out_size, void* d_ws, size_t ws_size,
                              hipStream_t stream) {
  const float* x       = (const float*)d_in[0];
  const float* eattr   = (const float*)d_in[1];
  const int*   idtok   = (const int*)d_in[2];
  const int*   ei      = (const int*)d_in[3];
  const int*   etype   = (const int*)d_in[4];
  const int*   batch   = (const int*)d_in[5];
  const float* idemb   = (const float*)d_in[6];
  const float* inw     = (const float*)d_in[7];
  const float* inb     = (const float*)d_in[8];
  const float* relemb  = (const float*)d_in[9];
  const float* linlw   = (const float*)d_in[10];
  const float* linlb   = (const float*)d_in[11];
  const float* linrw   = (const float*)d_in[12];
  const float* linrb   = (const float*)d_in[13];
  const float* linew   = (const float*)d_in[14];
  const float* attw    = (const float*)d_in[15];
  const float* convb   = (const float*)d_in[16];
  const float* relgate = (const float*)d_in[17];
  const float* n1w     = (const float*)d_in[18];
  const float* n1b     = (const float*)d_in[19];
  const float* n2w     = (const float*)d_in[20];
  const float* n2b     = (const float*)d_in[21];
  const float* f1w     = (const float*)d_in[22];
  const float* f1bias  = (const float*)d_in[23];
  const float* f2w     = (const float*)d_in[24];
  const float* f2bias  = (const float*)d_in[25];
  const float* rnw     = (const float*)d_in[26];
  const float* rnb     = (const float*)d_in[27];
  const float* bw1     = (const float*)d_in[28];
  const float* sw1     = (const float*)d_in[29];
  const float* sc1     = (const float*)d_in[30];
  const float* grid1   = (const float*)d_in[31];
  const float* bw2     = (const float*)d_in[32];
  const float* sw2     = (const float*)d_in[33];
  const float* sc2     = (const float*)d_in[34];
  const float* grid2   = (const float*)d_in[35];
  float* out = (float*)d_out;
  (void)in_sizes; (void)n_in; (void)out_size; (void)ws_size;

  char* p = (char*)d_ws;
  auto alloc = [&](size_t bytes) { void* q = (void*)p; p += (bytes + 255) & ~(size_t)255; return q; };
  float* h    = (float*)alloc((size_t)NN * HID * 4);
  float* hmsg = (float*)alloc((size_t)NN * HID * 4);
  unsigned short* hbf = (unsigned short*)alloc((size_t)NN * HID * 2);
  unsigned short* xlb = (unsigned short*)alloc((size_t)NR * CAPS * 512 * 2);  // 134.2MB
  unsigned short* xrh = (unsigned short*)alloc((size_t)NR * CAPH * 512 * 2);  // 37.7MB
  int* elist = (int*)alloc((size_t)NE * 4);
  int* rsrc  = (int*)alloc((size_t)NE * 4);
  int* rsrcx = (int*)alloc((size_t)NE * 4);
  float* eacsr = (float*)alloc((size_t)NE * NEA * 4);
  int* bcnt  = (int*)alloc((size_t)NBIN * 8 + 8);
  int* cur   = bcnt + NBIN;
  int* csroff = (int*)alloc((size_t)(NBIN + 1) * 4);
  int* srcpos = (int*)alloc((size_t)(NBIN + 1) * 4);
  int* bsum  = (int*)alloc((size_t)SCAN_BLK * 4);
  int* hotlist = (int*)alloc((size_t)NR * NN * 4);
  int* solosrc = (int*)alloc((size_t)NR * NN * 4);
  int* solodst = (int*)alloc((size_t)NR * NN * 4);
  int* srclist = (int*)alloc((size_t)NR * NN * 4);
  int* srcflag = (int*)alloc((size_t)NBIN * 4);
  int* srcmap  = (int*)alloc((size_t)NBIN * 4);
  int* cnts    = (int*)alloc(1024);
  int* nsolo   = cnts;
  int* nhot    = cnts + 64;
  int* nsrc    = cnts + 128;
  unsigned short* linlwb = (unsigned short*)alloc((size_t)NL * NR * 512 * 128 * 2);
  unsigned short* linrwb = (unsigned short*)alloc((size_t)NL * NR * 512 * 128 * 2);
  unsigned short* f1wb   = (unsigned short*)alloc((size_t)NL * 256 * 128 * 2);
  unsigned short* f2wb   = (unsigned short*)alloc((size_t)NL * 128 * 256 * 2);
  unsigned short* inwb   = (unsigned short*)alloc((size_t)128 * 96 * 2);
  unsigned short* wsumb  = (unsigned short*)alloc((size_t)NL * NR * 128 * 128 * 2);
  float* bsumf = (float*)alloc((size_t)NL * NR * 128 * 4);
  float* gate = (float*)alloc(NL * NR * 4);
  float* cb   = (float*)alloc(NL * HID * 4);
  int* gstart = (int*)alloc((size_t)(NG + 1) * 4);
  float* psum = (float*)alloc((size_t)NG * 8 * HID * 4);
  float* pmax = (float*)alloc((size_t)NG * 8 * HID * 4);
  float* zpart = (float*)alloc((size_t)8 * NG * KH * 4);
  float* g = (float*)alloc((size_t)NG * 256 * 4);
  unsigned short* xinbf = xlb;  // aliased: in-proj input staged before layer loop

  const int NB64 = (NN + 63) / 64;
  const int RPX = (NB64 + 7) / 8;

  {
    int n;
    n = NL * NR * 512 * 128 / 4;
    cvt_bf16<<<(n + 255) / 256, 256, 0, stream>>>(linlw, linlwb, n);
    cvt_bf16<<<(n + 255) / 256, 256, 0, stream>>>(linrw, linrwb, n);
    n = NL * 256 * 128 / 4;
    cvt_bf16<<<(n + 255) / 256, 256, 0, stream>>>(f1w, f1wb, n);
    cvt_bf16<<<(n + 255) / 256, 256, 0, stream>>>(f2w, f2wb, n);
    n = 128 * 96 / 4;
    cvt_bf16<<<(n + 255) / 256, 256, 0, stream>>>(inw, inwb, n);
  }
  wsum_build<<<(NL * NR * 128 * 128 + 255) / 256, 256, 0, stream>>>(linlw, linlb, wsumb, bsumf);

  hipMemsetAsync(bcnt, 0, (size_t)NBIN * 8 + 8, stream);
  hipMemsetAsync(srcflag, 0, (size_t)NBIN * 4, stream);
  hipMemsetAsync(cnts, 0, 1024, stream);
  hist_bin<<<(NE + 255) / 256, 256, 0, stream>>>(ei, etype, bcnt);
  scan1<<<SCAN_BLK, 256, 0, stream>>>(bcnt, csroff, bsum);
  scan2<<<1, 256, 0, stream>>>(bsum);
  scan3<<<(NBIN + 255) / 256, 256, 0, stream>>>(csroff, bsum, bcnt);
  scatter_bin<<<(NE + 255) / 256, 256, 0, stream>>>(ei, etype, csroff, cur, elist);
  sort_bins<<<(NBIN + 255) / 256, 256, 0, stream>>>(csroff, elist);
  gather_edge<<<(NE + 255) / 256, 256, 0, stream>>>(ei, elist, eattr, rsrc, eacsr);
  mark_hotsrc<<<(NBIN + 255) / 256, 256, 0, stream>>>(csroff, rsrc, srcflag);
  scan1<<<SCAN_BLK, 256, 0, stream>>>(srcflag, srcpos, bsum);
  scan2<<<1, 256, 0, stream>>>(bsum);
  scan3<<<(NBIN + 255) / 256, 256, 0, stream>>>(srcpos, bsum, srcflag);
  build_src_o<<<(NBIN + 255) / 256, 256, 0, stream>>>(srcflag, srcpos, srclist, srcmap);
  fincnt<<<1, 64, 0, stream>>>(srcpos, nsrc);
  remap_rsrc<<<(NE + 255) / 256, 256, 0, stream>>>(csroff, rsrc, srcmap, rsrcx);
  build_hot<<<(NBIN + 255) / 256, 256, 0, stream>>>(csroff, rsrc, nsolo, nhot,
                                                    solosrc, solodst, hotlist);
  gate_cb_all<<<NL, 128, 0, stream>>>(relgate, convb, gate, cb);

  build_xin_bf<<<(NN * 96 + 255) / 256, 256, 0, stream>>>(x, idtok, idemb, xinbf);
  gemm_bf16_t<96><<<8 * RPX, 256, 0, stream>>>(xinbf, inwb, inb, h, hbf, NN, 128, 1, 1);

  for (int l = 0; l < NL; ++l) {
    hipMemsetAsync(hmsg, 0, (size_t)NN * HID * 4, stream);
    solo_gemm<<<2048, 256, 0, stream>>>(
        hbf, solosrc, solodst, nsolo,
        wsumb + (size_t)l * NR * 16384, bsumf + (size_t)l * NR * 128,
        gate + l * NR, hmsg);
    conv_xl_all<<<4096, 256, 0, stream>>>(
        hbf, srclist, hotlist, cnts,
        linlwb + (size_t)l * NR * 512 * 128, linlb + (size_t)l * NR * 512,
        linrwb + (size_t)l * NR * 512 * 128, linrb + (size_t)l * NR * 512,
        xlb, xrh);
    for (int r = 0; r < NR; ++r) {
      int lr = l * NR + r;
      edge_all<<<4096, 256, 0, stream>>>(
          csroff, rsrcx, eacsr, relemb + (size_t)lr * RED,
          linew + (size_t)lr * 512 * 24,
          attw + (size_t)lr * 512,
          xlb + (size_t)r * CAPS * 512, xrh + (size_t)r * CAPH * 512,
          hotlist, nhot, hmsg, gate + l * NR, r);
    }
    layer_tail<<<8 * RPX, 256, 0, stream>>>(
        h, hmsg, cb + l * HID, n1w + l * HID, n1b + l * HID,
        f1wb + (size_t)l * 256 * 128, f1bias + (size_t)l * 256,
        f2wb + (size_t)l * 128 * 256, f2bias + (size_t)l * 128,
        n2w + l * HID, n2b + l * HID, hbf);
  }

  group_bounds<<<1, 128, 0, stream>>>(batch, gstart);
  readout_part2<<<dim3(NG, 8), 128, 0, stream>>>(h, gstart, psum, pmax);
  readout_final<<<NG, 256, 0, stream>>>(gstart, psum, pmax, rnw, rnb, g);
  kan1_part<<<dim3(NG, 8), 128, 0, stream>>>(g, bw1, sw1, sc1, grid1, zpart);
  kan2<<<NG, 128, 0, stream>>>(zpart, bw2, sw2, sc2, grid2, out);
}

// Round 9
// 1059.744 us; speedup vs baseline: 1.3482x; 1.0912x over previous
//
#include <hip/hip_runtime.h>
#include <math.h>

#define NN 50000
#define NE 120000
#define FN 64
#define NEA 16
#define NR 4
#define NH 4
#define HID 128
#define NL 3
#define IDE 32
#define RED 8
#define NG 64
#define NC 10
#define KH 128
#define FFH 256
#define NBIN (NR * NN)
#define SCAN_BLK ((NBIN + 1023) / 1024)
// per-rel compacted-row capacities (hot-srcs ~13K, hot-dsts ~6.1K per rel)
#define CAPS 32768
#define CAPH 9216

typedef short bf16x8 __attribute__((ext_vector_type(8)));
typedef float f32x4 __attribute__((ext_vector_type(4)));

__device__ __forceinline__ unsigned short f2b(float f) {
  unsigned u = __float_as_uint(f);
  unsigned r = (u + 0x7FFFu + ((u >> 16) & 1u)) >> 16;
  return (unsigned short)r;
}
__device__ __forceinline__ float b2f(unsigned short b) {
  return __uint_as_float((unsigned)b << 16);
}

__global__ void cvt_bf16(const float* __restrict__ s, unsigned short* __restrict__ d, int n4) {
  int i = blockIdx.x * blockDim.x + threadIdx.x;
  if (i >= n4) return;
  float4 v = ((const float4*)s)[i];
  ushort4 o;
  o.x = f2b(v.x); o.y = f2b(v.y); o.z = f2b(v.z); o.w = f2b(v.w);
  ((ushort4*)d)[i] = o;
}

// ---- GEMM core: 64x128 tile, NO-LDS streaming main loop (round-3/4 design).
template <int KT>
__device__ __forceinline__ void gemm_direct(
    const unsigned short* __restrict__ A, const int* __restrict__ rowlist,
    const unsigned short* __restrict__ W, const float* __restrict__ bias,
    float* __restrict__ Cf, unsigned short* __restrict__ Cb,
    int nrows, int mout, int act, int rowBase, int colBase) {
  constexpr int NK = KT / 32;
  __shared__ unsigned short Es[64][136];
  int t = threadIdx.x;
  int lane = t & 63, w = t >> 6;
  int wm = w >> 1, wn = w & 1;
  int q = lane >> 4, mr = lane & 15;

  const unsigned short* ap[2];
#pragma unroll
  for (int mt = 0; mt < 2; ++mt) {
    int gr = rowBase + wm * 32 + mt * 16 + mr;
    int cg = (gr < nrows) ? gr : 0;
    int ar = rowlist ? rowlist[cg] : cg;
    ap[mt] = A + (size_t)ar * KT + q * 8;
  }
  const unsigned short* wp[4];
#pragma unroll
  for (int nt = 0; nt < 4; ++nt)
    wp[nt] = W + (size_t)(colBase + wn * 64 + nt * 16 + mr) * KT + q * 8;

  f32x4 acc[2][4] = {};
#pragma unroll
  for (int k = 0; k < NK; ++k) {
    bf16x8 af[2], bfr[4];
#pragma unroll
    for (int mt = 0; mt < 2; ++mt) af[mt] = *(const bf16x8*)(ap[mt] + k * 32);
#pragma unroll
    for (int nt = 0; nt < 4; ++nt) bfr[nt] = *(const bf16x8*)(wp[nt] + k * 32);
#pragma unroll
    for (int mt = 0; mt < 2; ++mt)
#pragma unroll
      for (int nt = 0; nt < 4; ++nt)
        acc[mt][nt] = __builtin_amdgcn_mfma_f32_16x16x32_bf16(af[mt], bfr[nt], acc[mt][nt], 0, 0, 0);
  }

  float bv[4];
#pragma unroll
  for (int nt = 0; nt < 4; ++nt) bv[nt] = bias[colBase + wn * 64 + nt * 16 + mr];

  if (Cf) {
#pragma unroll
    for (int mt = 0; mt < 2; ++mt)
#pragma unroll
      for (int nt = 0; nt < 4; ++nt)
#pragma unroll
        for (int r = 0; r < 4; ++r) {
          int row = rowBase + wm * 32 + mt * 16 + q * 4 + r;
          int col = colBase + wn * 64 + nt * 16 + mr;
          if (row < nrows) {
            float v = acc[mt][nt][r] + bv[nt];
            if (act) v = v / (1.f + expf(-v));
            Cf[(size_t)row * mout + col] = v;
            if (Cb) Cb[(size_t)row * mout + col] = f2b(v);
          }
        }
  } else {
#pragma unroll
    for (int mt = 0; mt < 2; ++mt)
#pragma unroll
      for (int nt = 0; nt < 4; ++nt)
#pragma unroll
        for (int r = 0; r < 4; ++r) {
          float v = acc[mt][nt][r] + bv[nt];
          if (act) v = v / (1.f + expf(-v));
          Es[wm * 32 + mt * 16 + q * 4 + r][wn * 64 + nt * 16 + mr] = f2b(v);
        }
    __syncthreads();
    int rl = t >> 2, co = (t & 3) * 32;
    int grow = rowBase + rl;
    if (grow < nrows) {
      unsigned short* dst = Cb + (size_t)grow * mout + colBase + co;
#pragma unroll
      for (int j = 0; j < 4; ++j)
        *(bf16x8*)(dst + j * 8) = *(const bf16x8*)&Es[rl][co + j * 8];
    }
  }
}

// XCD-aware full GEMM (dispatch is round-robin over 8 XCDs: bid&7 = XCD)
template <int KT>
__global__ __launch_bounds__(256, 2) void gemm_bf16_t(
    const unsigned short* __restrict__ A, const unsigned short* __restrict__ W,
    const float* __restrict__ bias, float* __restrict__ Cf, unsigned short* __restrict__ Cb,
    int nrows, int mout, int act, int ncol) {
  int nbr = (nrows + 63) >> 6;
  int rpx = (nbr + 7) >> 3;
  int xcd = blockIdx.x & 7, j = blockIdx.x >> 3;
  int rowT = xcd * rpx + j / ncol;
  int cy = j - (j / ncol) * ncol;
  if (rowT >= nbr) return;
  gemm_direct<KT>(A, nullptr, W, bias, Cf, Cb, nrows, mout, act, rowT * 64, cy * 128);
}

// ---- merged conv + solo GEMM, one launch per layer.
// Segments 0..7: xl (hot-src lists) / xr (hot-dst lists) staging GEMMs.
// Segments 8..11: solo-edge GEMM (softmax==1): g/4*(hbf[src]@Wsum^T+bsum)
// scatter-added into hmsg (atomicAdd; <=1 add per (dst,rel), zeroed base ->
// 2-rel collisions commutatively exact, >=3-rel ulp-level vs 2e-3 tolerance).
__global__ __launch_bounds__(256, 2) void conv_solo_all(
    const unsigned short* __restrict__ hbf,
    const int* __restrict__ srclist, const int* __restrict__ hotlist,
    const int* __restrict__ cnts,  // nsolo @ [r*16], nhot @ [64+r*16], nsrc @ [128+r*16]
    const unsigned short* __restrict__ Wl, const float* __restrict__ bl,
    const unsigned short* __restrict__ Wr, const float* __restrict__ br,
    unsigned short* __restrict__ xlb, unsigned short* __restrict__ xrh,
    const int* __restrict__ solosrc, const int* __restrict__ solodst,
    const unsigned short* __restrict__ wsum, const float* __restrict__ bsum,
    const float* __restrict__ gate, float* __restrict__ hmsg) {
  int t = threadIdx.x, lane = t & 63, w = t >> 6;
  int wm = w >> 1, wn = w & 1, q = lane >> 4, mr = lane & 15;
  for (int tid = blockIdx.x;; tid += gridDim.x) {
    int rem = tid, seg = 0, nrows = 0;
    for (; seg < 12; ++seg) {
      int n, tseg;
      if (seg < 8) {
        int r = seg >> 1;
        n = (seg & 1) ? cnts[64 + r * 16] : cnts[128 + r * 16];
        int cap = (seg & 1) ? CAPH : CAPS;
        if (n > cap) n = cap;
        tseg = ((n + 63) >> 6) * 4;
      } else {
        n = cnts[(seg - 8) * 16];
        tseg = (n + 63) >> 6;
      }
      if (rem < tseg) { nrows = n; break; }
      rem -= tseg;
    }
    if (seg == 12) return;
    if (seg < 8) {
      int r = seg >> 1, sel = seg & 1;
      int rt = rem >> 2, ct = rem & 3;
      const int* list = (sel ? hotlist : srclist) + r * NN;
      const unsigned short* W = (sel ? Wr : Wl) + (size_t)r * 512 * 128;
      const float* bias = (sel ? br : bl) + (size_t)r * 512;
      unsigned short* C = sel ? (xrh + (size_t)r * CAPH * 512) : (xlb + (size_t)r * CAPS * 512);
      gemm_direct<128>(hbf, list, W, bias, nullptr, C, nrows, 512, 0, rt * 64, ct * 128);
    } else {
      int r = seg - 8;
      int rowBase = rem * 64;
      const unsigned short* ap[2];
#pragma unroll
      for (int mt = 0; mt < 2; ++mt) {
        int gr = rowBase + wm * 32 + mt * 16 + mr;
        int idx = (gr < nrows) ? solosrc[r * NN + gr] : 0;
        ap[mt] = hbf + (size_t)idx * HID + q * 8;
      }
      const unsigned short* wp[4];
#pragma unroll
      for (int nt = 0; nt < 4; ++nt)
        wp[nt] = wsum + (size_t)r * 16384 + (size_t)(wn * 64 + nt * 16 + mr) * HID + q * 8;
      f32x4 acc[2][4] = {};
#pragma unroll
      for (int k = 0; k < 4; ++k) {
        bf16x8 af[2], bfr[4];
#pragma unroll
        for (int mt = 0; mt < 2; ++mt) af[mt] = *(const bf16x8*)(ap[mt] + k * 32);
#pragma unroll
        for (int nt = 0; nt < 4; ++nt) bfr[nt] = *(const bf16x8*)(wp[nt] + k * 32);
#pragma unroll
        for (int mt = 0; mt < 2; ++mt)
#pragma unroll
          for (int nt = 0; nt < 4; ++nt)
            acc[mt][nt] = __builtin_amdgcn_mfma_f32_16x16x32_bf16(af[mt], bfr[nt], acc[mt][nt], 0, 0, 0);
      }
      float g4 = gate[r] * 0.25f;
      float bv[4];
#pragma unroll
      for (int nt = 0; nt < 4; ++nt) bv[nt] = bsum[r * 128 + wn * 64 + nt * 16 + mr];
#pragma unroll
      for (int mt = 0; mt < 2; ++mt)
#pragma unroll
        for (int rr = 0; rr < 4; ++rr) {
          int row = rowBase + wm * 32 + mt * 16 + q * 4 + rr;
          if (row < nrows) {
            int dst = solodst[r * NN + row];
#pragma unroll
            for (int nt = 0; nt < 4; ++nt) {
              int col = wn * 64 + nt * 16 + mr;
              atomicAdd(&hmsg[(size_t)dst * HID + col], g4 * (acc[mt][nt][rr] + bv[nt]));
            }
          }
        }
    }
    __syncthreads();  // LDS WAR between tiles (solo iterations participate too)
  }
}

// head-summed lin_l weights/bias per (layer,rel): Wsum[o][k] = sum_h Wl[h*128+o][k]
__global__ void wsum_build(const float* __restrict__ linlw, const float* __restrict__ linlb,
                           unsigned short* __restrict__ wsum, float* __restrict__ bsum) {
  int i = blockIdx.x * blockDim.x + threadIdx.x;
  if (i >= NL * NR * 128 * 128) return;
  int k = i & 127, o = (i >> 7) & 127, lr = i >> 14;
  float s = 0.f;
#pragma unroll
  for (int h = 0; h < NH; ++h) s += linlw[((size_t)lr * 512 + h * 128 + o) * 128 + k];
  wsum[i] = f2b(s);
  if (k == 0) {
    float b = 0.f;
#pragma unroll
    for (int h = 0; h < NH; ++h) b += linlb[(size_t)lr * 512 + h * 128 + o];
    bsum[lr * 128 + o] = b;
  }
}

// ---- layer tail: LN1(h+hmsg+cb) -> y (REGISTERS, not re-read from HBM);
// zeroes hmsg for the next layer (replaces per-layer memset);
// f1=silu(y@W1^T+b1); f2=f1@W2^T+b2; h=LN2(y+f2); emits hbf (post-LN2).
__global__ __launch_bounds__(256, 2) void layer_tail(
    float* __restrict__ h, float* __restrict__ hmsg, const float* __restrict__ cb,
    const float* __restrict__ n1w, const float* __restrict__ n1b,
    const unsigned short* __restrict__ W1, const float* __restrict__ b1,
    const unsigned short* __restrict__ W2, const float* __restrict__ b2,
    const float* __restrict__ n2w, const float* __restrict__ n2b,
    unsigned short* __restrict__ hbfout) {
  __shared__ __align__(16) char smem[64 * 136 * 2 + 64 * 264 * 2];
  unsigned short (*Y)[136] = (unsigned short (*)[136])smem;
  unsigned short (*F1)[264] = (unsigned short (*)[264])(smem + 64 * 136 * 2);
  float (*Ef)[132] = (float (*)[132])(smem + 64 * 136 * 2);
  int nbr = (NN + 63) >> 6;
  int rpx = (nbr + 7) >> 3;
  int xcd = blockIdx.x & 7, j = blockIdx.x >> 3;
  int rowT = xcd * rpx + j;
  if (rowT >= nbr) return;
  int rowBase = rowT * 64;

  int t = threadIdx.x;
  int lane = t & 63, w = t >> 6;
  int wm = w >> 1, wn = w & 1;
  int q = lane >> 4, mr = lane & 15;

  // ---- phase 0: LN1 over own 64 rows (wave-per-row); y kept in regs (static idx)
  float y0r[16], y1r[16];
  {
    float w0 = n1w[lane], w1 = n1w[64 + lane];
    float bb0 = n1b[lane], bb1 = n1b[64 + lane];
    float c0 = cb[lane], c1 = cb[64 + lane];
#pragma unroll
    for (int it = 0; it < 16; ++it) {
      int rr = it * 4 + w;
      int grow = rowBase + rr;
      if (grow < NN) {
        size_t base = (size_t)grow * HID;
        float x0 = h[base + lane] + hmsg[base + lane] + c0;
        float x1 = h[base + 64 + lane] + hmsg[base + 64 + lane] + c1;
        hmsg[base + lane] = 0.f;        // zero for next layer (fused memset)
        hmsg[base + 64 + lane] = 0.f;
        float s = x0 + x1;
#pragma unroll
        for (int o = 32; o > 0; o >>= 1) s += __shfl_xor(s, o, 64);
        float mean = s * (1.f / 128.f);
        float d0 = x0 - mean, d1 = x1 - mean;
        float v = d0 * d0 + d1 * d1;
#pragma unroll
        for (int o = 32; o > 0; o >>= 1) v += __shfl_xor(v, o, 64);
        float inv = 1.f / sqrtf(v * (1.f / 128.f) + 1e-5f);
        float y0 = d0 * inv * w0 + bb0;
        float y1 = d1 * inv * w1 + bb1;
        y0r[it] = y0;
        y1r[it] = y1;
        Y[rr][lane] = f2b(y0);
        Y[rr][64 + lane] = f2b(y1);
      } else {
        y0r[it] = 0.f;
        y1r[it] = 0.f;
        Y[rr][lane] = 0;
        Y[rr][64 + lane] = 0;
      }
    }
  }
  __syncthreads();

  // ---- phase A: f1 = silu(y @ W1^T + b1), A-frags from Y LDS
  bf16x8 a[2][4];
#pragma unroll
  for (int mt = 0; mt < 2; ++mt)
#pragma unroll
    for (int k = 0; k < 4; ++k)
      a[mt][k] = *(const bf16x8*)&Y[wm * 32 + mt * 16 + mr][k * 32 + q * 8];

#pragma unroll
  for (int ph = 0; ph < 2; ++ph) {
    const unsigned short* wp[4];
#pragma unroll
    for (int nt = 0; nt < 4; ++nt)
      wp[nt] = W1 + (size_t)(ph * 128 + wn * 64 + nt * 16 + mr) * HID + q * 8;
    f32x4 acc[2][4] = {};
#pragma unroll
    for (int k = 0; k < 4; ++k) {
      bf16x8 bfr[4];
#pragma unroll
      for (int nt = 0; nt < 4; ++nt) bfr[nt] = *(const bf16x8*)(wp[nt] + k * 32);
#pragma unroll
      for (int mt = 0; mt < 2; ++mt)
#pragma unroll
        for (int nt = 0; nt < 4; ++nt)
          acc[mt][nt] = __builtin_amdgcn_mfma_f32_16x16x32_bf16(a[mt][k], bfr[nt], acc[mt][nt], 0, 0, 0);
    }
    float bv[4];
#pragma unroll
    for (int nt = 0; nt < 4; ++nt) bv[nt] = b1[ph * 128 + wn * 64 + nt * 16 + mr];
#pragma unroll
    for (int mt = 0; mt < 2; ++mt)
#pragma unroll
      for (int nt = 0; nt < 4; ++nt)
#pragma unroll
        for (int r = 0; r < 4; ++r) {
          float v = acc[mt][nt][r] + bv[nt];
          v = v / (1.f + expf(-v));
          F1[wm * 32 + mt * 16 + q * 4 + r][ph * 128 + wn * 64 + nt * 16 + mr] = f2b(v);
        }
  }
  __syncthreads();

  // ---- phase B: f2 = f1 @ W2^T (K=256), A from LDS, W2 from L2
  const unsigned short* wp2[4];
#pragma unroll
  for (int nt = 0; nt < 4; ++nt)
    wp2[nt] = W2 + (size_t)(wn * 64 + nt * 16 + mr) * FFH + q * 8;
  f32x4 acc2[2][4] = {};
#pragma unroll
  for (int k = 0; k < 8; ++k) {
    bf16x8 af[2], bfr[4];
#pragma unroll
    for (int mt = 0; mt < 2; ++mt)
      af[mt] = *(const bf16x8*)&F1[wm * 32 + mt * 16 + mr][k * 32 + q * 8];
#pragma unroll
    for (int nt = 0; nt < 4; ++nt) bfr[nt] = *(const bf16x8*)(wp2[nt] + k * 32);
#pragma unroll
    for (int mt = 0; mt < 2; ++mt)
#pragma unroll
      for (int nt = 0; nt < 4; ++nt)
        acc2[mt][nt] = __builtin_amdgcn_mfma_f32_16x16x32_bf16(af[mt], bfr[nt], acc2[mt][nt], 0, 0, 0);
  }
  __syncthreads();  // all F1 reads done before overwriting as Ef

  // ---- phase C: stage f2+b2 in LDS (f32), then LN2(y + f2) -> h, hbf
  float bv2[4];
#pragma unroll
  for (int nt = 0; nt < 4; ++nt) bv2[nt] = b2[wn * 64 + nt * 16 + mr];
#pragma unroll
  for (int mt = 0; mt < 2; ++mt)
#pragma unroll
    for (int nt = 0; nt < 4; ++nt)
#pragma unroll
      for (int r = 0; r < 4; ++r)
        Ef[wm * 32 + mt * 16 + q * 4 + r][wn * 64 + nt * 16 + mr] = acc2[mt][nt][r] + bv2[nt];
  __syncthreads();

  float w0 = n2w[lane], w1 = n2w[64 + lane];
  float bb0 = n2b[lane], bb1 = n2b[64 + lane];
#pragma unroll
  for (int it = 0; it < 16; ++it) {
    int rr = it * 4 + w;
    int grow = rowBase + rr;
    if (grow >= NN) continue;
    size_t base = (size_t)grow * HID;
    float x0 = y0r[it] + Ef[rr][lane];   // y from regs: no HBM round-trip
    float x1 = y1r[it] + Ef[rr][64 + lane];
    float s = x0 + x1;
#pragma unroll
    for (int o = 32; o > 0; o >>= 1) s += __shfl_xor(s, o, 64);
    float mean = s * (1.f / 128.f);
    float d0 = x0 - mean, d1 = x1 - mean;
    float v = d0 * d0 + d1 * d1;
#pragma unroll
    for (int o = 32; o > 0; o >>= 1) v += __shfl_xor(v, o, 64);
    float inv = 1.f / sqrtf(v * (1.f / 128.f) + 1e-5f);
    float y0 = d0 * inv * w0 + bb0;
    float y1 = d1 * inv * w1 + bb1;
    h[base + lane] = y0;
    h[base + 64 + lane] = y1;
    hbfout[base + lane] = f2b(y0);
    hbfout[base + 64 + lane] = f2b(y1);
  }
}

__global__ void build_xin_bf(const float* __restrict__ x, const int* __restrict__ idtok,
                             const float* __restrict__ emb, unsigned short* __restrict__ xin) {
  int i = blockIdx.x * blockDim.x + threadIdx.x;
  if (i >= NN * 96) return;
  int n = i / 96, k = i - n * 96;
  float v = (k < FN) ? x[(size_t)n * FN + k] : emb[(size_t)idtok[n] * IDE + (k - FN)];
  xin[i] = f2b(v);
}

// ---- CSR by (rel, dst) ----
__global__ void hist_bin(const int* __restrict__ ei, const int* __restrict__ et,
                         int* __restrict__ bcnt) {
  int e = blockIdx.x * blockDim.x + threadIdx.x;
  if (e >= NE) return;
  atomicAdd(&bcnt[et[e] * NN + ei[NE + e]], 1);
}
__global__ __launch_bounds__(256) void scan1(const int* __restrict__ cnt,
                                             int* __restrict__ pos, int* __restrict__ bsum) {
  __shared__ int lds[256];
  int b = blockIdx.x, t = threadIdx.x;
  int base = b * 1024 + t * 4;
  int v[4];
#pragma unroll
  for (int j = 0; j < 4; ++j) v[j] = (base + j < NBIN) ? cnt[base + j] : 0;
  int tot = v[0] + v[1] + v[2] + v[3];
  lds[t] = tot;
  __syncthreads();
  for (int off = 1; off < 256; off <<= 1) {
    int x = (t >= off) ? lds[t - off] : 0;
    __syncthreads();
    lds[t] += x;
    __syncthreads();
  }
  if (t == 255) bsum[b] = lds[255];
  int run = lds[t] - tot;
#pragma unroll
  for (int j = 0; j < 4; ++j) {
    if (base + j < NBIN) pos[base + j] = run;
    run += v[j];
  }
}
__global__ __launch_bounds__(256) void scan2(int* __restrict__ bsum) {
  __shared__ int lds[256];
  int t = threadIdx.x;
  int v = (t < SCAN_BLK) ? bsum[t] : 0;
  lds[t] = v;
  __syncthreads();
  for (int off = 1; off < 256; off <<= 1) {
    int x = (t >= off) ? lds[t - off] : 0;
    __syncthreads();
    lds[t] += x;
    __syncthreads();
  }
  if (t < SCAN_BLK) bsum[t] = lds[t] - v;
}
__global__ void scan3(int* __restrict__ pos, const int* __restrict__ bsum,
                      const int* __restrict__ cnt) {
  int i = blockIdx.x * blockDim.x + threadIdx.x;
  if (i >= NBIN) return;
  pos[i] += bsum[i >> 10];
  if (i == NBIN - 1) pos[NBIN] = pos[i] + cnt[i];
}
__global__ void scatter_bin(const int* __restrict__ ei, const int* __restrict__ et,
                            const int* __restrict__ csroff, int* __restrict__ cur,
                            int* __restrict__ elist) {
  int e = blockIdx.x * blockDim.x + threadIdx.x;
  if (e >= NE) return;
  int bin = et[e] * NN + ei[NE + e];
  int p = atomicAdd(&cur[bin], 1);
  elist[csroff[bin] + p] = e;
}
// DETERMINISM: atomic scatter order varies call-to-call; sort each bin.
__global__ void sort_bins(const int* __restrict__ csroff, int* __restrict__ elist) {
  int b = blockIdx.x * blockDim.x + threadIdx.x;
  if (b >= NBIN) return;
  int s = csroff[b], e = csroff[b + 1];
  for (int i = s + 1; i < e; ++i) {
    int key = elist[i];
    int j = i - 1;
    while (j >= s && elist[j] > key) { elist[j + 1] = elist[j]; --j; }
    elist[j + 1] = key;
  }
}
__global__ void gather_edge(const int* __restrict__ ei, const int* __restrict__ elist,
                            const float* __restrict__ eattr,
                            int* __restrict__ rsrc, float* __restrict__ eacsr) {
  int p = blockIdx.x * blockDim.x + threadIdx.x;
  if (p >= NE) return;
  int e = elist[p];
  rsrc[p] = ei[e];
  const float4* s = (const float4*)(eattr + (size_t)e * NEA);
  float4* d = (float4*)(eacsr + (size_t)p * NEA);
#pragma unroll
  for (int j = 0; j < 4; ++j) d[j] = s[j];
}
// flag srcs that appear in deg>=2 (hot) bins: only these need per-head xl staging
__global__ void mark_hotsrc(const int* __restrict__ csroff, const int* __restrict__ rsrc,
                            int* __restrict__ srcflag) {
  int b = blockIdx.x * blockDim.x + threadIdx.x;
  if (b >= NBIN) return;
  int s = csroff[b], e = csroff[b + 1];
  if (e - s < 2) return;
  int rel = b / NN;
  for (int p = s; p < e; ++p) srcflag[rel * NN + rsrc[p]] = 1;
}
// ORDERED hot-src compaction from scan positions (deterministic + sequential gather)
__global__ void build_src_o(const int* __restrict__ srcflag, const int* __restrict__ srcpos,
                            int* __restrict__ srclist, int* __restrict__ srcmap) {
  int b = blockIdx.x * blockDim.x + threadIdx.x;
  if (b >= NBIN) return;
  if (srcflag[b]) {
    int rel = b / NN;
    int pos = srcpos[b] - srcpos[rel * NN];
    srcmap[b] = pos;
    srclist[rel * NN + pos] = b - rel * NN;
  }
}
__global__ void fincnt(const int* __restrict__ srcpos, int* __restrict__ nsrc) {
  int r = threadIdx.x;
  if (r < NR) nsrc[r * 16] = srcpos[(r + 1) * NN] - srcpos[r * NN];
}
// rsrcx: hot-src row index per edge position (garbage for solo positions, unread)
__global__ void remap_rsrc(const int* __restrict__ csroff, const int* __restrict__ rsrc,
                           const int* __restrict__ srcmap, int* __restrict__ rsrcx) {
  int p = blockIdx.x * blockDim.x + threadIdx.x;
  if (p >= NE) return;
  int rel = (p >= csroff[NN]) + (p >= csroff[2 * NN]) + (p >= csroff[3 * NN]);
  rsrcx[p] = srcmap[rel * NN + rsrc[p]];
}
// per-rel solo (deg==1: ORIGINAL src id + dst) + hot (deg>=2) lists.
__global__ __launch_bounds__(256) void build_hot(
    const int* __restrict__ csroff, const int* __restrict__ rsrc,
    int* __restrict__ nsolo, int* __restrict__ nhot,
    int* __restrict__ solosrc, int* __restrict__ solodst, int* __restrict__ hotlist) {
  __shared__ int wsc[4][4], whc[4][4];
  __shared__ int sbase[4], hbase[4];
  int t = threadIdx.x, wave = t >> 6, lane = t & 63;
  int b = blockIdx.x * 256 + t;
  bool valid = b < NBIN;
  int cnt = 0, rel = 0, s = 0;
  if (valid) { s = csroff[b]; cnt = csroff[b + 1] - s; rel = b / NN; }
  bool solo = valid && cnt == 1;
  bool hot = valid && cnt >= 2;
#pragma unroll
  for (int rr = 0; rr < 4; ++rr) {
    unsigned long long ms = __ballot(solo && rel == rr);
    unsigned long long mh = __ballot(hot && rel == rr);
    if (lane == 0) { wsc[wave][rr] = __popcll(ms); whc[wave][rr] = __popcll(mh); }
  }
  __syncthreads();
  if (t < 4) {
    int ssum = wsc[0][t] + wsc[1][t] + wsc[2][t] + wsc[3][t];
    int hsum = whc[0][t] + whc[1][t] + whc[2][t] + whc[3][t];
    sbase[t] = ssum ? atomicAdd(&nsolo[t * 16], ssum) : 0;
    hbase[t] = hsum ? atomicAdd(&nhot[t * 16], hsum) : 0;
  }
  __syncthreads();
#pragma unroll
  for (int rr = 0; rr < 4; ++rr) {
    unsigned long long ms = __ballot(solo && rel == rr);
    if (solo && rel == rr) {
      int before = 0;
#pragma unroll
      for (int wv = 0; wv < 4; ++wv) if (wv < wave) before += wsc[wv][rr];
      int pos = sbase[rr] + before + __popcll(ms & ((1ull << lane) - 1ull));
      solosrc[rr * NN + pos] = rsrc[s];
      solodst[rr * NN + pos] = b - rr * NN;
    }
    unsigned long long mh = __ballot(hot && rel == rr);
    if (hot && rel == rr) {
      int before = 0;
#pragma unroll
      for (int wv = 0; wv < 4; ++wv) if (wv < wave) before += whc[wv][rr];
      int pos = hbase[rr] + before + __popcll(mh & ((1ull << lane) - 1ull));
      hotlist[rr * NN + pos] = b - rr * NN;
    }
  }
}

// all-layers gate softmax + gated conv bias in one launch (block = layer)
__global__ void gate_cb_all(const float* __restrict__ rg, const float* __restrict__ cbias,
                            float* __restrict__ gate, float* __restrict__ cb) {
  __shared__ float g[NR];
  int l = blockIdx.x, t = threadIdx.x;
  const float* rgl = rg + l * NR;
  if (t == 0) {
    float mx = rgl[0];
    for (int r = 1; r < NR; ++r) mx = fmaxf(mx, rgl[r]);
    float s = 0.f, tmp[NR];
    for (int r = 0; r < NR; ++r) { tmp[r] = expf(rgl[r] - mx); s += tmp[r]; }
    for (int r = 0; r < NR; ++r) { g[r] = tmp[r] / s; gate[l * NR + r] = g[r]; }
  }
  __syncthreads();
  float c = 0.f;
  for (int r = 0; r < NR; ++r) c += g[r] * cbias[(size_t)l * NR * HID + r * HID + t];
  cb[l * HID + t] = c;
}

// ---- hot-only edge pass: block/dst, online softmax (solo handled in conv_solo_all)
__global__ __launch_bounds__(256) void edge_all(
    const int* __restrict__ csroff, const int* __restrict__ rsrcx,
    const float* __restrict__ eacsr, const float* __restrict__ relembp,
    const float* __restrict__ wedgep, const float* __restrict__ attwp,
    const unsigned short* __restrict__ xlb, const unsigned short* __restrict__ xrh,
    const int* __restrict__ hotlist, const int* __restrict__ nhot,
    float* __restrict__ hmsg, const float* __restrict__ gate, int rel) {
  __shared__ float lds[4][128];
  int wave = threadIdx.x >> 6, lane = threadIdx.x & 63;
  float g4 = gate[rel] * 0.25f;
  int hh = wave;
  float wreg[2][24], areg[2];
#pragma unroll
  for (int j = 0; j < 2; ++j) {
    int col = hh * 128 + j * 64 + lane;
    const float* wp = wedgep + (size_t)col * 24;
#pragma unroll
    for (int k = 0; k < 24; ++k) wreg[j][k] = wp[k];
    areg[j] = attwp[col];
  }
  float evr0 = 0.f, evr1 = 0.f;
#pragma unroll
  for (int k = 0; k < 8; ++k) {
    float rk = relembp[k];
    evr0 += rk * wreg[0][NEA + k];
    evr1 += rk * wreg[1][NEA + k];
  }
  int nh = nhot[rel * 16];
  for (int wi = blockIdx.x; wi < nh; wi += gridDim.x) {
    int dst = hotlist[rel * NN + wi];
    int s = csroff[rel * NN + dst], e = csroff[rel * NN + dst + 1];
    {
      const unsigned short* xrp = xrh + (size_t)wi * 512;
      float xr0 = b2f(xrp[hh * 128 + lane]);
      float xr1 = b2f(xrp[hh * 128 + 64 + lane]);
      float m = -3.4e38f, den = 0.f, acc0 = 0.f, acc1 = 0.f;
      for (int p = s; p < e; ++p) {
        int src = rsrcx[p];
        const float* eap = eacsr + (size_t)p * NEA;
        float eev0 = evr0, eev1 = evr1;
#pragma unroll
        for (int k = 0; k < NEA; ++k) {
          float er = eap[k];
          eev0 += er * wreg[0][k];
          eev1 += er * wreg[1][k];
        }
        float xl0 = b2f(xlb[(size_t)src * 512 + hh * 128 + lane]);
        float xl1 = b2f(xlb[(size_t)src * 512 + hh * 128 + 64 + lane]);
        float s0 = xl0 + xr0 + eev0; s0 = (s0 > 0.f) ? s0 : 0.2f * s0;
        float s1 = xl1 + xr1 + eev1; s1 = (s1 > 0.f) ? s1 : 0.2f * s1;
        float lg = s0 * areg[0] + s1 * areg[1];
#pragma unroll
        for (int o = 32; o > 0; o >>= 1) lg += __shfl_xor(lg, o, 64);
        float mn = fmaxf(m, lg);
        float sc = expf(m - mn);
        float ex = expf(lg - mn);
        den = den * sc + ex;
        acc0 = acc0 * sc + ex * xl0;
        acc1 = acc1 * sc + ex * xl1;
        m = mn;
      }
      float wgt = g4 / den;
      lds[wave][lane] = acc0 * wgt;
      lds[wave][64 + lane] = acc1 * wgt;
    }
    __syncthreads();
    if (wave < 2) {
      int d = wave * 64 + lane;
      float v = lds[0][d] + lds[1][d] + lds[2][d] + lds[3][d];
      hmsg[(size_t)dst * HID + d] += v;
    }
    __syncthreads();
  }
}

// ---- readout: deterministic ----
__global__ void group_bounds(const int* __restrict__ batch, int* __restrict__ gstart) {
  int g = threadIdx.x + blockIdx.x * blockDim.x;
  if (g > NG) return;
  int lo = 0, hi = NN;
  while (lo < hi) {
    int mid = (lo + hi) >> 1;
    if (batch[mid] < g) lo = mid + 1; else hi = mid;
  }
  gstart[g] = lo;
}
__global__ __launch_bounds__(128) void readout_part2(
    const float* __restrict__ h, const int* __restrict__ gstart,
    float* __restrict__ psum, float* __restrict__ pmax) {
  int g = blockIdx.x, s = blockIdx.y, t = threadIdx.x;
  int r0 = gstart[g], r1 = gstart[g + 1];
  float acc = 0.f, mx = -3.4e38f;
  for (int row = r0 + s; row < r1; row += 8) {
    float v = h[(size_t)row * HID + t];
    acc += v;
    mx = fmaxf(mx, v);
  }
  psum[((size_t)g * 8 + s) * HID + t] = acc;
  pmax[((size_t)g * 8 + s) * HID + t] = mx;
}
__global__ __launch_bounds__(256) void readout_final(
    const int* __restrict__ gstart, const float* __restrict__ psum,
    const float* __restrict__ pmax, const float* __restrict__ w,
    const float* __restrict__ b, float* __restrict__ g) {
  int bg = blockIdx.x, t = threadIdx.x;
  __shared__ float red[256];
  float c = fmaxf((float)(gstart[bg + 1] - gstart[bg]), 1.f);
  float x;
  if (t < HID) {
    float ssum = 0.f;
    for (int s = 0; s < 8; ++s) ssum += psum[((size_t)bg * 8 + s) * HID + t];
    x = ssum / c;
  } else {
    float mx = -3.4e38f;
    for (int s = 0; s < 8; ++s) mx = fmaxf(mx, pmax[((size_t)bg * 8 + s) * HID + (t - HID)]);
    x = mx;
  }
  red[t] = x;
  __syncthreads();
  for (int s = 128; s > 0; s >>= 1) {
    if (t < s) red[t] += red[t + s];
    __syncthreads();
  }
  float mean = red[0] * (1.f / 256.f);
  __syncthreads();
  float d = x - mean;
  red[t] = d * d;
  __syncthreads();
  for (int s = 128; s > 0; s >>= 1) {
    if (t < s) red[t] += red[t + s];
    __syncthreads();
  }
  float inv = 1.f / sqrtf(red[0] * (1.f / 256.f) + 1e-5f);
  g[(size_t)bg * 256 + t] = d * inv * w[t] + b[t];
}

__device__ __forceinline__ void bspline8(float x, const float* __restrict__ t,
                                         float* __restrict__ out) {
  float bs[11];
#pragma unroll
  for (int j = 0; j < 11; ++j) bs[j] = (x >= t[j] && x < t[j + 1]) ? 1.f : 0.f;
#pragma unroll
  for (int k = 1; k <= 3; ++k) {
    for (int j = 0; j < 11 - k; ++j) {
      bs[j] = (x - t[j]) / (t[j + k] - t[j]) * bs[j] +
              (t[j + k + 1] - x) / (t[j + k + 1] - t[j + 1]) * bs[j + 1];
    }
  }
#pragma unroll
  for (int j = 0; j < 8; ++j) out[j] = bs[j];
}

// ---- KAN1, K-chunked into fixed partial slots (deterministic) ----
__global__ __launch_bounds__(128) void kan1_part(
    const float* __restrict__ g, const float* __restrict__ bw,
    const float* __restrict__ sw, const float* __restrict__ sc,
    const float* __restrict__ grid, float* __restrict__ zpart) {
  int bg = blockIdx.x, ch = blockIdx.y, t = threadIdx.x;
  int base = ch * 32;
  __shared__ float B[32][8];
  __shared__ float sg[32];
  if (t < 32) {
    float x = g[(size_t)bg * 256 + base + t];
    sg[t] = x / (1.f + expf(-x));
    bspline8(x, grid + (size_t)(base + t) * 12, B[t]);
  }
  __syncthreads();
  float acc = 0.f;
  for (int i = 0; i < 32; ++i) {
    int col = base + i;
    acc += sg[i] * bw[(size_t)t * 256 + col];
    const float* swp = sw + ((size_t)t * 256 + col) * 8;
    float sp = 0.f;
#pragma unroll
    for (int k = 0; k < 8; ++k) sp += B[i][k] * swp[k];
    acc += sp * sc[(size_t)t * 256 + col];
  }
  zpart[((size_t)ch * NG + bg) * KH + t] = acc;
}

__global__ __launch_bounds__(128) void kan2(
    const float* __restrict__ zpart, const float* __restrict__ bw,
    const float* __restrict__ sw, const float* __restrict__ sc,
    const float* __restrict__ grid, float* __restrict__ out) {
  int bg = blockIdx.x, t = threadIdx.x;
  __shared__ float B[128][8];
  __shared__ float sz[128];
  float x = 0.f;
  for (int ch = 0; ch < 8; ++ch) x += zpart[((size_t)ch * NG + bg) * KH + t];
  sz[t] = x / (1.f + expf(-x));
  bspline8(x, grid + (size_t)t * 12, B[t]);
  __syncthreads();
  if (t < NC) {
    float acc = 0.f;
    for (int i = 0; i < 128; ++i) {
      acc += sz[i] * bw[(size_t)t * 128 + i];
      const float* swp = sw + ((size_t)t * 128 + i) * 8;
      float sp = 0.f;
#pragma unroll
      for (int k = 0; k < 8; ++k) sp += B[i][k] * swp[k];
      acc += sp * sc[(size_t)t * 128 + i];
    }
    out[(size_t)bg * NC + t] = acc;
  }
}

extern "C" void kernel_launch(void* const* d_in, const int* in_sizes, int n_in,
                              void* d_out, int out_size, void* d_ws, size_t ws_size,
                              hipStream_t stream) {
  const float* x       = (const float*)d_in[0];
  const float* eattr   = (const float*)d_in[1];
  const int*   idtok   = (const int*)d_in[2];
  const int*   ei      = (const int*)d_in[3];
  const int*   etype   = (const int*)d_in[4];
  const int*   batch   = (const int*)d_in[5];
  const float* idemb   = (const float*)d_in[6];
  const float* inw     = (const float*)d_in[7];
  const float* inb     = (const float*)d_in[8];
  const float* relemb  = (const float*)d_in[9];
  const float* linlw   = (const float*)d_in[10];
  const float* linlb   = (const float*)d_in[11];
  const float* linrw   = (const float*)d_in[12];
  const float* linrb   = (const float*)d_in[13];
  const float* linew   = (const float*)d_in[14];
  const float* attw    = (const float*)d_in[15];
  const float* convb   = (const float*)d_in[16];
  const float* relgate = (const float*)d_in[17];
  const float* n1w     = (const float*)d_in[18];
  const float* n1b     = (const float*)d_in[19];
  const float* n2w     = (const float*)d_in[20];
  const float* n2b     = (const float*)d_in[21];
  const float* f1w     = (const float*)d_in[22];
  const float* f1bias  = (const float*)d_in[23];
  const float* f2w     = (const float*)d_in[24];
  const float* f2bias  = (const float*)d_in[25];
  const float* rnw     = (const float*)d_in[26];
  const float* rnb     = (const float*)d_in[27];
  const float* bw1     = (const float*)d_in[28];
  const float* sw1     = (const float*)d_in[29];
  const float* sc1     = (const float*)d_in[30];
  const float* grid1   = (const float*)d_in[31];
  const float* bw2     = (const float*)d_in[32];
  const float* sw2     = (const float*)d_in[33];
  const float* sc2     = (const float*)d_in[34];
  const float* grid2   = (const float*)d_in[35];
  float* out = (float*)d_out;
  (void)in_sizes; (void)n_in; (void)out_size; (void)ws_size;

  char* p = (char*)d_ws;
  auto alloc = [&](size_t bytes) { void* q = (void*)p; p += (bytes + 255) & ~(size_t)255; return q; };
  float* h    = (float*)alloc((size_t)NN * HID * 4);
  float* hmsg = (float*)alloc((size_t)NN * HID * 4);
  unsigned short* hbf = (unsigned short*)alloc((size_t)NN * HID * 2);
  unsigned short* xlb = (unsigned short*)alloc((size_t)NR * CAPS * 512 * 2);  // 134.2MB
  unsigned short* xrh = (unsigned short*)alloc((size_t)NR * CAPH * 512 * 2);  // 37.7MB
  int* elist = (int*)alloc((size_t)NE * 4);
  int* rsrc  = (int*)alloc((size_t)NE * 4);
  int* rsrcx = (int*)alloc((size_t)NE * 4);
  float* eacsr = (float*)alloc((size_t)NE * NEA * 4);
  int* bcnt  = (int*)alloc((size_t)NBIN * 8 + 8);
  int* cur   = bcnt + NBIN;
  int* csroff = (int*)alloc((size_t)(NBIN + 1) * 4);
  int* srcpos = (int*)alloc((size_t)(NBIN + 1) * 4);
  int* bsum  = (int*)alloc((size_t)SCAN_BLK * 4);
  int* hotlist = (int*)alloc((size_t)NR * NN * 4);
  int* solosrc = (int*)alloc((size_t)NR * NN * 4);
  int* solodst = (int*)alloc((size_t)NR * NN * 4);
  int* srclist = (int*)alloc((size_t)NR * NN * 4);
  int* srcflag = (int*)alloc((size_t)NBIN * 4);
  int* srcmap  = (int*)alloc((size_t)NBIN * 4);
  int* cnts    = (int*)alloc(1024);
  int* nsolo   = cnts;
  int* nhot    = cnts + 64;
  int* nsrc    = cnts + 128;
  unsigned short* linlwb = (unsigned short*)alloc((size_t)NL * NR * 512 * 128 * 2);
  unsigned short* linrwb = (unsigned short*)alloc((size_t)NL * NR * 512 * 128 * 2);
  unsigned short* f1wb   = (unsigned short*)alloc((size_t)NL * 256 * 128 * 2);
  unsigned short* f2wb   = (unsigned short*)alloc((size_t)NL * 128 * 256 * 2);
  unsigned short* inwb   = (unsigned short*)alloc((size_t)128 * 96 * 2);
  unsigned short* wsumb  = (unsigned short*)alloc((size_t)NL * NR * 128 * 128 * 2);
  float* bsumf = (float*)alloc((size_t)NL * NR * 128 * 4);
  float* gate = (float*)alloc(NL * NR * 4);
  float* cb   = (float*)alloc(NL * HID * 4);
  int* gstart = (int*)alloc((size_t)(NG + 1) * 4);
  float* psum = (float*)alloc((size_t)NG * 8 * HID * 4);
  float* pmax = (float*)alloc((size_t)NG * 8 * HID * 4);
  float* zpart = (float*)alloc((size_t)8 * NG * KH * 4);
  float* g = (float*)alloc((size_t)NG * 256 * 4);
  unsigned short* xinbf = xlb;  // aliased: in-proj input staged before layer loop

  const int NB64 = (NN + 63) / 64;
  const int RPX = (NB64 + 7) / 8;

  {
    int n;
    n = NL * NR * 512 * 128 / 4;
    cvt_bf16<<<(n + 255) / 256, 256, 0, stream>>>(linlw, linlwb, n);
    cvt_bf16<<<(n + 255) / 256, 256, 0, stream>>>(linrw, linrwb, n);
    n = NL * 256 * 128 / 4;
    cvt_bf16<<<(n + 255) / 256, 256, 0, stream>>>(f1w, f1wb, n);
    cvt_bf16<<<(n + 255) / 256, 256, 0, stream>>>(f2w, f2wb, n);
    n = 128 * 96 / 4;
    cvt_bf16<<<(n + 255) / 256, 256, 0, stream>>>(inw, inwb, n);
  }
  wsum_build<<<(NL * NR * 128 * 128 + 255) / 256, 256, 0, stream>>>(linlw, linlb, wsumb, bsumf);

  hipMemsetAsync(bcnt, 0, (size_t)NBIN * 8 + 8, stream);
  hipMemsetAsync(srcflag, 0, (size_t)NBIN * 4, stream);
  hipMemsetAsync(cnts, 0, 1024, stream);
  hist_bin<<<(NE + 255) / 256, 256, 0, stream>>>(ei, etype, bcnt);
  scan1<<<SCAN_BLK, 256, 0, stream>>>(bcnt, csroff, bsum);
  scan2<<<1, 256, 0, stream>>>(bsum);
  scan3<<<(NBIN + 255) / 256, 256, 0, stream>>>(csroff, bsum, bcnt);
  scatter_bin<<<(NE + 255) / 256, 256, 0, stream>>>(ei, etype, csroff, cur, elist);
  sort_bins<<<(NBIN + 255) / 256, 256, 0, stream>>>(csroff, elist);
  gather_edge<<<(NE + 255) / 256, 256, 0, stream>>>(ei, elist, eattr, rsrc, eacsr);
  mark_hotsrc<<<(NBIN + 255) / 256, 256, 0, stream>>>(csroff, rsrc, srcflag);
  scan1<<<SCAN_BLK, 256, 0, stream>>>(srcflag, srcpos, bsum);
  scan2<<<1, 256, 0, stream>>>(bsum);
  scan3<<<(NBIN + 255) / 256, 256, 0, stream>>>(srcpos, bsum, srcflag);
  build_src_o<<<(NBIN + 255) / 256, 256, 0, stream>>>(srcflag, srcpos, srclist, srcmap);
  fincnt<<<1, 64, 0, stream>>>(srcpos, nsrc);
  remap_rsrc<<<(NE + 255) / 256, 256, 0, stream>>>(csroff, rsrc, srcmap, rsrcx);
  build_hot<<<(NBIN + 255) / 256, 256, 0, stream>>>(csroff, rsrc, nsolo, nhot,
                                                    solosrc, solodst, hotlist);
  gate_cb_all<<<NL, 128, 0, stream>>>(relgate, convb, gate, cb);

  build_xin_bf<<<(NN * 96 + 255) / 256, 256, 0, stream>>>(x, idtok, idemb, xinbf);
  gemm_bf16_t<96><<<8 * RPX, 256, 0, stream>>>(xinbf, inwb, inb, h, hbf, NN, 128, 1, 1);

  hipMemsetAsync(hmsg, 0, (size_t)NN * HID * 4, stream);  // l=0 only; layer_tail zeroes after
  for (int l = 0; l < NL; ++l) {
    conv_solo_all<<<4096, 256, 0, stream>>>(
        hbf, srclist, hotlist, cnts,
        linlwb + (size_t)l * NR * 512 * 128, linlb + (size_t)l * NR * 512,
        linrwb + (size_t)l * NR * 512 * 128, linrb + (size_t)l * NR * 512,
        xlb, xrh,
        solosrc, solodst,
        wsumb + (size_t)l * NR * 16384, bsumf + (size_t)l * NR * 128,
        gate + l * NR, hmsg);
    for (int r = 0; r < NR; ++r) {
      int lr = l * NR + r;
      edge_all<<<4096, 256, 0, stream>>>(
          csroff, rsrcx, eacsr, relemb + (size_t)lr * RED,
          linew + (size_t)lr * 512 * 24,
          attw + (size_t)lr * 512,
          xlb + (size_t)r * CAPS * 512, xrh + (size_t)r * CAPH * 512,
          hotlist, nhot, hmsg, gate + l * NR, r);
    }
    layer_tail<<<8 * RPX, 256, 0, stream>>>(
        h, hmsg, cb + l * HID, n1w + l * HID, n1b + l * HID,
        f1wb + (size_t)l * 256 * 128, f1bias + (size_t)l * 256,
        f2wb + (size_t)l * 128 * 256, f2bias + (size_t)l * 128,
        n2w + l * HID, n2b + l * HID, hbf);
  }

  group_bounds<<<1, 128, 0, stream>>>(batch, gstart);
  readout_part2<<<dim3(NG, 8), 128, 0, stream>>>(h, gstart, psum, pmax);
  readout_final<<<NG, 256, 0, stream>>>(gstart, psum, pmax, rnw, rnb, g);
  kan1_part<<<dim3(NG, 8), 128, 0, stream>>>(g, bw1, sw1, sc1, grid1, zpart);
  kan2<<<NG, 128, 0, stream>>>(zpart, bw2, sw2, sc2, grid2, out);
}

// Round 10
// 1017.939 us; speedup vs baseline: 1.4036x; 1.0411x over previous
//
#include <hip/hip_runtime.h>
#include <math.h>

#define NN 50000
#define NE 120000
#define FN 64
#define NEA 16
#define NR 4
#define NH 4
#define HID 128
#define NL 3
#define IDE 32
#define RED 8
#define NG 64
#define NC 10
#define KH 128
#define FFH 256
#define NBIN (NR * NN)
#define SCAN_BLK ((NBIN + 1023) / 1024)
// per-rel compacted-row capacities (hot-srcs ~13K, hot-dsts ~6.1K per rel)
#define CAPS 32768
#define CAPH 9216

typedef short bf16x8 __attribute__((ext_vector_type(8)));
typedef float f32x4 __attribute__((ext_vector_type(4)));

__device__ __forceinline__ unsigned short f2b(float f) {
  unsigned u = __float_as_uint(f);
  unsigned r = (u + 0x7FFFu + ((u >> 16) & 1u)) >> 16;
  return (unsigned short)r;
}
__device__ __forceinline__ float b2f(unsigned short b) {
  return __uint_as_float((unsigned)b << 16);
}

__global__ void cvt_bf16(const float* __restrict__ s, unsigned short* __restrict__ d, int n4) {
  int i = blockIdx.x * blockDim.x + threadIdx.x;
  if (i >= n4) return;
  float4 v = ((const float4*)s)[i];
  ushort4 o;
  o.x = f2b(v.x); o.y = f2b(v.y); o.z = f2b(v.z); o.w = f2b(v.w);
  ((ushort4*)d)[i] = o;
}

// ---- GEMM core: 64x128 tile, NO-LDS streaming main loop (round-3/4 design).
template <int KT>
__device__ __forceinline__ void gemm_direct(
    const unsigned short* __restrict__ A, const int* __restrict__ rowlist,
    const unsigned short* __restrict__ W, const float* __restrict__ bias,
    float* __restrict__ Cf, unsigned short* __restrict__ Cb,
    int nrows, int mout, int act, int rowBase, int colBase) {
  constexpr int NK = KT / 32;
  __shared__ unsigned short Es[64][136];
  int t = threadIdx.x;
  int lane = t & 63, w = t >> 6;
  int wm = w >> 1, wn = w & 1;
  int q = lane >> 4, mr = lane & 15;

  const unsigned short* ap[2];
#pragma unroll
  for (int mt = 0; mt < 2; ++mt) {
    int gr = rowBase + wm * 32 + mt * 16 + mr;
    int cg = (gr < nrows) ? gr : 0;
    int ar = rowlist ? rowlist[cg] : cg;
    ap[mt] = A + (size_t)ar * KT + q * 8;
  }
  const unsigned short* wp[4];
#pragma unroll
  for (int nt = 0; nt < 4; ++nt)
    wp[nt] = W + (size_t)(colBase + wn * 64 + nt * 16 + mr) * KT + q * 8;

  f32x4 acc[2][4] = {};
#pragma unroll
  for (int k = 0; k < NK; ++k) {
    bf16x8 af[2], bfr[4];
#pragma unroll
    for (int mt = 0; mt < 2; ++mt) af[mt] = *(const bf16x8*)(ap[mt] + k * 32);
#pragma unroll
    for (int nt = 0; nt < 4; ++nt) bfr[nt] = *(const bf16x8*)(wp[nt] + k * 32);
#pragma unroll
    for (int mt = 0; mt < 2; ++mt)
#pragma unroll
      for (int nt = 0; nt < 4; ++nt)
        acc[mt][nt] = __builtin_amdgcn_mfma_f32_16x16x32_bf16(af[mt], bfr[nt], acc[mt][nt], 0, 0, 0);
  }

  float bv[4];
#pragma unroll
  for (int nt = 0; nt < 4; ++nt) bv[nt] = bias[colBase + wn * 64 + nt * 16 + mr];

  if (Cf) {
#pragma unroll
    for (int mt = 0; mt < 2; ++mt)
#pragma unroll
      for (int nt = 0; nt < 4; ++nt)
#pragma unroll
        for (int r = 0; r < 4; ++r) {
          int row = rowBase + wm * 32 + mt * 16 + q * 4 + r;
          int col = colBase + wn * 64 + nt * 16 + mr;
          if (row < nrows) {
            float v = acc[mt][nt][r] + bv[nt];
            if (act) v = v / (1.f + expf(-v));
            Cf[(size_t)row * mout + col] = v;
            if (Cb) Cb[(size_t)row * mout + col] = f2b(v);
          }
        }
  } else {
#pragma unroll
    for (int mt = 0; mt < 2; ++mt)
#pragma unroll
      for (int nt = 0; nt < 4; ++nt)
#pragma unroll
        for (int r = 0; r < 4; ++r) {
          float v = acc[mt][nt][r] + bv[nt];
          if (act) v = v / (1.f + expf(-v));
          Es[wm * 32 + mt * 16 + q * 4 + r][wn * 64 + nt * 16 + mr] = f2b(v);
        }
    __syncthreads();
    int rl = t >> 2, co = (t & 3) * 32;
    int grow = rowBase + rl;
    if (grow < nrows) {
      unsigned short* dst = Cb + (size_t)grow * mout + colBase + co;
#pragma unroll
      for (int j = 0; j < 4; ++j)
        *(bf16x8*)(dst + j * 8) = *(const bf16x8*)&Es[rl][co + j * 8];
    }
  }
}

// XCD-aware full GEMM (dispatch is round-robin over 8 XCDs: bid&7 = XCD)
template <int KT>
__global__ __launch_bounds__(256, 2) void gemm_bf16_t(
    const unsigned short* __restrict__ A, const unsigned short* __restrict__ W,
    const float* __restrict__ bias, float* __restrict__ Cf, unsigned short* __restrict__ Cb,
    int nrows, int mout, int act, int ncol) {
  int nbr = (nrows + 63) >> 6;
  int rpx = (nbr + 7) >> 3;
  int xcd = blockIdx.x & 7, j = blockIdx.x >> 3;
  int rowT = xcd * rpx + j / ncol;
  int cy = j - (j / ncol) * ncol;
  if (rowT >= nbr) return;
  gemm_direct<KT>(A, nullptr, W, bias, Cf, Cb, nrows, mout, act, rowT * 64, cy * 128);
}

// ---- merged conv + solo GEMM, one launch per layer.
// Segments 0..7: xl (hot-src lists) / xr (hot-dst lists) staging GEMMs.
// Segments 8..11: solo-edge GEMM (softmax==1): g/4*(hbf[src]@Wsum^T+bsum)
// scatter-added into hmsg (atomicAdd; <=1 add per (dst,rel), zeroed base ->
// 2-rel collisions commutatively exact, >=3-rel ulp-level vs 2e-3 tolerance).
__global__ __launch_bounds__(256, 2) void conv_solo_all(
    const unsigned short* __restrict__ hbf,
    const int* __restrict__ srclist, const int* __restrict__ hotlist,
    const int* __restrict__ cnts,  // nsolo @ [r*16], nhot @ [64+r*16], nsrc @ [128+r*16]
    const unsigned short* __restrict__ Wl, const float* __restrict__ bl,
    const unsigned short* __restrict__ Wr, const float* __restrict__ br,
    unsigned short* __restrict__ xlb, unsigned short* __restrict__ xrh,
    const int* __restrict__ solosrc, const int* __restrict__ solodst,
    const unsigned short* __restrict__ wsum, const float* __restrict__ bsum,
    const float* __restrict__ gate, float* __restrict__ hmsg) {
  int t = threadIdx.x, lane = t & 63, w = t >> 6;
  int wm = w >> 1, wn = w & 1, q = lane >> 4, mr = lane & 15;
  for (int tid = blockIdx.x;; tid += gridDim.x) {
    int rem = tid, seg = 0, nrows = 0;
    for (; seg < 12; ++seg) {
      int n, tseg;
      if (seg < 8) {
        int r = seg >> 1;
        n = (seg & 1) ? cnts[64 + r * 16] : cnts[128 + r * 16];
        int cap = (seg & 1) ? CAPH : CAPS;
        if (n > cap) n = cap;
        tseg = ((n + 63) >> 6) * 4;
      } else {
        n = cnts[(seg - 8) * 16];
        tseg = (n + 63) >> 6;
      }
      if (rem < tseg) { nrows = n; break; }
      rem -= tseg;
    }
    if (seg == 12) return;
    if (seg < 8) {
      int r = seg >> 1, sel = seg & 1;
      int rt = rem >> 2, ct = rem & 3;
      const int* list = (sel ? hotlist : srclist) + r * NN;
      const unsigned short* W = (sel ? Wr : Wl) + (size_t)r * 512 * 128;
      const float* bias = (sel ? br : bl) + (size_t)r * 512;
      unsigned short* C = sel ? (xrh + (size_t)r * CAPH * 512) : (xlb + (size_t)r * CAPS * 512);
      gemm_direct<128>(hbf, list, W, bias, nullptr, C, nrows, 512, 0, rt * 64, ct * 128);
    } else {
      int r = seg - 8;
      int rowBase = rem * 64;
      const unsigned short* ap[2];
#pragma unroll
      for (int mt = 0; mt < 2; ++mt) {
        int gr = rowBase + wm * 32 + mt * 16 + mr;
        int idx = (gr < nrows) ? solosrc[r * NN + gr] : 0;
        ap[mt] = hbf + (size_t)idx * HID + q * 8;
      }
      const unsigned short* wp[4];
#pragma unroll
      for (int nt = 0; nt < 4; ++nt)
        wp[nt] = wsum + (size_t)r * 16384 + (size_t)(wn * 64 + nt * 16 + mr) * HID + q * 8;
      f32x4 acc[2][4] = {};
#pragma unroll
      for (int k = 0; k < 4; ++k) {
        bf16x8 af[2], bfr[4];
#pragma unroll
        for (int mt = 0; mt < 2; ++mt) af[mt] = *(const bf16x8*)(ap[mt] + k * 32);
#pragma unroll
        for (int nt = 0; nt < 4; ++nt) bfr[nt] = *(const bf16x8*)(wp[nt] + k * 32);
#pragma unroll
        for (int mt = 0; mt < 2; ++mt)
#pragma unroll
          for (int nt = 0; nt < 4; ++nt)
            acc[mt][nt] = __builtin_amdgcn_mfma_f32_16x16x32_bf16(af[mt], bfr[nt], acc[mt][nt], 0, 0, 0);
      }
      float g4 = gate[r] * 0.25f;
      float bv[4];
#pragma unroll
      for (int nt = 0; nt < 4; ++nt) bv[nt] = bsum[r * 128 + wn * 64 + nt * 16 + mr];
#pragma unroll
      for (int mt = 0; mt < 2; ++mt)
#pragma unroll
        for (int rr = 0; rr < 4; ++rr) {
          int row = rowBase + wm * 32 + mt * 16 + q * 4 + rr;
          if (row < nrows) {
            int dst = solodst[r * NN + row];
#pragma unroll
            for (int nt = 0; nt < 4; ++nt) {
              int col = wn * 64 + nt * 16 + mr;
              atomicAdd(&hmsg[(size_t)dst * HID + col], g4 * (acc[mt][nt][rr] + bv[nt]));
            }
          }
        }
    }
    __syncthreads();  // LDS WAR between tiles (solo iterations participate too)
  }
}

// head-summed lin_l weights/bias per (layer,rel): Wsum[o][k] = sum_h Wl[h*128+o][k]
__global__ void wsum_build(const float* __restrict__ linlw, const float* __restrict__ linlb,
                           unsigned short* __restrict__ wsum, float* __restrict__ bsum) {
  int i = blockIdx.x * blockDim.x + threadIdx.x;
  if (i >= NL * NR * 128 * 128) return;
  int k = i & 127, o = (i >> 7) & 127, lr = i >> 14;
  float s = 0.f;
#pragma unroll
  for (int h = 0; h < NH; ++h) s += linlw[((size_t)lr * 512 + h * 128 + o) * 128 + k];
  wsum[i] = f2b(s);
  if (k == 0) {
    float b = 0.f;
#pragma unroll
    for (int h = 0; h < NH; ++h) b += linlb[(size_t)lr * 512 + h * 128 + o];
    bsum[lr * 128 + o] = b;
  }
}

// ---- layer tail: LN1(h+hmsg+cb) -> y (REGISTERS, not re-read from HBM);
// zeroes hmsg for the next layer (replaces per-layer memset);
// f1=silu(y@W1^T+b1); f2=f1@W2^T+b2; h=LN2(y+f2); emits hbf (post-LN2).
__global__ __launch_bounds__(256, 2) void layer_tail(
    float* __restrict__ h, float* __restrict__ hmsg, const float* __restrict__ cb,
    const float* __restrict__ n1w, const float* __restrict__ n1b,
    const unsigned short* __restrict__ W1, const float* __restrict__ b1,
    const unsigned short* __restrict__ W2, const float* __restrict__ b2,
    const float* __restrict__ n2w, const float* __restrict__ n2b,
    unsigned short* __restrict__ hbfout) {
  __shared__ __align__(16) char smem[64 * 136 * 2 + 64 * 264 * 2];
  unsigned short (*Y)[136] = (unsigned short (*)[136])smem;
  unsigned short (*F1)[264] = (unsigned short (*)[264])(smem + 64 * 136 * 2);
  float (*Ef)[132] = (float (*)[132])(smem + 64 * 136 * 2);
  int nbr = (NN + 63) >> 6;
  int rpx = (nbr + 7) >> 3;
  int xcd = blockIdx.x & 7, j = blockIdx.x >> 3;
  int rowT = xcd * rpx + j;
  if (rowT >= nbr) return;
  int rowBase = rowT * 64;

  int t = threadIdx.x;
  int lane = t & 63, w = t >> 6;
  int wm = w >> 1, wn = w & 1;
  int q = lane >> 4, mr = lane & 15;

  // ---- phase 0: LN1 over own 64 rows (wave-per-row); y kept in regs (static idx)
  float y0r[16], y1r[16];
  {
    float w0 = n1w[lane], w1 = n1w[64 + lane];
    float bb0 = n1b[lane], bb1 = n1b[64 + lane];
    float c0 = cb[lane], c1 = cb[64 + lane];
#pragma unroll
    for (int it = 0; it < 16; ++it) {
      int rr = it * 4 + w;
      int grow = rowBase + rr;
      if (grow < NN) {
        size_t base = (size_t)grow * HID;
        float x0 = h[base + lane] + hmsg[base + lane] + c0;
        float x1 = h[base + 64 + lane] + hmsg[base + 64 + lane] + c1;
        hmsg[base + lane] = 0.f;        // zero for next layer (fused memset)
        hmsg[base + 64 + lane] = 0.f;
        float s = x0 + x1;
#pragma unroll
        for (int o = 32; o > 0; o >>= 1) s += __shfl_xor(s, o, 64);
        float mean = s * (1.f / 128.f);
        float d0 = x0 - mean, d1 = x1 - mean;
        float v = d0 * d0 + d1 * d1;
#pragma unroll
        for (int o = 32; o > 0; o >>= 1) v += __shfl_xor(v, o, 64);
        float inv = 1.f / sqrtf(v * (1.f / 128.f) + 1e-5f);
        float y0 = d0 * inv * w0 + bb0;
        float y1 = d1 * inv * w1 + bb1;
        y0r[it] = y0;
        y1r[it] = y1;
        Y[rr][lane] = f2b(y0);
        Y[rr][64 + lane] = f2b(y1);
      } else {
        y0r[it] = 0.f;
        y1r[it] = 0.f;
        Y[rr][lane] = 0;
        Y[rr][64 + lane] = 0;
      }
    }
  }
  __syncthreads();

  // ---- phase A: f1 = silu(y @ W1^T + b1), A-frags from Y LDS
  bf16x8 a[2][4];
#pragma unroll
  for (int mt = 0; mt < 2; ++mt)
#pragma unroll
    for (int k = 0; k < 4; ++k)
      a[mt][k] = *(const bf16x8*)&Y[wm * 32 + mt * 16 + mr][k * 32 + q * 8];

#pragma unroll
  for (int ph = 0; ph < 2; ++ph) {
    const unsigned short* wp[4];
#pragma unroll
    for (int nt = 0; nt < 4; ++nt)
      wp[nt] = W1 + (size_t)(ph * 128 + wn * 64 + nt * 16 + mr) * HID + q * 8;
    f32x4 acc[2][4] = {};
#pragma unroll
    for (int k = 0; k < 4; ++k) {
      bf16x8 bfr[4];
#pragma unroll
      for (int nt = 0; nt < 4; ++nt) bfr[nt] = *(const bf16x8*)(wp[nt] + k * 32);
#pragma unroll
      for (int mt = 0; mt < 2; ++mt)
#pragma unroll
        for (int nt = 0; nt < 4; ++nt)
          acc[mt][nt] = __builtin_amdgcn_mfma_f32_16x16x32_bf16(a[mt][k], bfr[nt], acc[mt][nt], 0, 0, 0);
    }
    float bv[4];
#pragma unroll
    for (int nt = 0; nt < 4; ++nt) bv[nt] = b1[ph * 128 + wn * 64 + nt * 16 + mr];
#pragma unroll
    for (int mt = 0; mt < 2; ++mt)
#pragma unroll
      for (int nt = 0; nt < 4; ++nt)
#pragma unroll
        for (int r = 0; r < 4; ++r) {
          float v = acc[mt][nt][r] + bv[nt];
          v = v / (1.f + expf(-v));
          F1[wm * 32 + mt * 16 + q * 4 + r][ph * 128 + wn * 64 + nt * 16 + mr] = f2b(v);
        }
  }
  __syncthreads();

  // ---- phase B: f2 = f1 @ W2^T (K=256), A from LDS, W2 from L2
  const unsigned short* wp2[4];
#pragma unroll
  for (int nt = 0; nt < 4; ++nt)
    wp2[nt] = W2 + (size_t)(wn * 64 + nt * 16 + mr) * FFH + q * 8;
  f32x4 acc2[2][4] = {};
#pragma unroll
  for (int k = 0; k < 8; ++k) {
    bf16x8 af[2], bfr[4];
#pragma unroll
    for (int mt = 0; mt < 2; ++mt)
      af[mt] = *(const bf16x8*)&F1[wm * 32 + mt * 16 + mr][k * 32 + q * 8];
#pragma unroll
    for (int nt = 0; nt < 4; ++nt) bfr[nt] = *(const bf16x8*)(wp2[nt] + k * 32);
#pragma unroll
    for (int mt = 0; mt < 2; ++mt)
#pragma unroll
      for (int nt = 0; nt < 4; ++nt)
        acc2[mt][nt] = __builtin_amdgcn_mfma_f32_16x16x32_bf16(af[mt], bfr[nt], acc2[mt][nt], 0, 0, 0);
  }
  __syncthreads();  // all F1 reads done before overwriting as Ef

  // ---- phase C: stage f2+b2 in LDS (f32), then LN2(y + f2) -> h, hbf
  float bv2[4];
#pragma unroll
  for (int nt = 0; nt < 4; ++nt) bv2[nt] = b2[wn * 64 + nt * 16 + mr];
#pragma unroll
  for (int mt = 0; mt < 2; ++mt)
#pragma unroll
    for (int nt = 0; nt < 4; ++nt)
#pragma unroll
      for (int r = 0; r < 4; ++r)
        Ef[wm * 32 + mt * 16 + q * 4 + r][wn * 64 + nt * 16 + mr] = acc2[mt][nt][r] + bv2[nt];
  __syncthreads();

  float w0 = n2w[lane], w1 = n2w[64 + lane];
  float bb0 = n2b[lane], bb1 = n2b[64 + lane];
#pragma unroll
  for (int it = 0; it < 16; ++it) {
    int rr = it * 4 + w;
    int grow = rowBase + rr;
    if (grow >= NN) continue;
    size_t base = (size_t)grow * HID;
    float x0 = y0r[it] + Ef[rr][lane];   // y from regs: no HBM round-trip
    float x1 = y1r[it] + Ef[rr][64 + lane];
    float s = x0 + x1;
#pragma unroll
    for (int o = 32; o > 0; o >>= 1) s += __shfl_xor(s, o, 64);
    float mean = s * (1.f / 128.f);
    float d0 = x0 - mean, d1 = x1 - mean;
    float v = d0 * d0 + d1 * d1;
#pragma unroll
    for (int o = 32; o > 0; o >>= 1) v += __shfl_xor(v, o, 64);
    float inv = 1.f / sqrtf(v * (1.f / 128.f) + 1e-5f);
    float y0 = d0 * inv * w0 + bb0;
    float y1 = d1 * inv * w1 + bb1;
    h[base + lane] = y0;
    h[base + 64 + lane] = y1;
    hbfout[base + lane] = f2b(y0);
    hbfout[base + 64 + lane] = f2b(y1);
  }
}

__global__ void build_xin_bf(const float* __restrict__ x, const int* __restrict__ idtok,
                             const float* __restrict__ emb, unsigned short* __restrict__ xin) {
  int i = blockIdx.x * blockDim.x + threadIdx.x;
  if (i >= NN * 96) return;
  int n = i / 96, k = i - n * 96;
  float v = (k < FN) ? x[(size_t)n * FN + k] : emb[(size_t)idtok[n] * IDE + (k - FN)];
  xin[i] = f2b(v);
}

// ---- CSR by (rel, dst) ----
__global__ void hist_bin(const int* __restrict__ ei, const int* __restrict__ et,
                         int* __restrict__ bcnt) {
  int e = blockIdx.x * blockDim.x + threadIdx.x;
  if (e >= NE) return;
  atomicAdd(&bcnt[et[e] * NN + ei[NE + e]], 1);
}
__global__ __launch_bounds__(256) void scan1(const int* __restrict__ cnt,
                                             int* __restrict__ pos, int* __restrict__ bsum) {
  __shared__ int lds[256];
  int b = blockIdx.x, t = threadIdx.x;
  int base = b * 1024 + t * 4;
  int v[4];
#pragma unroll
  for (int j = 0; j < 4; ++j) v[j] = (base + j < NBIN) ? cnt[base + j] : 0;
  int tot = v[0] + v[1] + v[2] + v[3];
  lds[t] = tot;
  __syncthreads();
  for (int off = 1; off < 256; off <<= 1) {
    int x = (t >= off) ? lds[t - off] : 0;
    __syncthreads();
    lds[t] += x;
    __syncthreads();
  }
  if (t == 255) bsum[b] = lds[255];
  int run = lds[t] - tot;
#pragma unroll
  for (int j = 0; j < 4; ++j) {
    if (base + j < NBIN) pos[base + j] = run;
    run += v[j];
  }
}
__global__ __launch_bounds__(256) void scan2(int* __restrict__ bsum) {
  __shared__ int lds[256];
  int t = threadIdx.x;
  int v = (t < SCAN_BLK) ? bsum[t] : 0;
  lds[t] = v;
  __syncthreads();
  for (int off = 1; off < 256; off <<= 1) {
    int x = (t >= off) ? lds[t - off] : 0;
    __syncthreads();
    lds[t] += x;
    __syncthreads();
  }
  if (t < SCAN_BLK) bsum[t] = lds[t] - v;
}
__global__ void scan3(int* __restrict__ pos, const int* __restrict__ bsum,
                      const int* __restrict__ cnt) {
  int i = blockIdx.x * blockDim.x + threadIdx.x;
  if (i >= NBIN) return;
  pos[i] += bsum[i >> 10];
  if (i == NBIN - 1) pos[NBIN] = pos[i] + cnt[i];
}
__global__ void scatter_bin(const int* __restrict__ ei, const int* __restrict__ et,
                            const int* __restrict__ csroff, int* __restrict__ cur,
                            int* __restrict__ elist) {
  int e = blockIdx.x * blockDim.x + threadIdx.x;
  if (e >= NE) return;
  int bin = et[e] * NN + ei[NE + e];
  int p = atomicAdd(&cur[bin], 1);
  elist[csroff[bin] + p] = e;
}
// DETERMINISM: atomic scatter order varies call-to-call; sort each bin.
__global__ void sort_bins(const int* __restrict__ csroff, int* __restrict__ elist) {
  int b = blockIdx.x * blockDim.x + threadIdx.x;
  if (b >= NBIN) return;
  int s = csroff[b], e = csroff[b + 1];
  for (int i = s + 1; i < e; ++i) {
    int key = elist[i];
    int j = i - 1;
    while (j >= s && elist[j] > key) { elist[j + 1] = elist[j]; --j; }
    elist[j + 1] = key;
  }
}
// gather edge attrs into CSR order + flag hot-srcs inline (deg>=2 bins only)
__global__ void gather_edge(const int* __restrict__ ei, const int* __restrict__ et,
                            const int* __restrict__ elist, const int* __restrict__ csroff,
                            const float* __restrict__ eattr,
                            int* __restrict__ rsrc, float* __restrict__ eacsr,
                            int* __restrict__ srcflag) {
  int p = blockIdx.x * blockDim.x + threadIdx.x;
  if (p >= NE) return;
  int e = elist[p];
  int src = ei[e];
  rsrc[p] = src;
  const float4* s = (const float4*)(eattr + (size_t)e * NEA);
  float4* d = (float4*)(eacsr + (size_t)p * NEA);
#pragma unroll
  for (int j = 0; j < 4; ++j) d[j] = s[j];
  int bin = et[e] * NN + ei[NE + e];
  if (csroff[bin + 1] - csroff[bin] >= 2) srcflag[et[e] * NN + src] = 1;
}
// ORDERED hot-src compaction from scan positions (deterministic + sequential gather)
__global__ void build_src_o(const int* __restrict__ srcflag, const int* __restrict__ srcpos,
                            int* __restrict__ srclist, int* __restrict__ srcmap) {
  int b = blockIdx.x * blockDim.x + threadIdx.x;
  if (b >= NBIN) return;
  if (srcflag[b]) {
    int rel = b / NN;
    int pos = srcpos[b] - srcpos[rel * NN];
    srcmap[b] = pos;
    srclist[rel * NN + pos] = b - rel * NN;
  }
}
__global__ void fincnt(const int* __restrict__ srcpos, int* __restrict__ nsrc) {
  int r = threadIdx.x;
  if (r < NR) nsrc[r * 16] = srcpos[(r + 1) * NN] - srcpos[r * NN];
}
// rsrcx: hot-src row index per edge position (garbage for solo positions, unread)
__global__ void remap_rsrc(const int* __restrict__ csroff, const int* __restrict__ rsrc,
                           const int* __restrict__ srcmap, int* __restrict__ rsrcx) {
  int p = blockIdx.x * blockDim.x + threadIdx.x;
  if (p >= NE) return;
  int rel = (p >= csroff[NN]) + (p >= csroff[2 * NN]) + (p >= csroff[3 * NN]);
  rsrcx[p] = srcmap[rel * NN + rsrc[p]];
}
// per-rel solo (deg==1: ORIGINAL src id + dst) + hot (deg>=2) lists.
__global__ __launch_bounds__(256) void build_hot(
    const int* __restrict__ csroff, const int* __restrict__ rsrc,
    int* __restrict__ nsolo, int* __restrict__ nhot,
    int* __restrict__ solosrc, int* __restrict__ solodst, int* __restrict__ hotlist) {
  __shared__ int wsc[4][4], whc[4][4];
  __shared__ int sbase[4], hbase[4];
  int t = threadIdx.x, wave = t >> 6, lane = t & 63;
  int b = blockIdx.x * 256 + t;
  bool valid = b < NBIN;
  int cnt = 0, rel = 0, s = 0;
  if (valid) { s = csroff[b]; cnt = csroff[b + 1] - s; rel = b / NN; }
  bool solo = valid && cnt == 1;
  bool hot = valid && cnt >= 2;
#pragma unroll
  for (int rr = 0; rr < 4; ++rr) {
    unsigned long long ms = __ballot(solo && rel == rr);
    unsigned long long mh = __ballot(hot && rel == rr);
    if (lane == 0) { wsc[wave][rr] = __popcll(ms); whc[wave][rr] = __popcll(mh); }
  }
  __syncthreads();
  if (t < 4) {
    int ssum = wsc[0][t] + wsc[1][t] + wsc[2][t] + wsc[3][t];
    int hsum = whc[0][t] + whc[1][t] + whc[2][t] + whc[3][t];
    sbase[t] = ssum ? atomicAdd(&nsolo[t * 16], ssum) : 0;
    hbase[t] = hsum ? atomicAdd(&nhot[t * 16], hsum) : 0;
  }
  __syncthreads();
#pragma unroll
  for (int rr = 0; rr < 4; ++rr) {
    unsigned long long ms = __ballot(solo && rel == rr);
    if (solo && rel == rr) {
      int before = 0;
#pragma unroll
      for (int wv = 0; wv < 4; ++wv) if (wv < wave) before += wsc[wv][rr];
      int pos = sbase[rr] + before + __popcll(ms & ((1ull << lane) - 1ull));
      solosrc[rr * NN + pos] = rsrc[s];
      solodst[rr * NN + pos] = b - rr * NN;
    }
    unsigned long long mh = __ballot(hot && rel == rr);
    if (hot && rel == rr) {
      int before = 0;
#pragma unroll
      for (int wv = 0; wv < 4; ++wv) if (wv < wave) before += whc[wv][rr];
      int pos = hbase[rr] + before + __popcll(mh & ((1ull << lane) - 1ull));
      hotlist[rr * NN + pos] = b - rr * NN;
    }
  }
}

// all-layers gate softmax + gated conv bias in one launch (block = layer)
__global__ void gate_cb_all(const float* __restrict__ rg, const float* __restrict__ cbias,
                            float* __restrict__ gate, float* __restrict__ cb) {
  __shared__ float g[NR];
  int l = blockIdx.x, t = threadIdx.x;
  const float* rgl = rg + l * NR;
  if (t == 0) {
    float mx = rgl[0];
    for (int r = 1; r < NR; ++r) mx = fmaxf(mx, rgl[r]);
    float s = 0.f, tmp[NR];
    for (int r = 0; r < NR; ++r) { tmp[r] = expf(rgl[r] - mx); s += tmp[r]; }
    for (int r = 0; r < NR; ++r) { g[r] = tmp[r] / s; gate[l * NR + r] = g[r]; }
  }
  __syncthreads();
  float c = 0.f;
  for (int r = 0; r < NR; ++r) c += g[r] * cbias[(size_t)l * NR * HID + r * HID + t];
  cb[l * HID + t] = c;
}

// ---- merged hot edge pass: ALL 4 rels in one launch (rel = bid&3, grid-stride
// within rel so weight regs load once per block). Block/dst online softmax.
// hmsg accumulation via atomicAdd (<=4 rel contributions + solo adds per dst;
// fp32 reorder noise ~ulp vs 2e-3 tolerance).
__global__ __launch_bounds__(256) void edge_merged(
    const int* __restrict__ csroff, const int* __restrict__ rsrcx,
    const float* __restrict__ eacsr, const float* __restrict__ relembL,
    const float* __restrict__ wedgeL, const float* __restrict__ attwL,
    const unsigned short* __restrict__ xlb, const unsigned short* __restrict__ xrh,
    const int* __restrict__ hotlist, const int* __restrict__ nhot,
    float* __restrict__ hmsg, const float* __restrict__ gate) {
  __shared__ float lds[4][128];
  int wave = threadIdx.x >> 6, lane = threadIdx.x & 63;
  int rel = blockIdx.x & 3;
  int b0 = blockIdx.x >> 2;
  int bstride = gridDim.x >> 2;
  float g4 = gate[rel] * 0.25f;
  int hh = wave;
  const float* wedgep = wedgeL + (size_t)rel * 512 * 24;
  const float* attwp = attwL + (size_t)rel * 512;
  const float* relembp = relembL + rel * RED;
  const unsigned short* xlbase = xlb + (size_t)rel * CAPS * 512;
  const unsigned short* xrbase = xrh + (size_t)rel * CAPH * 512;
  float wreg[2][24], areg[2];
#pragma unroll
  for (int j = 0; j < 2; ++j) {
    int col = hh * 128 + j * 64 + lane;
    const float* wp = wedgep + (size_t)col * 24;
#pragma unroll
    for (int k = 0; k < 24; ++k) wreg[j][k] = wp[k];
    areg[j] = attwp[col];
  }
  float evr0 = 0.f, evr1 = 0.f;
#pragma unroll
  for (int k = 0; k < 8; ++k) {
    float rk = relembp[k];
    evr0 += rk * wreg[0][NEA + k];
    evr1 += rk * wreg[1][NEA + k];
  }
  int nh = nhot[rel * 16];
  for (int wi = b0; wi < nh; wi += bstride) {
    int dst = hotlist[rel * NN + wi];
    int s = csroff[rel * NN + dst], e = csroff[rel * NN + dst + 1];
    {
      const unsigned short* xrp = xrbase + (size_t)wi * 512;
      float xr0 = b2f(xrp[hh * 128 + lane]);
      float xr1 = b2f(xrp[hh * 128 + 64 + lane]);
      float m = -3.4e38f, den = 0.f, acc0 = 0.f, acc1 = 0.f;
      for (int p = s; p < e; ++p) {
        int src = rsrcx[p];
        const float* eap = eacsr + (size_t)p * NEA;
        float eev0 = evr0, eev1 = evr1;
#pragma unroll
        for (int k = 0; k < NEA; ++k) {
          float er = eap[k];
          eev0 += er * wreg[0][k];
          eev1 += er * wreg[1][k];
        }
        float xl0 = b2f(xlbase[(size_t)src * 512 + hh * 128 + lane]);
        float xl1 = b2f(xlbase[(size_t)src * 512 + hh * 128 + 64 + lane]);
        float s0 = xl0 + xr0 + eev0; s0 = (s0 > 0.f) ? s0 : 0.2f * s0;
        float s1 = xl1 + xr1 + eev1; s1 = (s1 > 0.f) ? s1 : 0.2f * s1;
        float lg = s0 * areg[0] + s1 * areg[1];
#pragma unroll
        for (int o = 32; o > 0; o >>= 1) lg += __shfl_xor(lg, o, 64);
        float mn = fmaxf(m, lg);
        float sc = expf(m - mn);
        float ex = expf(lg - mn);
        den = den * sc + ex;
        acc0 = acc0 * sc + ex * xl0;
        acc1 = acc1 * sc + ex * xl1;
        m = mn;
      }
      float wgt = g4 / den;
      lds[wave][lane] = acc0 * wgt;
      lds[wave][64 + lane] = acc1 * wgt;
    }
    __syncthreads();
    if (wave < 2) {
      int d = wave * 64 + lane;
      float v = lds[0][d] + lds[1][d] + lds[2][d] + lds[3][d];
      atomicAdd(&hmsg[(size_t)dst * HID + d], v);
    }
    __syncthreads();
  }
}

// ---- readout: deterministic ----
__global__ void group_bounds(const int* __restrict__ batch, int* __restrict__ gstart) {
  int g = threadIdx.x + blockIdx.x * blockDim.x;
  if (g > NG) return;
  int lo = 0, hi = NN;
  while (lo < hi) {
    int mid = (lo + hi) >> 1;
    if (batch[mid] < g) lo = mid + 1; else hi = mid;
  }
  gstart[g] = lo;
}
__global__ __launch_bounds__(128) void readout_part2(
    const float* __restrict__ h, const int* __restrict__ gstart,
    float* __restrict__ psum, float* __restrict__ pmax) {
  int g = blockIdx.x, s = blockIdx.y, t = threadIdx.x;
  int r0 = gstart[g], r1 = gstart[g + 1];
  float acc = 0.f, mx = -3.4e38f;
  for (int row = r0 + s; row < r1; row += 8) {
    float v = h[(size_t)row * HID + t];
    acc += v;
    mx = fmaxf(mx, v);
  }
  psum[((size_t)g * 8 + s) * HID + t] = acc;
  pmax[((size_t)g * 8 + s) * HID + t] = mx;
}
__global__ __launch_bounds__(256) void readout_final(
    const int* __restrict__ gstart, const float* __restrict__ psum,
    const float* __restrict__ pmax, const float* __restrict__ w,
    const float* __restrict__ b, float* __restrict__ g) {
  int bg = blockIdx.x, t = threadIdx.x;
  __shared__ float red[256];
  float c = fmaxf((float)(gstart[bg + 1] - gstart[bg]), 1.f);
  float x;
  if (t < HID) {
    float ssum = 0.f;
    for (int s = 0; s < 8; ++s) ssum += psum[((size_t)bg * 8 + s) * HID + t];
    x = ssum / c;
  } else {
    float mx = -3.4e38f;
    for (int s = 0; s < 8; ++s) mx = fmaxf(mx, pmax[((size_t)bg * 8 + s) * HID + (t - HID)]);
    x = mx;
  }
  red[t] = x;
  __syncthreads();
  for (int s = 128; s > 0; s >>= 1) {
    if (t < s) red[t] += red[t + s];
    __syncthreads();
  }
  float mean = red[0] * (1.f / 256.f);
  __syncthreads();
  float d = x - mean;
  red[t] = d * d;
  __syncthreads();
  for (int s = 128; s > 0; s >>= 1) {
    if (t < s) red[t] += red[t + s];
    __syncthreads();
  }
  float inv = 1.f / sqrtf(red[0] * (1.f / 256.f) + 1e-5f);
  g[(size_t)bg * 256 + t] = d * inv * w[t] + b[t];
}

__device__ __forceinline__ void bspline8(float x, const float* __restrict__ t,
                                         float* __restrict__ out) {
  float bs[11];
#pragma unroll
  for (int j = 0; j < 11; ++j) bs[j] = (x >= t[j] && x < t[j + 1]) ? 1.f : 0.f;
#pragma unroll
  for (int k = 1; k <= 3; ++k) {
    for (int j = 0; j < 11 - k; ++j) {
      bs[j] = (x - t[j]) / (t[j + k] - t[j]) * bs[j] +
              (t[j + k + 1] - x) / (t[j + k + 1] - t[j + 1]) * bs[j + 1];
    }
  }
#pragma unroll
  for (int j = 0; j < 8; ++j) out[j] = bs[j];
}

// ---- KAN1, K-chunked into fixed partial slots (deterministic) ----
__global__ __launch_bounds__(128) void kan1_part(
    const float* __restrict__ g, const float* __restrict__ bw,
    const float* __restrict__ sw, const float* __restrict__ sc,
    const float* __restrict__ grid, float* __restrict__ zpart) {
  int bg = blockIdx.x, ch = blockIdx.y, t = threadIdx.x;
  int base = ch * 32;
  __shared__ float B[32][8];
  __shared__ float sg[32];
  if (t < 32) {
    float x = g[(size_t)bg * 256 + base + t];
    sg[t] = x / (1.f + expf(-x));
    bspline8(x, grid + (size_t)(base + t) * 12, B[t]);
  }
  __syncthreads();
  float acc = 0.f;
  for (int i = 0; i < 32; ++i) {
    int col = base + i;
    acc += sg[i] * bw[(size_t)t * 256 + col];
    const float* swp = sw + ((size_t)t * 256 + col) * 8;
    float sp = 0.f;
#pragma unroll
    for (int k = 0; k < 8; ++k) sp += B[i][k] * swp[k];
    acc += sp * sc[(size_t)t * 256 + col];
  }
  zpart[((size_t)ch * NG + bg) * KH + t] = acc;
}

__global__ __launch_bounds__(128) void kan2(
    const float* __restrict__ zpart, const float* __restrict__ bw,
    const float* __restrict__ sw, const float* __restrict__ sc,
    const float* __restrict__ grid, float* __restrict__ out) {
  int bg = blockIdx.x, t = threadIdx.x;
  __shared__ float B[128][8];
  __shared__ float sz[128];
  float x = 0.f;
  for (int ch = 0; ch < 8; ++ch) x += zpart[((size_t)ch * NG + bg) * KH + t];
  sz[t] = x / (1.f + expf(-x));
  bspline8(x, grid + (size_t)t * 12, B[t]);
  __syncthreads();
  if (t < NC) {
    float acc = 0.f;
    for (int i = 0; i < 128; ++i) {
      acc += sz[i] * bw[(size_t)t * 128 + i];
      const float* swp = sw + ((size_t)t * 128 + i) * 8;
      float sp = 0.f;
#pragma unroll
      for (int k = 0; k < 8; ++k) sp += B[i][k] * swp[k];
      acc += sp * sc[(size_t)t * 128 + i];
    }
    out[(size_t)bg * NC + t] = acc;
  }
}

extern "C" void kernel_launch(void* const* d_in, const int* in_sizes, int n_in,
                              void* d_out, int out_size, void* d_ws, size_t ws_size,
                              hipStream_t stream) {
  const float* x       = (const float*)d_in[0];
  const float* eattr   = (const float*)d_in[1];
  const int*   idtok   = (const int*)d_in[2];
  const int*   ei      = (const int*)d_in[3];
  const int*   etype   = (const int*)d_in[4];
  const int*   batch   = (const int*)d_in[5];
  const float* idemb   = (const float*)d_in[6];
  const float* inw     = (const float*)d_in[7];
  const float* inb     = (const float*)d_in[8];
  const float* relemb  = (const float*)d_in[9];
  const float* linlw   = (const float*)d_in[10];
  const float* linlb   = (const float*)d_in[11];
  const float* linrw   = (const float*)d_in[12];
  const float* linrb   = (const float*)d_in[13];
  const float* linew   = (const float*)d_in[14];
  const float* attw    = (const float*)d_in[15];
  const float* convb   = (const float*)d_in[16];
  const float* relgate = (const float*)d_in[17];
  const float* n1w     = (const float*)d_in[18];
  const float* n1b     = (const float*)d_in[19];
  const float* n2w     = (const float*)d_in[20];
  const float* n2b     = (const float*)d_in[21];
  const float* f1w     = (const float*)d_in[22];
  const float* f1bias  = (const float*)d_in[23];
  const float* f2w     = (const float*)d_in[24];
  const float* f2bias  = (const float*)d_in[25];
  const float* rnw     = (const float*)d_in[26];
  const float* rnb     = (const float*)d_in[27];
  const float* bw1     = (const float*)d_in[28];
  const float* sw1     = (const float*)d_in[29];
  const float* sc1     = (const float*)d_in[30];
  const float* grid1   = (const float*)d_in[31];
  const float* bw2     = (const float*)d_in[32];
  const float* sw2     = (const float*)d_in[33];
  const float* sc2     = (const float*)d_in[34];
  const float* grid2   = (const float*)d_in[35];
  float* out = (float*)d_out;
  (void)in_sizes; (void)n_in; (void)out_size; (void)ws_size;

  char* p = (char*)d_ws;
  auto alloc = [&](size_t bytes) { void* q = (void*)p; p += (bytes + 255) & ~(size_t)255; return q; };
  float* h    = (float*)alloc((size_t)NN * HID * 4);
  float* hmsg = (float*)alloc((size_t)NN * HID * 4);
  unsigned short* hbf = (unsigned short*)alloc((size_t)NN * HID * 2);
  unsigned short* xlb = (unsigned short*)alloc((size_t)NR * CAPS * 512 * 2);  // 134.2MB
  unsigned short* xrh = (unsigned short*)alloc((size_t)NR * CAPH * 512 * 2);  // 37.7MB
  int* elist = (int*)alloc((size_t)NE * 4);
  int* rsrc  = (int*)alloc((size_t)NE * 4);
  int* rsrcx = (int*)alloc((size_t)NE * 4);
  float* eacsr = (float*)alloc((size_t)NE * NEA * 4);
  int* bcnt  = (int*)alloc((size_t)NBIN * 8 + 8);
  int* cur   = bcnt + NBIN;
  int* csroff = (int*)alloc((size_t)(NBIN + 1) * 4);
  int* srcpos = (int*)alloc((size_t)(NBIN + 1) * 4);
  int* bsum  = (int*)alloc((size_t)SCAN_BLK * 4);
  int* hotlist = (int*)alloc((size_t)NR * NN * 4);
  int* solosrc = (int*)alloc((size_t)NR * NN * 4);
  int* solodst = (int*)alloc((size_t)NR * NN * 4);
  int* srclist = (int*)alloc((size_t)NR * NN * 4);
  int* srcflag = (int*)alloc((size_t)NBIN * 4);
  int* srcmap  = (int*)alloc((size_t)NBIN * 4);
  int* cnts    = (int*)alloc(1024);
  int* nsolo   = cnts;
  int* nhot    = cnts + 64;
  int* nsrc    = cnts + 128;
  unsigned short* linlwb = (unsigned short*)alloc((size_t)NL * NR * 512 * 128 * 2);
  unsigned short* linrwb = (unsigned short*)alloc((size_t)NL * NR * 512 * 128 * 2);
  unsigned short* f1wb   = (unsigned short*)alloc((size_t)NL * 256 * 128 * 2);
  unsigned short* f2wb   = (unsigned short*)alloc((size_t)NL * 128 * 256 * 2);
  unsigned short* inwb   = (unsigned short*)alloc((size_t)128 * 96 * 2);
  unsigned short* wsumb  = (unsigned short*)alloc((size_t)NL * NR * 128 * 128 * 2);
  float* bsumf = (float*)alloc((size_t)NL * NR * 128 * 4);
  float* gate = (float*)alloc(NL * NR * 4);
  float* cb   = (float*)alloc(NL * HID * 4);
  int* gstart = (int*)alloc((size_t)(NG + 1) * 4);
  float* psum = (float*)alloc((size_t)NG * 8 * HID * 4);
  float* pmax = (float*)alloc((size_t)NG * 8 * HID * 4);
  float* zpart = (float*)alloc((size_t)8 * NG * KH * 4);
  float* g = (float*)alloc((size_t)NG * 256 * 4);
  unsigned short* xinbf = xlb;  // aliased: in-proj input staged before layer loop

  const int NB64 = (NN + 63) / 64;
  const int RPX = (NB64 + 7) / 8;

  {
    int n;
    n = NL * NR * 512 * 128 / 4;
    cvt_bf16<<<(n + 255) / 256, 256, 0, stream>>>(linlw, linlwb, n);
    cvt_bf16<<<(n + 255) / 256, 256, 0, stream>>>(linrw, linrwb, n);
    n = NL * 256 * 128 / 4;
    cvt_bf16<<<(n + 255) / 256, 256, 0, stream>>>(f1w, f1wb, n);
    cvt_bf16<<<(n + 255) / 256, 256, 0, stream>>>(f2w, f2wb, n);
    n = 128 * 96 / 4;
    cvt_bf16<<<(n + 255) / 256, 256, 0, stream>>>(inw, inwb, n);
  }
  wsum_build<<<(NL * NR * 128 * 128 + 255) / 256, 256, 0, stream>>>(linlw, linlb, wsumb, bsumf);

  hipMemsetAsync(bcnt, 0, (size_t)NBIN * 8 + 8, stream);
  hipMemsetAsync(srcflag, 0, (size_t)NBIN * 4, stream);
  hipMemsetAsync(cnts, 0, 1024, stream);
  hist_bin<<<(NE + 255) / 256, 256, 0, stream>>>(ei, etype, bcnt);
  scan1<<<SCAN_BLK, 256, 0, stream>>>(bcnt, csroff, bsum);
  scan2<<<1, 256, 0, stream>>>(bsum);
  scan3<<<(NBIN + 255) / 256, 256, 0, stream>>>(csroff, bsum, bcnt);
  scatter_bin<<<(NE + 255) / 256, 256, 0, stream>>>(ei, etype, csroff, cur, elist);
  sort_bins<<<(NBIN + 255) / 256, 256, 0, stream>>>(csroff, elist);
  gather_edge<<<(NE + 255) / 256, 256, 0, stream>>>(ei, etype, elist, csroff, eattr,
                                                    rsrc, eacsr, srcflag);
  scan1<<<SCAN_BLK, 256, 0, stream>>>(srcflag, srcpos, bsum);
  scan2<<<1, 256, 0, stream>>>(bsum);
  scan3<<<(NBIN + 255) / 256, 256, 0, stream>>>(srcpos, bsum, srcflag);
  build_src_o<<<(NBIN + 255) / 256, 256, 0, stream>>>(srcflag, srcpos, srclist, srcmap);
  fincnt<<<1, 64, 0, stream>>>(srcpos, nsrc);
  remap_rsrc<<<(NE + 255) / 256, 256, 0, stream>>>(csroff, rsrc, srcmap, rsrcx);
  build_hot<<<(NBIN + 255) / 256, 256, 0, stream>>>(csroff, rsrc, nsolo, nhot,
                                                    solosrc, solodst, hotlist);
  gate_cb_all<<<NL, 128, 0, stream>>>(relgate, convb, gate, cb);

  build_xin_bf<<<(NN * 96 + 255) / 256, 256, 0, stream>>>(x, idtok, idemb, xinbf);
  gemm_bf16_t<96><<<8 * RPX, 256, 0, stream>>>(xinbf, inwb, inb, h, hbf, NN, 128, 1, 1);

  hipMemsetAsync(hmsg, 0, (size_t)NN * HID * 4, stream);  // l=0 only; layer_tail zeroes after
  for (int l = 0; l < NL; ++l) {
    conv_solo_all<<<8192, 256, 0, stream>>>(
        hbf, srclist, hotlist, cnts,
        linlwb + (size_t)l * NR * 512 * 128, linlb + (size_t)l * NR * 512,
        linrwb + (size_t)l * NR * 512 * 128, linrb + (size_t)l * NR * 512,
        xlb, xrh,
        solosrc, solodst,
        wsumb + (size_t)l * NR * 16384, bsumf + (size_t)l * NR * 128,
        gate + l * NR, hmsg);
    edge_merged<<<4096, 256, 0, stream>>>(
        csroff, rsrcx, eacsr,
        relemb + (size_t)l * NR * RED,
        linew + (size_t)l * NR * 512 * 24,
        attw + (size_t)l * NR * 512,
        xlb, xrh, hotlist, nhot, hmsg, gate + l * NR);
    layer_tail<<<8 * RPX, 256, 0, stream>>>(
        h, hmsg, cb + l * HID, n1w + l * HID, n1b + l * HID,
        f1wb + (size_t)l * 256 * 128, f1bias + (size_t)l * 256,
        f2wb + (size_t)l * 128 * 256, f2bias + (size_t)l * 128,
        n2w + l * HID, n2b + l * HID, hbf);
  }

  group_bounds<<<1, 128, 0, stream>>>(batch, gstart);
  readout_part2<<<dim3(NG, 8), 128, 0, stream>>>(h, gstart, psum, pmax);
  readout_final<<<NG, 256, 0, stream>>>(gstart, psum, pmax, rnw, rnb, g);
  kan1_part<<<dim3(NG, 8), 128, 0, stream>>>(g, bw1, sw1, sc1, grid1, zpart);
  kan2<<<NG, 128, 0, stream>>>(zpart, bw2, sw2, sc2, grid2, out);
}

// Round 11
// 962.592 us; speedup vs baseline: 1.4843x; 1.0575x over previous
//
#include <hip/hip_runtime.h>
#include <math.h>

#define NN 50000
#define NE 120000
#define FN 64
#define NEA 16
#define NR 4
#define NH 4
#define HID 128
#define NL 3
#define IDE 32
#define RED 8
#define NG 64
#define NC 10
#define KH 128
#define FFH 256
#define NBIN (NR * NN)
#define SCAN_BLK ((NBIN + 1023) / 1024)
// per-rel compacted-row capacities (hot-srcs ~13K, hot-dsts ~6.1K per rel)
#define CAPS 32768
#define CAPH 9216

typedef short bf16x8 __attribute__((ext_vector_type(8)));
typedef float f32x4 __attribute__((ext_vector_type(4)));

__device__ __forceinline__ unsigned short f2b(float f) {
  unsigned u = __float_as_uint(f);
  unsigned r = (u + 0x7FFFu + ((u >> 16) & 1u)) >> 16;
  return (unsigned short)r;
}
__device__ __forceinline__ float b2f(unsigned short b) {
  return __uint_as_float((unsigned)b << 16);
}

__global__ void cvt_bf16(const float* __restrict__ s, unsigned short* __restrict__ d, int n4) {
  int i = blockIdx.x * blockDim.x + threadIdx.x;
  if (i >= n4) return;
  float4 v = ((const float4*)s)[i];
  ushort4 o;
  o.x = f2b(v.x); o.y = f2b(v.y); o.z = f2b(v.z); o.w = f2b(v.w);
  ((ushort4*)d)[i] = o;
}

// ---- GEMM core: 64x128 tile, NO-LDS streaming main loop (round-3/4 design).
template <int KT>
__device__ __forceinline__ void gemm_direct(
    const unsigned short* __restrict__ A, const int* __restrict__ rowlist,
    const unsigned short* __restrict__ W, const float* __restrict__ bias,
    float* __restrict__ Cf, unsigned short* __restrict__ Cb,
    int nrows, int mout, int act, int rowBase, int colBase) {
  constexpr int NK = KT / 32;
  __shared__ unsigned short Es[64][136];
  int t = threadIdx.x;
  int lane = t & 63, w = t >> 6;
  int wm = w >> 1, wn = w & 1;
  int q = lane >> 4, mr = lane & 15;

  const unsigned short* ap[2];
#pragma unroll
  for (int mt = 0; mt < 2; ++mt) {
    int gr = rowBase + wm * 32 + mt * 16 + mr;
    int cg = (gr < nrows) ? gr : 0;
    int ar = rowlist ? rowlist[cg] : cg;
    ap[mt] = A + (size_t)ar * KT + q * 8;
  }
  const unsigned short* wp[4];
#pragma unroll
  for (int nt = 0; nt < 4; ++nt)
    wp[nt] = W + (size_t)(colBase + wn * 64 + nt * 16 + mr) * KT + q * 8;

  f32x4 acc[2][4] = {};
#pragma unroll
  for (int k = 0; k < NK; ++k) {
    bf16x8 af[2], bfr[4];
#pragma unroll
    for (int mt = 0; mt < 2; ++mt) af[mt] = *(const bf16x8*)(ap[mt] + k * 32);
#pragma unroll
    for (int nt = 0; nt < 4; ++nt) bfr[nt] = *(const bf16x8*)(wp[nt] + k * 32);
#pragma unroll
    for (int mt = 0; mt < 2; ++mt)
#pragma unroll
      for (int nt = 0; nt < 4; ++nt)
        acc[mt][nt] = __builtin_amdgcn_mfma_f32_16x16x32_bf16(af[mt], bfr[nt], acc[mt][nt], 0, 0, 0);
  }

  float bv[4];
#pragma unroll
  for (int nt = 0; nt < 4; ++nt) bv[nt] = bias[colBase + wn * 64 + nt * 16 + mr];

  if (Cf) {
#pragma unroll
    for (int mt = 0; mt < 2; ++mt)
#pragma unroll
      for (int nt = 0; nt < 4; ++nt)
#pragma unroll
        for (int r = 0; r < 4; ++r) {
          int row = rowBase + wm * 32 + mt * 16 + q * 4 + r;
          int col = colBase + wn * 64 + nt * 16 + mr;
          if (row < nrows) {
            float v = acc[mt][nt][r] + bv[nt];
            if (act) v = v / (1.f + expf(-v));
            Cf[(size_t)row * mout + col] = v;
            if (Cb) Cb[(size_t)row * mout + col] = f2b(v);
          }
        }
  } else {
#pragma unroll
    for (int mt = 0; mt < 2; ++mt)
#pragma unroll
      for (int nt = 0; nt < 4; ++nt)
#pragma unroll
        for (int r = 0; r < 4; ++r) {
          float v = acc[mt][nt][r] + bv[nt];
          if (act) v = v / (1.f + expf(-v));
          Es[wm * 32 + mt * 16 + q * 4 + r][wn * 64 + nt * 16 + mr] = f2b(v);
        }
    __syncthreads();
    int rl = t >> 2, co = (t & 3) * 32;
    int grow = rowBase + rl;
    if (grow < nrows) {
      unsigned short* dst = Cb + (size_t)grow * mout + colBase + co;
#pragma unroll
      for (int j = 0; j < 4; ++j)
        *(bf16x8*)(dst + j * 8) = *(const bf16x8*)&Es[rl][co + j * 8];
    }
  }
}

// XCD-aware full GEMM (dispatch is round-robin over 8 XCDs: bid&7 = XCD)
template <int KT>
__global__ __launch_bounds__(256, 2) void gemm_bf16_t(
    const unsigned short* __restrict__ A, const unsigned short* __restrict__ W,
    const float* __restrict__ bias, float* __restrict__ Cf, unsigned short* __restrict__ Cb,
    int nrows, int mout, int act, int ncol) {
  int nbr = (nrows + 63) >> 6;
  int rpx = (nbr + 7) >> 3;
  int xcd = blockIdx.x & 7, j = blockIdx.x >> 3;
  int rowT = xcd * rpx + j / ncol;
  int cy = j - (j / ncol) * ncol;
  if (rowT >= nbr) return;
  gemm_direct<KT>(A, nullptr, W, bias, Cf, Cb, nrows, mout, act, rowT * 64, cy * 128);
}

// ---- merged conv + solo GEMM, one launch per layer.
// Segments 0..7: xl (hot-src lists) / xr (hot-dst lists) staging GEMMs.
// Segments 8..11: solo-edge GEMM (softmax==1): g/4*(hbf[src]@Wsum^T+bsum)
// scatter-added DIRECTLY INTO h (residual accumulator; atomicAdd, ulp-level
// reorder noise vs 2e-3 tolerance).
__global__ __launch_bounds__(256, 2) void conv_solo_all(
    const unsigned short* __restrict__ hbf,
    const int* __restrict__ srclist, const int* __restrict__ hotlist,
    const int* __restrict__ cnts,  // nsolo @ [r*16], nhot @ [64+r*16], nsrc @ [128+r*16]
    const unsigned short* __restrict__ Wl, const float* __restrict__ bl,
    const unsigned short* __restrict__ Wr, const float* __restrict__ br,
    unsigned short* __restrict__ xlb, unsigned short* __restrict__ xrh,
    const int* __restrict__ solosrc, const int* __restrict__ solodst,
    const unsigned short* __restrict__ wsum, const float* __restrict__ bsum,
    const float* __restrict__ gate, float* __restrict__ hacc) {
  int t = threadIdx.x, lane = t & 63, w = t >> 6;
  int wm = w >> 1, wn = w & 1, q = lane >> 4, mr = lane & 15;
  for (int tid = blockIdx.x;; tid += gridDim.x) {
    int rem = tid, seg = 0, nrows = 0;
    for (; seg < 12; ++seg) {
      int n, tseg;
      if (seg < 8) {
        int r = seg >> 1;
        n = (seg & 1) ? cnts[64 + r * 16] : cnts[128 + r * 16];
        int cap = (seg & 1) ? CAPH : CAPS;
        if (n > cap) n = cap;
        tseg = ((n + 63) >> 6) * 4;
      } else {
        n = cnts[(seg - 8) * 16];
        tseg = (n + 63) >> 6;
      }
      if (rem < tseg) { nrows = n; break; }
      rem -= tseg;
    }
    if (seg == 12) return;
    if (seg < 8) {
      int r = seg >> 1, sel = seg & 1;
      int rt = rem >> 2, ct = rem & 3;
      const int* list = (sel ? hotlist : srclist) + r * NN;
      const unsigned short* W = (sel ? Wr : Wl) + (size_t)r * 512 * 128;
      const float* bias = (sel ? br : bl) + (size_t)r * 512;
      unsigned short* C = sel ? (xrh + (size_t)r * CAPH * 512) : (xlb + (size_t)r * CAPS * 512);
      gemm_direct<128>(hbf, list, W, bias, nullptr, C, nrows, 512, 0, rt * 64, ct * 128);
    } else {
      int r = seg - 8;
      int rowBase = rem * 64;
      const unsigned short* ap[2];
#pragma unroll
      for (int mt = 0; mt < 2; ++mt) {
        int gr = rowBase + wm * 32 + mt * 16 + mr;
        int idx = (gr < nrows) ? solosrc[r * NN + gr] : 0;
        ap[mt] = hbf + (size_t)idx * HID + q * 8;
      }
      const unsigned short* wp[4];
#pragma unroll
      for (int nt = 0; nt < 4; ++nt)
        wp[nt] = wsum + (size_t)r * 16384 + (size_t)(wn * 64 + nt * 16 + mr) * HID + q * 8;
      f32x4 acc[2][4] = {};
#pragma unroll
      for (int k = 0; k < 4; ++k) {
        bf16x8 af[2], bfr[4];
#pragma unroll
        for (int mt = 0; mt < 2; ++mt) af[mt] = *(const bf16x8*)(ap[mt] + k * 32);
#pragma unroll
        for (int nt = 0; nt < 4; ++nt) bfr[nt] = *(const bf16x8*)(wp[nt] + k * 32);
#pragma unroll
        for (int mt = 0; mt < 2; ++mt)
#pragma unroll
          for (int nt = 0; nt < 4; ++nt)
            acc[mt][nt] = __builtin_amdgcn_mfma_f32_16x16x32_bf16(af[mt], bfr[nt], acc[mt][nt], 0, 0, 0);
      }
      float g4 = gate[r] * 0.25f;
      float bv[4];
#pragma unroll
      for (int nt = 0; nt < 4; ++nt) bv[nt] = bsum[r * 128 + wn * 64 + nt * 16 + mr];
#pragma unroll
      for (int mt = 0; mt < 2; ++mt)
#pragma unroll
        for (int rr = 0; rr < 4; ++rr) {
          int row = rowBase + wm * 32 + mt * 16 + q * 4 + rr;
          if (row < nrows) {
            int dst = solodst[r * NN + row];
#pragma unroll
            for (int nt = 0; nt < 4; ++nt) {
              int col = wn * 64 + nt * 16 + mr;
              atomicAdd(&hacc[(size_t)dst * HID + col], g4 * (acc[mt][nt][rr] + bv[nt]));
            }
          }
        }
    }
    __syncthreads();  // LDS WAR between tiles (solo iterations participate too)
  }
}

// head-summed lin_l weights/bias per (layer,rel): Wsum[o][k] = sum_h Wl[h*128+o][k]
__global__ void wsum_build(const float* __restrict__ linlw, const float* __restrict__ linlb,
                           unsigned short* __restrict__ wsum, float* __restrict__ bsum) {
  int i = blockIdx.x * blockDim.x + threadIdx.x;
  if (i >= NL * NR * 128 * 128) return;
  int k = i & 127, o = (i >> 7) & 127, lr = i >> 14;
  float s = 0.f;
#pragma unroll
  for (int h = 0; h < NH; ++h) s += linlw[((size_t)lr * 512 + h * 128 + o) * 128 + k];
  wsum[i] = f2b(s);
  if (k == 0) {
    float b = 0.f;
#pragma unroll
    for (int h = 0; h < NH; ++h) b += linlb[(size_t)lr * 512 + h * 128 + o];
    bsum[lr * 128 + o] = b;
  }
}

// ---- layer tail: h already holds residual+messages (solo/edge added in place).
// LN1(h+cb) -> y (regs); f1=silu(y@W1^T+b1); f2=f1@W2^T+b2; h=LN2(y+f2); emits hbf.
__global__ __launch_bounds__(256, 2) void layer_tail(
    float* __restrict__ h, const float* __restrict__ cb,
    const float* __restrict__ n1w, const float* __restrict__ n1b,
    const unsigned short* __restrict__ W1, const float* __restrict__ b1,
    const unsigned short* __restrict__ W2, const float* __restrict__ b2,
    const float* __restrict__ n2w, const float* __restrict__ n2b,
    unsigned short* __restrict__ hbfout) {
  __shared__ __align__(16) char smem[64 * 136 * 2 + 64 * 264 * 2];
  unsigned short (*Y)[136] = (unsigned short (*)[136])smem;
  unsigned short (*F1)[264] = (unsigned short (*)[264])(smem + 64 * 136 * 2);
  float (*Ef)[132] = (float (*)[132])(smem + 64 * 136 * 2);
  int nbr = (NN + 63) >> 6;
  int rpx = (nbr + 7) >> 3;
  int xcd = blockIdx.x & 7, j = blockIdx.x >> 3;
  int rowT = xcd * rpx + j;
  if (rowT >= nbr) return;
  int rowBase = rowT * 64;

  int t = threadIdx.x;
  int lane = t & 63, w = t >> 6;
  int wm = w >> 1, wn = w & 1;
  int q = lane >> 4, mr = lane & 15;

  // ---- phase 0: LN1 over own 64 rows (wave-per-row); y kept in regs (static idx)
  float y0r[16], y1r[16];
  {
    float w0 = n1w[lane], w1 = n1w[64 + lane];
    float bb0 = n1b[lane], bb1 = n1b[64 + lane];
    float c0 = cb[lane], c1 = cb[64 + lane];
#pragma unroll
    for (int it = 0; it < 16; ++it) {
      int rr = it * 4 + w;
      int grow = rowBase + rr;
      if (grow < NN) {
        size_t base = (size_t)grow * HID;
        float x0 = h[base + lane] + c0;
        float x1 = h[base + 64 + lane] + c1;
        float s = x0 + x1;
#pragma unroll
        for (int o = 32; o > 0; o >>= 1) s += __shfl_xor(s, o, 64);
        float mean = s * (1.f / 128.f);
        float d0 = x0 - mean, d1 = x1 - mean;
        float v = d0 * d0 + d1 * d1;
#pragma unroll
        for (int o = 32; o > 0; o >>= 1) v += __shfl_xor(v, o, 64);
        float inv = 1.f / sqrtf(v * (1.f / 128.f) + 1e-5f);
        float y0 = d0 * inv * w0 + bb0;
        float y1 = d1 * inv * w1 + bb1;
        y0r[it] = y0;
        y1r[it] = y1;
        Y[rr][lane] = f2b(y0);
        Y[rr][64 + lane] = f2b(y1);
      } else {
        y0r[it] = 0.f;
        y1r[it] = 0.f;
        Y[rr][lane] = 0;
        Y[rr][64 + lane] = 0;
      }
    }
  }
  __syncthreads();

  // ---- phase A: f1 = silu(y @ W1^T + b1), A-frags from Y LDS
  bf16x8 a[2][4];
#pragma unroll
  for (int mt = 0; mt < 2; ++mt)
#pragma unroll
    for (int k = 0; k < 4; ++k)
      a[mt][k] = *(const bf16x8*)&Y[wm * 32 + mt * 16 + mr][k * 32 + q * 8];

#pragma unroll
  for (int ph = 0; ph < 2; ++ph) {
    const unsigned short* wp[4];
#pragma unroll
    for (int nt = 0; nt < 4; ++nt)
      wp[nt] = W1 + (size_t)(ph * 128 + wn * 64 + nt * 16 + mr) * HID + q * 8;
    f32x4 acc[2][4] = {};
#pragma unroll
    for (int k = 0; k < 4; ++k) {
      bf16x8 bfr[4];
#pragma unroll
      for (int nt = 0; nt < 4; ++nt) bfr[nt] = *(const bf16x8*)(wp[nt] + k * 32);
#pragma unroll
      for (int mt = 0; mt < 2; ++mt)
#pragma unroll
        for (int nt = 0; nt < 4; ++nt)
          acc[mt][nt] = __builtin_amdgcn_mfma_f32_16x16x32_bf16(a[mt][k], bfr[nt], acc[mt][nt], 0, 0, 0);
    }
    float bv[4];
#pragma unroll
    for (int nt = 0; nt < 4; ++nt) bv[nt] = b1[ph * 128 + wn * 64 + nt * 16 + mr];
#pragma unroll
    for (int mt = 0; mt < 2; ++mt)
#pragma unroll
      for (int nt = 0; nt < 4; ++nt)
#pragma unroll
        for (int r = 0; r < 4; ++r) {
          float v = acc[mt][nt][r] + bv[nt];
          v = v / (1.f + expf(-v));
          F1[wm * 32 + mt * 16 + q * 4 + r][ph * 128 + wn * 64 + nt * 16 + mr] = f2b(v);
        }
  }
  __syncthreads();

  // ---- phase B: f2 = f1 @ W2^T (K=256), A from LDS, W2 from L2
  const unsigned short* wp2[4];
#pragma unroll
  for (int nt = 0; nt < 4; ++nt)
    wp2[nt] = W2 + (size_t)(wn * 64 + nt * 16 + mr) * FFH + q * 8;
  f32x4 acc2[2][4] = {};
#pragma unroll
  for (int k = 0; k < 8; ++k) {
    bf16x8 af[2], bfr[4];
#pragma unroll
    for (int mt = 0; mt < 2; ++mt)
      af[mt] = *(const bf16x8*)&F1[wm * 32 + mt * 16 + mr][k * 32 + q * 8];
#pragma unroll
    for (int nt = 0; nt < 4; ++nt) bfr[nt] = *(const bf16x8*)(wp2[nt] + k * 32);
#pragma unroll
    for (int mt = 0; mt < 2; ++mt)
#pragma unroll
      for (int nt = 0; nt < 4; ++nt)
        acc2[mt][nt] = __builtin_amdgcn_mfma_f32_16x16x32_bf16(af[mt], bfr[nt], acc2[mt][nt], 0, 0, 0);
  }
  __syncthreads();  // all F1 reads done before overwriting as Ef

  // ---- phase C: stage f2+b2 in LDS (f32), then LN2(y + f2) -> h, hbf
  float bv2[4];
#pragma unroll
  for (int nt = 0; nt < 4; ++nt) bv2[nt] = b2[wn * 64 + nt * 16 + mr];
#pragma unroll
  for (int mt = 0; mt < 2; ++mt)
#pragma unroll
    for (int nt = 0; nt < 4; ++nt)
#pragma unroll
      for (int r = 0; r < 4; ++r)
        Ef[wm * 32 + mt * 16 + q * 4 + r][wn * 64 + nt * 16 + mr] = acc2[mt][nt][r] + bv2[nt];
  __syncthreads();

  float w0 = n2w[lane], w1 = n2w[64 + lane];
  float bb0 = n2b[lane], bb1 = n2b[64 + lane];
#pragma unroll
  for (int it = 0; it < 16; ++it) {
    int rr = it * 4 + w;
    int grow = rowBase + rr;
    if (grow >= NN) continue;
    size_t base = (size_t)grow * HID;
    float x0 = y0r[it] + Ef[rr][lane];   // y from regs: no HBM round-trip
    float x1 = y1r[it] + Ef[rr][64 + lane];
    float s = x0 + x1;
#pragma unroll
    for (int o = 32; o > 0; o >>= 1) s += __shfl_xor(s, o, 64);
    float mean = s * (1.f / 128.f);
    float d0 = x0 - mean, d1 = x1 - mean;
    float v = d0 * d0 + d1 * d1;
#pragma unroll
    for (int o = 32; o > 0; o >>= 1) v += __shfl_xor(v, o, 64);
    float inv = 1.f / sqrtf(v * (1.f / 128.f) + 1e-5f);
    float y0 = d0 * inv * w0 + bb0;
    float y1 = d1 * inv * w1 + bb1;
    h[base + lane] = y0;
    h[base + 64 + lane] = y1;
    hbfout[base + lane] = f2b(y0);
    hbfout[base + 64 + lane] = f2b(y1);
  }
}

__global__ void build_xin_bf(const float* __restrict__ x, const int* __restrict__ idtok,
                             const float* __restrict__ emb, unsigned short* __restrict__ xin) {
  int i = blockIdx.x * blockDim.x + threadIdx.x;
  if (i >= NN * 96) return;
  int n = i / 96, k = i - n * 96;
  float v = (k < FN) ? x[(size_t)n * FN + k] : emb[(size_t)idtok[n] * IDE + (k - FN)];
  xin[i] = f2b(v);
}

// ---- CSR by (rel, dst) ----
__global__ void hist_bin(const int* __restrict__ ei, const int* __restrict__ et,
                         int* __restrict__ bcnt) {
  int e = blockIdx.x * blockDim.x + threadIdx.x;
  if (e >= NE) return;
  atomicAdd(&bcnt[et[e] * NN + ei[NE + e]], 1);
}
__global__ __launch_bounds__(256) void scan1(const int* __restrict__ cnt,
                                             int* __restrict__ pos, int* __restrict__ bsum) {
  __shared__ int lds[256];
  int b = blockIdx.x, t = threadIdx.x;
  int base = b * 1024 + t * 4;
  int v[4];
#pragma unroll
  for (int j = 0; j < 4; ++j) v[j] = (base + j < NBIN) ? cnt[base + j] : 0;
  int tot = v[0] + v[1] + v[2] + v[3];
  lds[t] = tot;
  __syncthreads();
  for (int off = 1; off < 256; off <<= 1) {
    int x = (t >= off) ? lds[t - off] : 0;
    __syncthreads();
    lds[t] += x;
    __syncthreads();
  }
  if (t == 255) bsum[b] = lds[255];
  int run = lds[t] - tot;
#pragma unroll
  for (int j = 0; j < 4; ++j) {
    if (base + j < NBIN) pos[base + j] = run;
    run += v[j];
  }
}
__global__ __launch_bounds__(256) void scan2(int* __restrict__ bsum) {
  __shared__ int lds[256];
  int t = threadIdx.x;
  int v = (t < SCAN_BLK) ? bsum[t] : 0;
  lds[t] = v;
  __syncthreads();
  for (int off = 1; off < 256; off <<= 1) {
    int x = (t >= off) ? lds[t - off] : 0;
    __syncthreads();
    lds[t] += x;
    __syncthreads();
  }
  if (t < SCAN_BLK) bsum[t] = lds[t] - v;
}
__global__ void scan3(int* __restrict__ pos, const int* __restrict__ bsum,
                      const int* __restrict__ cnt) {
  int i = blockIdx.x * blockDim.x + threadIdx.x;
  if (i >= NBIN) return;
  pos[i] += bsum[i >> 10];
  if (i == NBIN - 1) pos[NBIN] = pos[i] + cnt[i];
}
__global__ void scatter_bin(const int* __restrict__ ei, const int* __restrict__ et,
                            const int* __restrict__ csroff, int* __restrict__ cur,
                            int* __restrict__ elist) {
  int e = blockIdx.x * blockDim.x + threadIdx.x;
  if (e >= NE) return;
  int bin = et[e] * NN + ei[NE + e];
  int p = atomicAdd(&cur[bin], 1);
  elist[csroff[bin] + p] = e;
}
// DETERMINISM: atomic scatter order varies call-to-call; sort each bin.
__global__ void sort_bins(const int* __restrict__ csroff, int* __restrict__ elist) {
  int b = blockIdx.x * blockDim.x + threadIdx.x;
  if (b >= NBIN) return;
  int s = csroff[b], e = csroff[b + 1];
  for (int i = s + 1; i < e; ++i) {
    int key = elist[i];
    int j = i - 1;
    while (j >= s && elist[j] > key) { elist[j + 1] = elist[j]; --j; }
    elist[j + 1] = key;
  }
}
// gather edge attrs into CSR order + flag hot-srcs inline (deg>=2 bins only)
__global__ void gather_edge(const int* __restrict__ ei, const int* __restrict__ et,
                            const int* __restrict__ elist, const int* __restrict__ csroff,
                            const float* __restrict__ eattr,
                            int* __restrict__ rsrc, float* __restrict__ eacsr,
                            int* __restrict__ srcflag) {
  int p = blockIdx.x * blockDim.x + threadIdx.x;
  if (p >= NE) return;
  int e = elist[p];
  int src = ei[e];
  rsrc[p] = src;
  const float4* s = (const float4*)(eattr + (size_t)e * NEA);
  float4* d = (float4*)(eacsr + (size_t)p * NEA);
#pragma unroll
  for (int j = 0; j < 4; ++j) d[j] = s[j];
  int bin = et[e] * NN + ei[NE + e];
  if (csroff[bin + 1] - csroff[bin] >= 2) srcflag[et[e] * NN + src] = 1;
}
// ORDERED hot-src compaction from scan positions (deterministic + sequential gather)
__global__ void build_src_o(const int* __restrict__ srcflag, const int* __restrict__ srcpos,
                            int* __restrict__ srclist, int* __restrict__ srcmap) {
  int b = blockIdx.x * blockDim.x + threadIdx.x;
  if (b >= NBIN) return;
  if (srcflag[b]) {
    int rel = b / NN;
    int pos = srcpos[b] - srcpos[rel * NN];
    srcmap[b] = pos;
    srclist[rel * NN + pos] = b - rel * NN;
  }
}
__global__ void fincnt(const int* __restrict__ srcpos, int* __restrict__ nsrc) {
  int r = threadIdx.x;
  if (r < NR) nsrc[r * 16] = srcpos[(r + 1) * NN] - srcpos[r * NN];
}
// rsrcx: hot-src row index per edge position (garbage for solo positions, unread)
__global__ void remap_rsrc(const int* __restrict__ csroff, const int* __restrict__ rsrc,
                           const int* __restrict__ srcmap, int* __restrict__ rsrcx) {
  int p = blockIdx.x * blockDim.x + threadIdx.x;
  if (p >= NE) return;
  int rel = (p >= csroff[NN]) + (p >= csroff[2 * NN]) + (p >= csroff[3 * NN]);
  rsrcx[p] = srcmap[rel * NN + rsrc[p]];
}
// per-rel solo (deg==1: ORIGINAL src id + dst) + hot (deg>=2) lists.
__global__ __launch_bounds__(256) void build_hot(
    const int* __restrict__ csroff, const int* __restrict__ rsrc,
    int* __restrict__ nsolo, int* __restrict__ nhot,
    int* __restrict__ solosrc, int* __restrict__ solodst, int* __restrict__ hotlist) {
  __shared__ int wsc[4][4], whc[4][4];
  __shared__ int sbase[4], hbase[4];
  int t = threadIdx.x, wave = t >> 6, lane = t & 63;
  int b = blockIdx.x * 256 + t;
  bool valid = b < NBIN;
  int cnt = 0, rel = 0, s = 0;
  if (valid) { s = csroff[b]; cnt = csroff[b + 1] - s; rel = b / NN; }
  bool solo = valid && cnt == 1;
  bool hot = valid && cnt >= 2;
#pragma unroll
  for (int rr = 0; rr < 4; ++rr) {
    unsigned long long ms = __ballot(solo && rel == rr);
    unsigned long long mh = __ballot(hot && rel == rr);
    if (lane == 0) { wsc[wave][rr] = __popcll(ms); whc[wave][rr] = __popcll(mh); }
  }
  __syncthreads();
  if (t < 4) {
    int ssum = wsc[0][t] + wsc[1][t] + wsc[2][t] + wsc[3][t];
    int hsum = whc[0][t] + whc[1][t] + whc[2][t] + whc[3][t];
    sbase[t] = ssum ? atomicAdd(&nsolo[t * 16], ssum) : 0;
    hbase[t] = hsum ? atomicAdd(&nhot[t * 16], hsum) : 0;
  }
  __syncthreads();
#pragma unroll
  for (int rr = 0; rr < 4; ++rr) {
    unsigned long long ms = __ballot(solo && rel == rr);
    if (solo && rel == rr) {
      int before = 0;
#pragma unroll
      for (int wv = 0; wv < 4; ++wv) if (wv < wave) before += wsc[wv][rr];
      int pos = sbase[rr] + before + __popcll(ms & ((1ull << lane) - 1ull));
      solosrc[rr * NN + pos] = rsrc[s];
      solodst[rr * NN + pos] = b - rr * NN;
    }
    unsigned long long mh = __ballot(hot && rel == rr);
    if (hot && rel == rr) {
      int before = 0;
#pragma unroll
      for (int wv = 0; wv < 4; ++wv) if (wv < wave) before += whc[wv][rr];
      int pos = hbase[rr] + before + __popcll(mh & ((1ull << lane) - 1ull));
      hotlist[rr * NN + pos] = b - rr * NN;
    }
  }
}

// all-layers gate softmax + gated conv bias in one launch (block = layer)
__global__ void gate_cb_all(const float* __restrict__ rg, const float* __restrict__ cbias,
                            float* __restrict__ gate, float* __restrict__ cb) {
  __shared__ float g[NR];
  int l = blockIdx.x, t = threadIdx.x;
  const float* rgl = rg + l * NR;
  if (t == 0) {
    float mx = rgl[0];
    for (int r = 1; r < NR; ++r) mx = fmaxf(mx, rgl[r]);
    float s = 0.f, tmp[NR];
    for (int r = 0; r < NR; ++r) { tmp[r] = expf(rgl[r] - mx); s += tmp[r]; }
    for (int r = 0; r < NR; ++r) { g[r] = tmp[r] / s; gate[l * NR + r] = g[r]; }
  }
  __syncthreads();
  float c = 0.f;
  for (int r = 0; r < NR; ++r) c += g[r] * cbias[(size_t)l * NR * HID + r * HID + t];
  cb[l * HID + t] = c;
}

// ---- merged hot edge pass: ALL 4 rels in one launch (rel = bid&3, grid-stride
// within rel so weight regs load once per block). Block/dst online softmax.
// Accumulates DIRECTLY INTO h via atomicAdd (<=4 rel contributions + solo adds
// per dst; fp32 reorder noise ~ulp vs 2e-3 tolerance).
__global__ __launch_bounds__(256) void edge_merged(
    const int* __restrict__ csroff, const int* __restrict__ rsrcx,
    const float* __restrict__ eacsr, const float* __restrict__ relembL,
    const float* __restrict__ wedgeL, const float* __restrict__ attwL,
    const unsigned short* __restrict__ xlb, const unsigned short* __restrict__ xrh,
    const int* __restrict__ hotlist, const int* __restrict__ nhot,
    float* __restrict__ hacc, const float* __restrict__ gate) {
  __shared__ float lds[4][128];
  int wave = threadIdx.x >> 6, lane = threadIdx.x & 63;
  int rel = blockIdx.x & 3;
  int b0 = blockIdx.x >> 2;
  int bstride = gridDim.x >> 2;
  float g4 = gate[rel] * 0.25f;
  int hh = wave;
  const float* wedgep = wedgeL + (size_t)rel * 512 * 24;
  const float* attwp = attwL + (size_t)rel * 512;
  const float* relembp = relembL + rel * RED;
  const unsigned short* xlbase = xlb + (size_t)rel * CAPS * 512;
  const unsigned short* xrbase = xrh + (size_t)rel * CAPH * 512;
  float wreg[2][24], areg[2];
#pragma unroll
  for (int j = 0; j < 2; ++j) {
    int col = hh * 128 + j * 64 + lane;
    const float* wp = wedgep + (size_t)col * 24;
#pragma unroll
    for (int k = 0; k < 24; ++k) wreg[j][k] = wp[k];
    areg[j] = attwp[col];
  }
  float evr0 = 0.f, evr1 = 0.f;
#pragma unroll
  for (int k = 0; k < 8; ++k) {
    float rk = relembp[k];
    evr0 += rk * wreg[0][NEA + k];
    evr1 += rk * wreg[1][NEA + k];
  }
  int nh = nhot[rel * 16];
  for (int wi = b0; wi < nh; wi += bstride) {
    int dst = hotlist[rel * NN + wi];
    int s = csroff[rel * NN + dst], e = csroff[rel * NN + dst + 1];
    {
      const unsigned short* xrp = xrbase + (size_t)wi * 512;
      float xr0 = b2f(xrp[hh * 128 + lane]);
      float xr1 = b2f(xrp[hh * 128 + 64 + lane]);
      float m = -3.4e38f, den = 0.f, acc0 = 0.f, acc1 = 0.f;
      for (int p = s; p < e; ++p) {
        int src = rsrcx[p];
        const float* eap = eacsr + (size_t)p * NEA;
        float eev0 = evr0, eev1 = evr1;
#pragma unroll
        for (int k = 0; k < NEA; ++k) {
          float er = eap[k];
          eev0 += er * wreg[0][k];
          eev1 += er * wreg[1][k];
        }
        float xl0 = b2f(xlbase[(size_t)src * 512 + hh * 128 + lane]);
        float xl1 = b2f(xlbase[(size_t)src * 512 + hh * 128 + 64 + lane]);
        float s0 = xl0 + xr0 + eev0; s0 = (s0 > 0.f) ? s0 : 0.2f * s0;
        float s1 = xl1 + xr1 + eev1; s1 = (s1 > 0.f) ? s1 : 0.2f * s1;
        float lg = s0 * areg[0] + s1 * areg[1];
#pragma unroll
        for (int o = 32; o > 0; o >>= 1) lg += __shfl_xor(lg, o, 64);
        float mn = fmaxf(m, lg);
        float sc = expf(m - mn);
        float ex = expf(lg - mn);
        den = den * sc + ex;
        acc0 = acc0 * sc + ex * xl0;
        acc1 = acc1 * sc + ex * xl1;
        m = mn;
      }
      float wgt = g4 / den;
      lds[wave][lane] = acc0 * wgt;
      lds[wave][64 + lane] = acc1 * wgt;
    }
    __syncthreads();
    if (wave < 2) {
      int d = wave * 64 + lane;
      float v = lds[0][d] + lds[1][d] + lds[2][d] + lds[3][d];
      atomicAdd(&hacc[(size_t)dst * HID + d], v);
    }
    __syncthreads();
  }
}

// ---- readout: deterministic ----
__global__ void group_bounds(const int* __restrict__ batch, int* __restrict__ gstart) {
  int g = threadIdx.x + blockIdx.x * blockDim.x;
  if (g > NG) return;
  int lo = 0, hi = NN;
  while (lo < hi) {
    int mid = (lo + hi) >> 1;
    if (batch[mid] < g) lo = mid + 1; else hi = mid;
  }
  gstart[g] = lo;
}
__global__ __launch_bounds__(128) void readout_part2(
    const float* __restrict__ h, const int* __restrict__ gstart,
    float* __restrict__ psum, float* __restrict__ pmax) {
  int g = blockIdx.x, s = blockIdx.y, t = threadIdx.x;
  int r0 = gstart[g], r1 = gstart[g + 1];
  float acc = 0.f, mx = -3.4e38f;
  for (int row = r0 + s; row < r1; row += 8) {
    float v = h[(size_t)row * HID + t];
    acc += v;
    mx = fmaxf(mx, v);
  }
  psum[((size_t)g * 8 + s) * HID + t] = acc;
  pmax[((size_t)g * 8 + s) * HID + t] = mx;
}
__global__ __launch_bounds__(256) void readout_final(
    const int* __restrict__ gstart, const float* __restrict__ psum,
    const float* __restrict__ pmax, const float* __restrict__ w,
    const float* __restrict__ b, float* __restrict__ g) {
  int bg = blockIdx.x, t = threadIdx.x;
  __shared__ float red[256];
  float c = fmaxf((float)(gstart[bg + 1] - gstart[bg]), 1.f);
  float x;
  if (t < HID) {
    float ssum = 0.f;
    for (int s = 0; s < 8; ++s) ssum += psum[((size_t)bg * 8 + s) * HID + t];
    x = ssum / c;
  } else {
    float mx = -3.4e38f;
    for (int s = 0; s < 8; ++s) mx = fmaxf(mx, pmax[((size_t)bg * 8 + s) * HID + (t - HID)]);
    x = mx;
  }
  red[t] = x;
  __syncthreads();
  for (int s = 128; s > 0; s >>= 1) {
    if (t < s) red[t] += red[t + s];
    __syncthreads();
  }
  float mean = red[0] * (1.f / 256.f);
  __syncthreads();
  float d = x - mean;
  red[t] = d * d;
  __syncthreads();
  for (int s = 128; s > 0; s >>= 1) {
    if (t < s) red[t] += red[t + s];
    __syncthreads();
  }
  float inv = 1.f / sqrtf(red[0] * (1.f / 256.f) + 1e-5f);
  g[(size_t)bg * 256 + t] = d * inv * w[t] + b[t];
}

__device__ __forceinline__ void bspline8(float x, const float* __restrict__ t,
                                         float* __restrict__ out) {
  float bs[11];
#pragma unroll
  for (int j = 0; j < 11; ++j) bs[j] = (x >= t[j] && x < t[j + 1]) ? 1.f : 0.f;
#pragma unroll
  for (int k = 1; k <= 3; ++k) {
    for (int j = 0; j < 11 - k; ++j) {
      bs[j] = (x - t[j]) / (t[j + k] - t[j]) * bs[j] +
              (t[j + k + 1] - x) / (t[j + k + 1] - t[j + 1]) * bs[j + 1];
    }
  }
#pragma unroll
  for (int j = 0; j < 8; ++j) out[j] = bs[j];
}

// ---- KAN1, K-chunked into fixed partial slots (deterministic) ----
__global__ __launch_bounds__(128) void kan1_part(
    const float* __restrict__ g, const float* __restrict__ bw,
    const float* __restrict__ sw, const float* __restrict__ sc,
    const float* __restrict__ grid, float* __restrict__ zpart) {
  int bg = blockIdx.x, ch = blockIdx.y, t = threadIdx.x;
  int base = ch * 32;
  __shared__ float B[32][8];
  __shared__ float sg[32];
  if (t < 32) {
    float x = g[(size_t)bg * 256 + base + t];
    sg[t] = x / (1.f + expf(-x));
    bspline8(x, grid + (size_t)(base + t) * 12, B[t]);
  }
  __syncthreads();
  float acc = 0.f;
  for (int i = 0; i < 32; ++i) {
    int col = base + i;
    acc += sg[i] * bw[(size_t)t * 256 + col];
    const float* swp = sw + ((size_t)t * 256 + col) * 8;
    float sp = 0.f;
#pragma unroll
    for (int k = 0; k < 8; ++k) sp += B[i][k] * swp[k];
    acc += sp * sc[(size_t)t * 256 + col];
  }
  zpart[((size_t)ch * NG + bg) * KH + t] = acc;
}

__global__ __launch_bounds__(128) void kan2(
    const float* __restrict__ zpart, const float* __restrict__ bw,
    const float* __restrict__ sw, const float* __restrict__ sc,
    const float* __restrict__ grid, float* __restrict__ out) {
  int bg = blockIdx.x, t = threadIdx.x;
  __shared__ float B[128][8];
  __shared__ float sz[128];
  float x = 0.f;
  for (int ch = 0; ch < 8; ++ch) x += zpart[((size_t)ch * NG + bg) * KH + t];
  sz[t] = x / (1.f + expf(-x));
  bspline8(x, grid + (size_t)t * 12, B[t]);
  __syncthreads();
  if (t < NC) {
    float acc = 0.f;
    for (int i = 0; i < 128; ++i) {
      acc += sz[i] * bw[(size_t)t * 128 + i];
      const float* swp = sw + ((size_t)t * 128 + i) * 8;
      float sp = 0.f;
#pragma unroll
      for (int k = 0; k < 8; ++k) sp += B[i][k] * swp[k];
      acc += sp * sc[(size_t)t * 128 + i];
    }
    out[(size_t)bg * NC + t] = acc;
  }
}

extern "C" void kernel_launch(void* const* d_in, const int* in_sizes, int n_in,
                              void* d_out, int out_size, void* d_ws, size_t ws_size,
                              hipStream_t stream) {
  const float* x       = (const float*)d_in[0];
  const float* eattr   = (const float*)d_in[1];
  const int*   idtok   = (const int*)d_in[2];
  const int*   ei      = (const int*)d_in[3];
  const int*   etype   = (const int*)d_in[4];
  const int*   batch   = (const int*)d_in[5];
  const float* idemb   = (const float*)d_in[6];
  const float* inw     = (const float*)d_in[7];
  const float* inb     = (const float*)d_in[8];
  const float* relemb  = (const float*)d_in[9];
  const float* linlw   = (const float*)d_in[10];
  const float* linlb   = (const float*)d_in[11];
  const float* linrw   = (const float*)d_in[12];
  const float* linrb   = (const float*)d_in[13];
  const float* linew   = (const float*)d_in[14];
  const float* attw    = (const float*)d_in[15];
  const float* convb   = (const float*)d_in[16];
  const float* relgate = (const float*)d_in[17];
  const float* n1w     = (const float*)d_in[18];
  const float* n1b     = (const float*)d_in[19];
  const float* n2w     = (const float*)d_in[20];
  const float* n2b     = (const float*)d_in[21];
  const float* f1w     = (const float*)d_in[22];
  const float* f1bias  = (const float*)d_in[23];
  const float* f2w     = (const float*)d_in[24];
  const float* f2bias  = (const float*)d_in[25];
  const float* rnw     = (const float*)d_in[26];
  const float* rnb     = (const float*)d_in[27];
  const float* bw1     = (const float*)d_in[28];
  const float* sw1     = (const float*)d_in[29];
  const float* sc1     = (const float*)d_in[30];
  const float* grid1   = (const float*)d_in[31];
  const float* bw2     = (const float*)d_in[32];
  const float* sw2     = (const float*)d_in[33];
  const float* sc2     = (const float*)d_in[34];
  const float* grid2   = (const float*)d_in[35];
  float* out = (float*)d_out;
  (void)in_sizes; (void)n_in; (void)out_size; (void)ws_size;

  char* p = (char*)d_ws;
  auto alloc = [&](size_t bytes) { void* q = (void*)p; p += (bytes + 255) & ~(size_t)255; return q; };
  float* h    = (float*)alloc((size_t)NN * HID * 4);
  unsigned short* hbf = (unsigned short*)alloc((size_t)NN * HID * 2);
  unsigned short* xlb = (unsigned short*)alloc((size_t)NR * CAPS * 512 * 2);  // 134.2MB
  unsigned short* xrh = (unsigned short*)alloc((size_t)NR * CAPH * 512 * 2);  // 37.7MB
  int* elist = (int*)alloc((size_t)NE * 4);
  int* rsrc  = (int*)alloc((size_t)NE * 4);
  int* rsrcx = (int*)alloc((size_t)NE * 4);
  float* eacsr = (float*)alloc((size_t)NE * NEA * 4);
  int* bcnt  = (int*)alloc((size_t)NBIN * 8 + 8);
  int* cur   = bcnt + NBIN;
  int* csroff = (int*)alloc((size_t)(NBIN + 1) * 4);
  int* srcpos = (int*)alloc((size_t)(NBIN + 1) * 4);
  int* bsum  = (int*)alloc((size_t)SCAN_BLK * 4);
  int* hotlist = (int*)alloc((size_t)NR * NN * 4);
  int* solosrc = (int*)alloc((size_t)NR * NN * 4);
  int* solodst = (int*)alloc((size_t)NR * NN * 4);
  int* srclist = (int*)alloc((size_t)NR * NN * 4);
  int* srcflag = (int*)alloc((size_t)NBIN * 4);
  int* srcmap  = (int*)alloc((size_t)NBIN * 4);
  int* cnts    = (int*)alloc(1024);
  int* nsolo   = cnts;
  int* nhot    = cnts + 64;
  int* nsrc    = cnts + 128;
  unsigned short* linlwb = (unsigned short*)alloc((size_t)NL * NR * 512 * 128 * 2);
  unsigned short* linrwb = (unsigned short*)alloc((size_t)NL * NR * 512 * 128 * 2);
  unsigned short* f1wb   = (unsigned short*)alloc((size_t)NL * 256 * 128 * 2);
  unsigned short* f2wb   = (unsigned short*)alloc((size_t)NL * 128 * 256 * 2);
  unsigned short* inwb   = (unsigned short*)alloc((size_t)128 * 96 * 2);
  unsigned short* wsumb  = (unsigned short*)alloc((size_t)NL * NR * 128 * 128 * 2);
  float* bsumf = (float*)alloc((size_t)NL * NR * 128 * 4);
  float* gate = (float*)alloc(NL * NR * 4);
  float* cb   = (float*)alloc(NL * HID * 4);
  int* gstart = (int*)alloc((size_t)(NG + 1) * 4);
  float* psum = (float*)alloc((size_t)NG * 8 * HID * 4);
  float* pmax = (float*)alloc((size_t)NG * 8 * HID * 4);
  float* zpart = (float*)alloc((size_t)8 * NG * KH * 4);
  float* g = (float*)alloc((size_t)NG * 256 * 4);
  unsigned short* xinbf = xlb;  // aliased: in-proj input staged before layer loop

  const int NB64 = (NN + 63) / 64;
  const int RPX = (NB64 + 7) / 8;

  {
    int n;
    n = NL * NR * 512 * 128 / 4;
    cvt_bf16<<<(n + 255) / 256, 256, 0, stream>>>(linlw, linlwb, n);
    cvt_bf16<<<(n + 255) / 256, 256, 0, stream>>>(linrw, linrwb, n);
    n = NL * 256 * 128 / 4;
    cvt_bf16<<<(n + 255) / 256, 256, 0, stream>>>(f1w, f1wb, n);
    cvt_bf16<<<(n + 255) / 256, 256, 0, stream>>>(f2w, f2wb, n);
    n = 128 * 96 / 4;
    cvt_bf16<<<(n + 255) / 256, 256, 0, stream>>>(inw, inwb, n);
  }
  wsum_build<<<(NL * NR * 128 * 128 + 255) / 256, 256, 0, stream>>>(linlw, linlb, wsumb, bsumf);

  hipMemsetAsync(bcnt, 0, (size_t)NBIN * 8 + 8, stream);
  hipMemsetAsync(srcflag, 0, (size_t)NBIN * 4, stream);
  hipMemsetAsync(cnts, 0, 1024, stream);
  hist_bin<<<(NE + 255) / 256, 256, 0, stream>>>(ei, etype, bcnt);
  scan1<<<SCAN_BLK, 256, 0, stream>>>(bcnt, csroff, bsum);
  scan2<<<1, 256, 0, stream>>>(bsum);
  scan3<<<(NBIN + 255) / 256, 256, 0, stream>>>(csroff, bsum, bcnt);
  scatter_bin<<<(NE + 255) / 256, 256, 0, stream>>>(ei, etype, csroff, cur, elist);
  sort_bins<<<(NBIN + 255) / 256, 256, 0, stream>>>(csroff, elist);
  gather_edge<<<(NE + 255) / 256, 256, 0, stream>>>(ei, etype, elist, csroff, eattr,
                                                    rsrc, eacsr, srcflag);
  scan1<<<SCAN_BLK, 256, 0, stream>>>(srcflag, srcpos, bsum);
  scan2<<<1, 256, 0, stream>>>(bsum);
  scan3<<<(NBIN + 255) / 256, 256, 0, stream>>>(srcpos, bsum, srcflag);
  build_src_o<<<(NBIN + 255) / 256, 256, 0, stream>>>(srcflag, srcpos, srclist, srcmap);
  fincnt<<<1, 64, 0, stream>>>(srcpos, nsrc);
  remap_rsrc<<<(NE + 255) / 256, 256, 0, stream>>>(csroff, rsrc, srcmap, rsrcx);
  build_hot<<<(NBIN + 255) / 256, 256, 0, stream>>>(csroff, rsrc, nsolo, nhot,
                                                    solosrc, solodst, hotlist);
  gate_cb_all<<<NL, 128, 0, stream>>>(relgate, convb, gate, cb);

  build_xin_bf<<<(NN * 96 + 255) / 256, 256, 0, stream>>>(x, idtok, idemb, xinbf);
  gemm_bf16_t<96><<<8 * RPX, 256, 0, stream>>>(xinbf, inwb, inb, h, hbf, NN, 128, 1, 1);

  for (int l = 0; l < NL; ++l) {
    conv_solo_all<<<4096, 256, 0, stream>>>(
        hbf, srclist, hotlist, cnts,
        linlwb + (size_t)l * NR * 512 * 128, linlb + (size_t)l * NR * 512,
        linrwb + (size_t)l * NR * 512 * 128, linrb + (size_t)l * NR * 512,
        xlb, xrh,
        solosrc, solodst,
        wsumb + (size_t)l * NR * 16384, bsumf + (size_t)l * NR * 128,
        gate + l * NR, h);
    edge_merged<<<4096, 256, 0, stream>>>(
        csroff, rsrcx, eacsr,
        relemb + (size_t)l * NR * RED,
        linew + (size_t)l * NR * 512 * 24,
        attw + (size_t)l * NR * 512,
        xlb, xrh, hotlist, nhot, h, gate + l * NR);
    layer_tail<<<8 * RPX, 256, 0, stream>>>(
        h, cb + l * HID, n1w + l * HID, n1b + l * HID,
        f1wb + (size_t)l * 256 * 128, f1bias + (size_t)l * 256,
        f2wb + (size_t)l * 128 * 256, f2bias + (size_t)l * 128,
        n2w + l * HID, n2b + l * HID, hbf);
  }

  group_bounds<<<1, 128, 0, stream>>>(batch, gstart);
  readout_part2<<<dim3(NG, 8), 128, 0, stream>>>(h, gstart, psum, pmax);
  readout_final<<<NG, 256, 0, stream>>>(gstart, psum, pmax, rnw, rnb, g);
  kan1_part<<<dim3(NG, 8), 128, 0, stream>>>(g, bw1, sw1, sc1, grid1, zpart);
  kan2<<<NG, 128, 0, stream>>>(zpart, bw2, sw2, sc2, grid2, out);
}

// Round 12
// 938.281 us; speedup vs baseline: 1.5228x; 1.0259x over previous
//
#include <hip/hip_runtime.h>
#include <math.h>

#define NN 50000
#define NE 120000
#define FN 64
#define NEA 16
#define NR 4
#define NH 4
#define HID 128
#define NL 3
#define IDE 32
#define RED 8
#define NG 64
#define NC 10
#define KH 128
#define FFH 256
#define NBIN (NR * NN)
#define SCAN_BLK ((NBIN + 1023) / 1024)
// per-rel compacted-row capacities (hot-srcs ~13K, hot-dsts ~6.1K per rel)
#define CAPS 32768
#define CAPH 9216

typedef short bf16x8 __attribute__((ext_vector_type(8)));
typedef float f32x4 __attribute__((ext_vector_type(4)));

__device__ __forceinline__ unsigned short f2b(float f) {
  unsigned u = __float_as_uint(f);
  unsigned r = (u + 0x7FFFu + ((u >> 16) & 1u)) >> 16;
  return (unsigned short)r;
}
__device__ __forceinline__ float b2f(unsigned short b) {
  return __uint_as_float((unsigned)b << 16);
}

__global__ void cvt_bf16(const float* __restrict__ s, unsigned short* __restrict__ d, int n4) {
  int i = blockIdx.x * blockDim.x + threadIdx.x;
  if (i >= n4) return;
  float4 v = ((const float4*)s)[i];
  ushort4 o;
  o.x = f2b(v.x); o.y = f2b(v.y); o.z = f2b(v.z); o.w = f2b(v.w);
  ((ushort4*)d)[i] = o;
}

// ---- GEMM core: 64x128 tile, NO-LDS streaming main loop (round-3/4 design).
template <int KT>
__device__ __forceinline__ void gemm_direct(
    const unsigned short* __restrict__ A, const int* __restrict__ rowlist,
    const unsigned short* __restrict__ W, const float* __restrict__ bias,
    float* __restrict__ Cf, unsigned short* __restrict__ Cb,
    int nrows, int mout, int act, int rowBase, int colBase) {
  constexpr int NK = KT / 32;
  __shared__ unsigned short Es[64][136];
  int t = threadIdx.x;
  int lane = t & 63, w = t >> 6;
  int wm = w >> 1, wn = w & 1;
  int q = lane >> 4, mr = lane & 15;

  const unsigned short* ap[2];
#pragma unroll
  for (int mt = 0; mt < 2; ++mt) {
    int gr = rowBase + wm * 32 + mt * 16 + mr;
    int cg = (gr < nrows) ? gr : 0;
    int ar = rowlist ? rowlist[cg] : cg;
    ap[mt] = A + (size_t)ar * KT + q * 8;
  }
  const unsigned short* wp[4];
#pragma unroll
  for (int nt = 0; nt < 4; ++nt)
    wp[nt] = W + (size_t)(colBase + wn * 64 + nt * 16 + mr) * KT + q * 8;

  f32x4 acc[2][4] = {};
#pragma unroll
  for (int k = 0; k < NK; ++k) {
    bf16x8 af[2], bfr[4];
#pragma unroll
    for (int mt = 0; mt < 2; ++mt) af[mt] = *(const bf16x8*)(ap[mt] + k * 32);
#pragma unroll
    for (int nt = 0; nt < 4; ++nt) bfr[nt] = *(const bf16x8*)(wp[nt] + k * 32);
#pragma unroll
    for (int mt = 0; mt < 2; ++mt)
#pragma unroll
      for (int nt = 0; nt < 4; ++nt)
        acc[mt][nt] = __builtin_amdgcn_mfma_f32_16x16x32_bf16(af[mt], bfr[nt], acc[mt][nt], 0, 0, 0);
  }

  float bv[4];
#pragma unroll
  for (int nt = 0; nt < 4; ++nt) bv[nt] = bias[colBase + wn * 64 + nt * 16 + mr];

  if (Cf) {
#pragma unroll
    for (int mt = 0; mt < 2; ++mt)
#pragma unroll
      for (int nt = 0; nt < 4; ++nt)
#pragma unroll
        for (int r = 0; r < 4; ++r) {
          int row = rowBase + wm * 32 + mt * 16 + q * 4 + r;
          int col = colBase + wn * 64 + nt * 16 + mr;
          if (row < nrows) {
            float v = acc[mt][nt][r] + bv[nt];
            if (act) v = v / (1.f + expf(-v));
            Cf[(size_t)row * mout + col] = v;
            if (Cb) Cb[(size_t)row * mout + col] = f2b(v);
          }
        }
  } else {
#pragma unroll
    for (int mt = 0; mt < 2; ++mt)
#pragma unroll
      for (int nt = 0; nt < 4; ++nt)
#pragma unroll
        for (int r = 0; r < 4; ++r) {
          float v = acc[mt][nt][r] + bv[nt];
          if (act) v = v / (1.f + expf(-v));
          Es[wm * 32 + mt * 16 + q * 4 + r][wn * 64 + nt * 16 + mr] = f2b(v);
        }
    __syncthreads();
    int rl = t >> 2, co = (t & 3) * 32;
    int grow = rowBase + rl;
    if (grow < nrows) {
      unsigned short* dst = Cb + (size_t)grow * mout + colBase + co;
#pragma unroll
      for (int j = 0; j < 4; ++j)
        *(bf16x8*)(dst + j * 8) = *(const bf16x8*)&Es[rl][co + j * 8];
    }
    __syncthreads();  // Es WAR for caller reuse
  }
}

// XCD-aware full GEMM (dispatch is round-robin over 8 XCDs: bid&7 = XCD)
template <int KT>
__global__ __launch_bounds__(256, 2) void gemm_bf16_t(
    const unsigned short* __restrict__ A, const unsigned short* __restrict__ W,
    const float* __restrict__ bias, float* __restrict__ Cf, unsigned short* __restrict__ Cb,
    int nrows, int mout, int act, int ncol) {
  int nbr = (nrows + 63) >> 6;
  int rpx = (nbr + 7) >> 3;
  int xcd = blockIdx.x & 7, j = blockIdx.x >> 3;
  int rowT = xcd * rpx + j / ncol;
  int cy = j - (j / ncol) * ncol;
  if (rowT >= nbr) return;
  gemm_direct<KT>(A, nullptr, W, bias, Cf, Cb, nrows, mout, act, rowT * 64, cy * 128);
}

// ---- merged conv + solo GEMM, one launch per layer.
// Segments 0..7: ROW-STRIP staging GEMMs — one block owns a 64-row x 512-col
// strip; A-frags loaded ONCE into regs and reused across the 4 column-tiles
// (cuts the 4x A re-gather seen as FETCH=2.1x logical in round-11 PMC).
// Segments 8..11: solo-edge GEMM (softmax==1): g/4*(hbf[src]@Wsum^T+bsum)
// scatter-added DIRECTLY INTO h (atomicAdd, ulp noise vs 2e-3 tolerance).
__global__ __launch_bounds__(256, 2) void conv_solo_all(
    const unsigned short* __restrict__ hbf,
    const int* __restrict__ srclist, const int* __restrict__ hotlist,
    const int* __restrict__ cnts,  // nsolo @ [r*16], nhot @ [64+r*16], nsrc @ [128+r*16]
    const unsigned short* __restrict__ Wl, const float* __restrict__ bl,
    const unsigned short* __restrict__ Wr, const float* __restrict__ br,
    unsigned short* __restrict__ xlb, unsigned short* __restrict__ xrh,
    const int* __restrict__ solosrc, const int* __restrict__ solodst,
    const unsigned short* __restrict__ wsum, const float* __restrict__ bsum,
    const float* __restrict__ gate, float* __restrict__ hacc) {
  __shared__ unsigned short Es[64][136];
  int t = threadIdx.x, lane = t & 63, w = t >> 6;
  int wm = w >> 1, wn = w & 1, q = lane >> 4, mr = lane & 15;
  for (int tid = blockIdx.x;; tid += gridDim.x) {
    int rem = tid, seg = 0, nrows = 0;
    for (; seg < 12; ++seg) {
      int n, tseg;
      if (seg < 8) {
        int r = seg >> 1;
        n = (seg & 1) ? cnts[64 + r * 16] : cnts[128 + r * 16];
        int cap = (seg & 1) ? CAPH : CAPS;
        if (n > cap) n = cap;
        tseg = (n + 63) >> 6;  // row strips (512 cols each)
      } else {
        n = cnts[(seg - 8) * 16];
        tseg = (n + 63) >> 6;
      }
      if (rem < tseg) { nrows = n; break; }
      rem -= tseg;
    }
    if (seg == 12) return;
    if (seg < 8) {
      int r = seg >> 1, sel = seg & 1;
      int rowBase = rem * 64;
      const int* list = (sel ? hotlist : srclist) + r * NN;
      const unsigned short* W = (sel ? Wr : Wl) + (size_t)r * 512 * 128;
      const float* bias = (sel ? br : bl) + (size_t)r * 512;
      unsigned short* C = sel ? (xrh + (size_t)r * CAPH * 512) : (xlb + (size_t)r * CAPS * 512);
      // A-frags once for the whole 512-wide strip
      const unsigned short* ap[2];
#pragma unroll
      for (int mt = 0; mt < 2; ++mt) {
        int gr = rowBase + wm * 32 + mt * 16 + mr;
        int cg = (gr < nrows) ? gr : 0;
        ap[mt] = hbf + (size_t)list[cg] * HID + q * 8;
      }
      bf16x8 a[2][4];
#pragma unroll
      for (int mt = 0; mt < 2; ++mt)
#pragma unroll
        for (int k = 0; k < 4; ++k) a[mt][k] = *(const bf16x8*)(ap[mt] + k * 32);
#pragma unroll
      for (int ct = 0; ct < 4; ++ct) {
        const unsigned short* wp[4];
#pragma unroll
        for (int nt = 0; nt < 4; ++nt)
          wp[nt] = W + (size_t)(ct * 128 + wn * 64 + nt * 16 + mr) * HID + q * 8;
        f32x4 acc[2][4] = {};
#pragma unroll
        for (int k = 0; k < 4; ++k) {
          bf16x8 bfr[4];
#pragma unroll
          for (int nt = 0; nt < 4; ++nt) bfr[nt] = *(const bf16x8*)(wp[nt] + k * 32);
#pragma unroll
          for (int mt = 0; mt < 2; ++mt)
#pragma unroll
            for (int nt = 0; nt < 4; ++nt)
              acc[mt][nt] = __builtin_amdgcn_mfma_f32_16x16x32_bf16(a[mt][k], bfr[nt], acc[mt][nt], 0, 0, 0);
        }
        float bv[4];
#pragma unroll
        for (int nt = 0; nt < 4; ++nt) bv[nt] = bias[ct * 128 + wn * 64 + nt * 16 + mr];
#pragma unroll
        for (int mt = 0; mt < 2; ++mt)
#pragma unroll
          for (int nt = 0; nt < 4; ++nt)
#pragma unroll
            for (int rr = 0; rr < 4; ++rr)
              Es[wm * 32 + mt * 16 + q * 4 + rr][wn * 64 + nt * 16 + mr] =
                  f2b(acc[mt][nt][rr] + bv[nt]);
        __syncthreads();
        int rl = t >> 2, co = (t & 3) * 32;
        int grow = rowBase + rl;
        if (grow < nrows) {
          unsigned short* dst = C + (size_t)grow * 512 + ct * 128 + co;
#pragma unroll
          for (int j = 0; j < 4; ++j)
            *(bf16x8*)(dst + j * 8) = *(const bf16x8*)&Es[rl][co + j * 8];
        }
        __syncthreads();  // Es WAR before next ct
      }
    } else {
      int r = seg - 8;
      int rowBase = rem * 64;
      const unsigned short* ap[2];
#pragma unroll
      for (int mt = 0; mt < 2; ++mt) {
        int gr = rowBase + wm * 32 + mt * 16 + mr;
        int idx = (gr < nrows) ? solosrc[r * NN + gr] : 0;
        ap[mt] = hbf + (size_t)idx * HID + q * 8;
      }
      const unsigned short* wp[4];
#pragma unroll
      for (int nt = 0; nt < 4; ++nt)
        wp[nt] = wsum + (size_t)r * 16384 + (size_t)(wn * 64 + nt * 16 + mr) * HID + q * 8;
      f32x4 acc[2][4] = {};
#pragma unroll
      for (int k = 0; k < 4; ++k) {
        bf16x8 af[2], bfr[4];
#pragma unroll
        for (int mt = 0; mt < 2; ++mt) af[mt] = *(const bf16x8*)(ap[mt] + k * 32);
#pragma unroll
        for (int nt = 0; nt < 4; ++nt) bfr[nt] = *(const bf16x8*)(wp[nt] + k * 32);
#pragma unroll
        for (int mt = 0; mt < 2; ++mt)
#pragma unroll
          for (int nt = 0; nt < 4; ++nt)
            acc[mt][nt] = __builtin_amdgcn_mfma_f32_16x16x32_bf16(af[mt], bfr[nt], acc[mt][nt], 0, 0, 0);
      }
      float g4 = gate[r] * 0.25f;
      float bv[4];
#pragma unroll
      for (int nt = 0; nt < 4; ++nt) bv[nt] = bsum[r * 128 + wn * 64 + nt * 16 + mr];
#pragma unroll
      for (int mt = 0; mt < 2; ++mt)
#pragma unroll
        for (int rr = 0; rr < 4; ++rr) {
          int row = rowBase + wm * 32 + mt * 16 + q * 4 + rr;
          if (row < nrows) {
            int dst = solodst[r * NN + row];
#pragma unroll
            for (int nt = 0; nt < 4; ++nt) {
              int col = wn * 64 + nt * 16 + mr;
              atomicAdd(&hacc[(size_t)dst * HID + col], g4 * (acc[mt][nt][rr] + bv[nt]));
            }
          }
        }
      __syncthreads();  // uniform with strip path's final barrier
    }
  }
}

// head-summed lin_l weights/bias per (layer,rel): Wsum[o][k] = sum_h Wl[h*128+o][k]
__global__ void wsum_build(const float* __restrict__ linlw, const float* __restrict__ linlb,
                           unsigned short* __restrict__ wsum, float* __restrict__ bsum) {
  int i = blockIdx.x * blockDim.x + threadIdx.x;
  if (i >= NL * NR * 128 * 128) return;
  int k = i & 127, o = (i >> 7) & 127, lr = i >> 14;
  float s = 0.f;
#pragma unroll
  for (int h = 0; h < NH; ++h) s += linlw[((size_t)lr * 512 + h * 128 + o) * 128 + k];
  wsum[i] = f2b(s);
  if (k == 0) {
    float b = 0.f;
#pragma unroll
    for (int h = 0; h < NH; ++h) b += linlb[(size_t)lr * 512 + h * 128 + o];
    bsum[lr * 128 + o] = b;
  }
}

// ---- layer tail: h already holds residual+messages (solo/edge added in place).
// LN1(h+cb) -> y (regs); f1=silu(y@W1^T+b1); f2=f1@W2^T+b2; h=LN2(y+f2); emits hbf.
__global__ __launch_bounds__(256, 2) void layer_tail(
    float* __restrict__ h, const float* __restrict__ cb,
    const float* __restrict__ n1w, const float* __restrict__ n1b,
    const unsigned short* __restrict__ W1, const float* __restrict__ b1,
    const unsigned short* __restrict__ W2, const float* __restrict__ b2,
    const float* __restrict__ n2w, const float* __restrict__ n2b,
    unsigned short* __restrict__ hbfout) {
  __shared__ __align__(16) char smem[64 * 136 * 2 + 64 * 264 * 2];
  unsigned short (*Y)[136] = (unsigned short (*)[136])smem;
  unsigned short (*F1)[264] = (unsigned short (*)[264])(smem + 64 * 136 * 2);
  float (*Ef)[132] = (float (*)[132])(smem + 64 * 136 * 2);
  int nbr = (NN + 63) >> 6;
  int rpx = (nbr + 7) >> 3;
  int xcd = blockIdx.x & 7, j = blockIdx.x >> 3;
  int rowT = xcd * rpx + j;
  if (rowT >= nbr) return;
  int rowBase = rowT * 64;

  int t = threadIdx.x;
  int lane = t & 63, w = t >> 6;
  int wm = w >> 1, wn = w & 1;
  int q = lane >> 4, mr = lane & 15;

  // ---- phase 0: LN1 over own 64 rows (wave-per-row); y kept in regs (static idx)
  float y0r[16], y1r[16];
  {
    float w0 = n1w[lane], w1 = n1w[64 + lane];
    float bb0 = n1b[lane], bb1 = n1b[64 + lane];
    float c0 = cb[lane], c1 = cb[64 + lane];
#pragma unroll
    for (int it = 0; it < 16; ++it) {
      int rr = it * 4 + w;
      int grow = rowBase + rr;
      if (grow < NN) {
        size_t base = (size_t)grow * HID;
        float x0 = h[base + lane] + c0;
        float x1 = h[base + 64 + lane] + c1;
        float s = x0 + x1;
#pragma unroll
        for (int o = 32; o > 0; o >>= 1) s += __shfl_xor(s, o, 64);
        float mean = s * (1.f / 128.f);
        float d0 = x0 - mean, d1 = x1 - mean;
        float v = d0 * d0 + d1 * d1;
#pragma unroll
        for (int o = 32; o > 0; o >>= 1) v += __shfl_xor(v, o, 64);
        float inv = 1.f / sqrtf(v * (1.f / 128.f) + 1e-5f);
        float y0 = d0 * inv * w0 + bb0;
        float y1 = d1 * inv * w1 + bb1;
        y0r[it] = y0;
        y1r[it] = y1;
        Y[rr][lane] = f2b(y0);
        Y[rr][64 + lane] = f2b(y1);
      } else {
        y0r[it] = 0.f;
        y1r[it] = 0.f;
        Y[rr][lane] = 0;
        Y[rr][64 + lane] = 0;
      }
    }
  }
  __syncthreads();

  // ---- phase A: f1 = silu(y @ W1^T + b1), A-frags from Y LDS
  bf16x8 a[2][4];
#pragma unroll
  for (int mt = 0; mt < 2; ++mt)
#pragma unroll
    for (int k = 0; k < 4; ++k)
      a[mt][k] = *(const bf16x8*)&Y[wm * 32 + mt * 16 + mr][k * 32 + q * 8];

#pragma unroll
  for (int ph = 0; ph < 2; ++ph) {
    const unsigned short* wp[4];
#pragma unroll
    for (int nt = 0; nt < 4; ++nt)
      wp[nt] = W1 + (size_t)(ph * 128 + wn * 64 + nt * 16 + mr) * HID + q * 8;
    f32x4 acc[2][4] = {};
#pragma unroll
    for (int k = 0; k < 4; ++k) {
      bf16x8 bfr[4];
#pragma unroll
      for (int nt = 0; nt < 4; ++nt) bfr[nt] = *(const bf16x8*)(wp[nt] + k * 32);
#pragma unroll
      for (int mt = 0; mt < 2; ++mt)
#pragma unroll
        for (int nt = 0; nt < 4; ++nt)
          acc[mt][nt] = __builtin_amdgcn_mfma_f32_16x16x32_bf16(a[mt][k], bfr[nt], acc[mt][nt], 0, 0, 0);
    }
    float bv[4];
#pragma unroll
    for (int nt = 0; nt < 4; ++nt) bv[nt] = b1[ph * 128 + wn * 64 + nt * 16 + mr];
#pragma unroll
    for (int mt = 0; mt < 2; ++mt)
#pragma unroll
      for (int nt = 0; nt < 4; ++nt)
#pragma unroll
        for (int r = 0; r < 4; ++r) {
          float v = acc[mt][nt][r] + bv[nt];
          v = v / (1.f + expf(-v));
          F1[wm * 32 + mt * 16 + q * 4 + r][ph * 128 + wn * 64 + nt * 16 + mr] = f2b(v);
        }
  }
  __syncthreads();

  // ---- phase B: f2 = f1 @ W2^T (K=256), A from LDS, W2 from L2
  const unsigned short* wp2[4];
#pragma unroll
  for (int nt = 0; nt < 4; ++nt)
    wp2[nt] = W2 + (size_t)(wn * 64 + nt * 16 + mr) * FFH + q * 8;
  f32x4 acc2[2][4] = {};
#pragma unroll
  for (int k = 0; k < 8; ++k) {
    bf16x8 af[2], bfr[4];
#pragma unroll
    for (int mt = 0; mt < 2; ++mt)
      af[mt] = *(const bf16x8*)&F1[wm * 32 + mt * 16 + mr][k * 32 + q * 8];
#pragma unroll
    for (int nt = 0; nt < 4; ++nt) bfr[nt] = *(const bf16x8*)(wp2[nt] + k * 32);
#pragma unroll
    for (int mt = 0; mt < 2; ++mt)
#pragma unroll
      for (int nt = 0; nt < 4; ++nt)
        acc2[mt][nt] = __builtin_amdgcn_mfma_f32_16x16x32_bf16(af[mt], bfr[nt], acc2[mt][nt], 0, 0, 0);
  }
  __syncthreads();  // all F1 reads done before overwriting as Ef

  // ---- phase C: stage f2+b2 in LDS (f32), then LN2(y + f2) -> h, hbf
  float bv2[4];
#pragma unroll
  for (int nt = 0; nt < 4; ++nt) bv2[nt] = b2[wn * 64 + nt * 16 + mr];
#pragma unroll
  for (int mt = 0; mt < 2; ++mt)
#pragma unroll
    for (int nt = 0; nt < 4; ++nt)
#pragma unroll
      for (int r = 0; r < 4; ++r)
        Ef[wm * 32 + mt * 16 + q * 4 + r][wn * 64 + nt * 16 + mr] = acc2[mt][nt][r] + bv2[nt];
  __syncthreads();

  float w0 = n2w[lane], w1 = n2w[64 + lane];
  float bb0 = n2b[lane], bb1 = n2b[64 + lane];
#pragma unroll
  for (int it = 0; it < 16; ++it) {
    int rr = it * 4 + w;
    int grow = rowBase + rr;
    if (grow >= NN) continue;
    size_t base = (size_t)grow * HID;
    float x0 = y0r[it] + Ef[rr][lane];   // y from regs: no HBM round-trip
    float x1 = y1r[it] + Ef[rr][64 + lane];
    float s = x0 + x1;
#pragma unroll
    for (int o = 32; o > 0; o >>= 1) s += __shfl_xor(s, o, 64);
    float mean = s * (1.f / 128.f);
    float d0 = x0 - mean, d1 = x1 - mean;
    float v = d0 * d0 + d1 * d1;
#pragma unroll
    for (int o = 32; o > 0; o >>= 1) v += __shfl_xor(v, o, 64);
    float inv = 1.f / sqrtf(v * (1.f / 128.f) + 1e-5f);
    float y0 = d0 * inv * w0 + bb0;
    float y1 = d1 * inv * w1 + bb1;
    h[base + lane] = y0;
    h[base + 64 + lane] = y1;
    hbfout[base + lane] = f2b(y0);
    hbfout[base + 64 + lane] = f2b(y1);
  }
}

__global__ void build_xin_bf(const float* __restrict__ x, const int* __restrict__ idtok,
                             const float* __restrict__ emb, unsigned short* __restrict__ xin) {
  int i = blockIdx.x * blockDim.x + threadIdx.x;
  if (i >= NN * 96) return;
  int n = i / 96, k = i - n * 96;
  float v = (k < FN) ? x[(size_t)n * FN + k] : emb[(size_t)idtok[n] * IDE + (k - FN)];
  xin[i] = f2b(v);
}

// ---- CSR by (rel, dst) ----
__global__ void hist_bin(const int* __restrict__ ei, const int* __restrict__ et,
                         int* __restrict__ bcnt) {
  int e = blockIdx.x * blockDim.x + threadIdx.x;
  if (e >= NE) return;
  atomicAdd(&bcnt[et[e] * NN + ei[NE + e]], 1);
}
__global__ __launch_bounds__(256) void scan1(const int* __restrict__ cnt,
                                             int* __restrict__ pos, int* __restrict__ bsum) {
  __shared__ int lds[256];
  int b = blockIdx.x, t = threadIdx.x;
  int base = b * 1024 + t * 4;
  int v[4];
#pragma unroll
  for (int j = 0; j < 4; ++j) v[j] = (base + j < NBIN) ? cnt[base + j] : 0;
  int tot = v[0] + v[1] + v[2] + v[3];
  lds[t] = tot;
  __syncthreads();
  for (int off = 1; off < 256; off <<= 1) {
    int x = (t >= off) ? lds[t - off] : 0;
    __syncthreads();
    lds[t] += x;
    __syncthreads();
  }
  if (t == 255) bsum[b] = lds[255];
  int run = lds[t] - tot;
#pragma unroll
  for (int j = 0; j < 4; ++j) {
    if (base + j < NBIN) pos[base + j] = run;
    run += v[j];
  }
}
__global__ __launch_bounds__(256) void scan2(int* __restrict__ bsum) {
  __shared__ int lds[256];
  int t = threadIdx.x;
  int v = (t < SCAN_BLK) ? bsum[t] : 0;
  lds[t] = v;
  __syncthreads();
  for (int off = 1; off < 256; off <<= 1) {
    int x = (t >= off) ? lds[t - off] : 0;
    __syncthreads();
    lds[t] += x;
    __syncthreads();
  }
  if (t < SCAN_BLK) bsum[t] = lds[t] - v;
}
__global__ void scan3(int* __restrict__ pos, const int* __restrict__ bsum,
                      const int* __restrict__ cnt) {
  int i = blockIdx.x * blockDim.x + threadIdx.x;
  if (i >= NBIN) return;
  pos[i] += bsum[i >> 10];
  if (i == NBIN - 1) pos[NBIN] = pos[i] + cnt[i];
}
__global__ void scatter_bin(const int* __restrict__ ei, const int* __restrict__ et,
                            const int* __restrict__ csroff, int* __restrict__ cur,
                            int* __restrict__ elist) {
  int e = blockIdx.x * blockDim.x + threadIdx.x;
  if (e >= NE) return;
  int bin = et[e] * NN + ei[NE + e];
  int p = atomicAdd(&cur[bin], 1);
  elist[csroff[bin] + p] = e;
}
// DETERMINISM: atomic scatter order varies call-to-call; sort each bin.
__global__ void sort_bins(const int* __restrict__ csroff, int* __restrict__ elist) {
  int b = blockIdx.x * blockDim.x + threadIdx.x;
  if (b >= NBIN) return;
  int s = csroff[b], e = csroff[b + 1];
  for (int i = s + 1; i < e; ++i) {
    int key = elist[i];
    int j = i - 1;
    while (j >= s && elist[j] > key) { elist[j + 1] = elist[j]; --j; }
    elist[j + 1] = key;
  }
}
// gather edge attrs into CSR order + flag hot-srcs inline (deg>=2 bins only)
__global__ void gather_edge(const int* __restrict__ ei, const int* __restrict__ et,
                            const int* __restrict__ elist, const int* __restrict__ csroff,
                            const float* __restrict__ eattr,
                            int* __restrict__ rsrc, float* __restrict__ eacsr,
                            int* __restrict__ srcflag) {
  int p = blockIdx.x * blockDim.x + threadIdx.x;
  if (p >= NE) return;
  int e = elist[p];
  int src = ei[e];
  rsrc[p] = src;
  const float4* s = (const float4*)(eattr + (size_t)e * NEA);
  float4* d = (float4*)(eacsr + (size_t)p * NEA);
#pragma unroll
  for (int j = 0; j < 4; ++j) d[j] = s[j];
  int bin = et[e] * NN + ei[NE + e];
  if (csroff[bin + 1] - csroff[bin] >= 2) srcflag[et[e] * NN + src] = 1;
}
// ORDERED hot-src compaction from scan positions (deterministic + sequential gather)
__global__ void build_src_o(const int* __restrict__ srcflag, const int* __restrict__ srcpos,
                            int* __restrict__ srclist, int* __restrict__ srcmap) {
  int b = blockIdx.x * blockDim.x + threadIdx.x;
  if (b >= NBIN) return;
  if (srcflag[b]) {
    int rel = b / NN;
    int pos = srcpos[b] - srcpos[rel * NN];
    srcmap[b] = pos;
    srclist[rel * NN + pos] = b - rel * NN;
  }
}
__global__ void fincnt(const int* __restrict__ srcpos, int* __restrict__ nsrc) {
  int r = threadIdx.x;
  if (r < NR) nsrc[r * 16] = srcpos[(r + 1) * NN] - srcpos[r * NN];
}
// rsrcx: hot-src row index per edge position (garbage for solo positions, unread)
__global__ void remap_rsrc(const int* __restrict__ csroff, const int* __restrict__ rsrc,
                           const int* __restrict__ srcmap, int* __restrict__ rsrcx) {
  int p = blockIdx.x * blockDim.x + threadIdx.x;
  if (p >= NE) return;
  int rel = (p >= csroff[NN]) + (p >= csroff[2 * NN]) + (p >= csroff[3 * NN]);
  rsrcx[p] = srcmap[rel * NN + rsrc[p]];
}
// per-rel solo (deg==1: ORIGINAL src id + dst) + hot (deg>=2) lists.
__global__ __launch_bounds__(256) void build_hot(
    const int* __restrict__ csroff, const int* __restrict__ rsrc,
    int* __restrict__ nsolo, int* __restrict__ nhot,
    int* __restrict__ solosrc, int* __restrict__ solodst, int* __restrict__ hotlist) {
  __shared__ int wsc[4][4], whc[4][4];
  __shared__ int sbase[4], hbase[4];
  int t = threadIdx.x, wave = t >> 6, lane = t & 63;
  int b = blockIdx.x * 256 + t;
  bool valid = b < NBIN;
  int cnt = 0, rel = 0, s = 0;
  if (valid) { s = csroff[b]; cnt = csroff[b + 1] - s; rel = b / NN; }
  bool solo = valid && cnt == 1;
  bool hot = valid && cnt >= 2;
#pragma unroll
  for (int rr = 0; rr < 4; ++rr) {
    unsigned long long ms = __ballot(solo && rel == rr);
    unsigned long long mh = __ballot(hot && rel == rr);
    if (lane == 0) { wsc[wave][rr] = __popcll(ms); whc[wave][rr] = __popcll(mh); }
  }
  __syncthreads();
  if (t < 4) {
    int ssum = wsc[0][t] + wsc[1][t] + wsc[2][t] + wsc[3][t];
    int hsum = whc[0][t] + whc[1][t] + whc[2][t] + whc[3][t];
    sbase[t] = ssum ? atomicAdd(&nsolo[t * 16], ssum) : 0;
    hbase[t] = hsum ? atomicAdd(&nhot[t * 16], hsum) : 0;
  }
  __syncthreads();
#pragma unroll
  for (int rr = 0; rr < 4; ++rr) {
    unsigned long long ms = __ballot(solo && rel == rr);
    if (solo && rel == rr) {
      int before = 0;
#pragma unroll
      for (int wv = 0; wv < 4; ++wv) if (wv < wave) before += wsc[wv][rr];
      int pos = sbase[rr] + before + __popcll(ms & ((1ull << lane) - 1ull));
      solosrc[rr * NN + pos] = rsrc[s];
      solodst[rr * NN + pos] = b - rr * NN;
    }
    unsigned long long mh = __ballot(hot && rel == rr);
    if (hot && rel == rr) {
      int before = 0;
#pragma unroll
      for (int wv = 0; wv < 4; ++wv) if (wv < wave) before += whc[wv][rr];
      int pos = hbase[rr] + before + __popcll(mh & ((1ull << lane) - 1ull));
      hotlist[rr * NN + pos] = b - rr * NN;
    }
  }
}

// all-layers gate softmax + gated conv bias in one launch (block = layer)
__global__ void gate_cb_all(const float* __restrict__ rg, const float* __restrict__ cbias,
                            float* __restrict__ gate, float* __restrict__ cb) {
  __shared__ float g[NR];
  int l = blockIdx.x, t = threadIdx.x;
  const float* rgl = rg + l * NR;
  if (t == 0) {
    float mx = rgl[0];
    for (int r = 1; r < NR; ++r) mx = fmaxf(mx, rgl[r]);
    float s = 0.f, tmp[NR];
    for (int r = 0; r < NR; ++r) { tmp[r] = expf(rgl[r] - mx); s += tmp[r]; }
    for (int r = 0; r < NR; ++r) { g[r] = tmp[r] / s; gate[l * NR + r] = g[r]; }
  }
  __syncthreads();
  float c = 0.f;
  for (int r = 0; r < NR; ++r) c += g[r] * cbias[(size_t)l * NR * HID + r * HID + t];
  cb[l * HID + t] = c;
}

// ---- merged hot edge pass: ALL 4 rels in one launch (rel = bid&3, grid-stride
// within rel so weight regs load once per block). Block/dst online softmax.
// Accumulates DIRECTLY INTO h via atomicAdd (<=4 rel contributions + solo adds
// per dst; fp32 reorder noise ~ulp vs 2e-3 tolerance).
__global__ __launch_bounds__(256) void edge_merged(
    const int* __restrict__ csroff, const int* __restrict__ rsrcx,
    const float* __restrict__ eacsr, const float* __restrict__ relembL,
    const float* __restrict__ wedgeL, const float* __restrict__ attwL,
    const unsigned short* __restrict__ xlb, const unsigned short* __restrict__ xrh,
    const int* __restrict__ hotlist, const int* __restrict__ nhot,
    float* __restrict__ hacc, const float* __restrict__ gate) {
  __shared__ float lds[4][128];
  int wave = threadIdx.x >> 6, lane = threadIdx.x & 63;
  int rel = blockIdx.x & 3;
  int b0 = blockIdx.x >> 2;
  int bstride = gridDim.x >> 2;
  float g4 = gate[rel] * 0.25f;
  int hh = wave;
  const float* wedgep = wedgeL + (size_t)rel * 512 * 24;
  const float* attwp = attwL + (size_t)rel * 512;
  const float* relembp = relembL + rel * RED;
  const unsigned short* xlbase = xlb + (size_t)rel * CAPS * 512;
  const unsigned short* xrbase = xrh + (size_t)rel * CAPH * 512;
  float wreg[2][24], areg[2];
#pragma unroll
  for (int j = 0; j < 2; ++j) {
    int col = hh * 128 + j * 64 + lane;
    const float* wp = wedgep + (size_t)col * 24;
#pragma unroll
    for (int k = 0; k < 24; ++k) wreg[j][k] = wp[k];
    areg[j] = attwp[col];
  }
  float evr0 = 0.f, evr1 = 0.f;
#pragma unroll
  for (int k = 0; k < 8; ++k) {
    float rk = relembp[k];
    evr0 += rk * wreg[0][NEA + k];
    evr1 += rk * wreg[1][NEA + k];
  }
  int nh = nhot[rel * 16];
  for (int wi = b0; wi < nh; wi += bstride) {
    int dst = hotlist[rel * NN + wi];
    int s = csroff[rel * NN + dst], e = csroff[rel * NN + dst + 1];
    {
      const unsigned short* xrp = xrbase + (size_t)wi * 512;
      float xr0 = b2f(xrp[hh * 128 + lane]);
      float xr1 = b2f(xrp[hh * 128 + 64 + lane]);
      float m = -3.4e38f, den = 0.f, acc0 = 0.f, acc1 = 0.f;
      for (int p = s; p < e; ++p) {
        int src = rsrcx[p];
        const float* eap = eacsr + (size_t)p * NEA;
        float eev0 = evr0, eev1 = evr1;
#pragma unroll
        for (int k = 0; k < NEA; ++k) {
          float er = eap[k];
          eev0 += er * wreg[0][k];
          eev1 += er * wreg[1][k];
        }
        float xl0 = b2f(xlbase[(size_t)src * 512 + hh * 128 + lane]);
        float xl1 = b2f(xlbase[(size_t)src * 512 + hh * 128 + 64 + lane]);
        float s0 = xl0 + xr0 + eev0; s0 = (s0 > 0.f) ? s0 : 0.2f * s0;
        float s1 = xl1 + xr1 + eev1; s1 = (s1 > 0.f) ? s1 : 0.2f * s1;
        float lg = s0 * areg[0] + s1 * areg[1];
#pragma unroll
        for (int o = 32; o > 0; o >>= 1) lg += __shfl_xor(lg, o, 64);
        float mn = fmaxf(m, lg);
        float sc = expf(m - mn);
        float ex = expf(lg - mn);
        den = den * sc + ex;
        acc0 = acc0 * sc + ex * xl0;
        acc1 = acc1 * sc + ex * xl1;
        m = mn;
      }
      float wgt = g4 / den;
      lds[wave][lane] = acc0 * wgt;
      lds[wave][64 + lane] = acc1 * wgt;
    }
    __syncthreads();
    if (wave < 2) {
      int d = wave * 64 + lane;
      float v = lds[0][d] + lds[1][d] + lds[2][d] + lds[3][d];
      atomicAdd(&hacc[(size_t)dst * HID + d], v);
    }
    __syncthreads();
  }
}

// ---- readout: deterministic ----
__global__ void group_bounds(const int* __restrict__ batch, int* __restrict__ gstart) {
  int g = threadIdx.x + blockIdx.x * blockDim.x;
  if (g > NG) return;
  int lo = 0, hi = NN;
  while (lo < hi) {
    int mid = (lo + hi) >> 1;
    if (batch[mid] < g) lo = mid + 1; else hi = mid;
  }
  gstart[g] = lo;
}
__global__ __launch_bounds__(128) void readout_part2(
    const float* __restrict__ h, const int* __restrict__ gstart,
    float* __restrict__ psum, float* __restrict__ pmax) {
  int g = blockIdx.x, s = blockIdx.y, t = threadIdx.x;
  int r0 = gstart[g], r1 = gstart[g + 1];
  float acc = 0.f, mx = -3.4e38f;
  for (int row = r0 + s; row < r1; row += 8) {
    float v = h[(size_t)row * HID + t];
    acc += v;
    mx = fmaxf(mx, v);
  }
  psum[((size_t)g * 8 + s) * HID + t] = acc;
  pmax[((size_t)g * 8 + s) * HID + t] = mx;
}
__global__ __launch_bounds__(256) void readout_final(
    const int* __restrict__ gstart, const float* __restrict__ psum,
    const float* __restrict__ pmax, const float* __restrict__ w,
    const float* __restrict__ b, float* __restrict__ g) {
  int bg = blockIdx.x, t = threadIdx.x;
  __shared__ float red[256];
  float c = fmaxf((float)(gstart[bg + 1] - gstart[bg]), 1.f);
  float x;
  if (t < HID) {
    float ssum = 0.f;
    for (int s = 0; s < 8; ++s) ssum += psum[((size_t)bg * 8 + s) * HID + t];
    x = ssum / c;
  } else {
    float mx = -3.4e38f;
    for (int s = 0; s < 8; ++s) mx = fmaxf(mx, pmax[((size_t)bg * 8 + s) * HID + (t - HID)]);
    x = mx;
  }
  red[t] = x;
  __syncthreads();
  for (int s = 128; s > 0; s >>= 1) {
    if (t < s) red[t] += red[t + s];
    __syncthreads();
  }
  float mean = red[0] * (1.f / 256.f);
  __syncthreads();
  float d = x - mean;
  red[t] = d * d;
  __syncthreads();
  for (int s = 128; s > 0; s >>= 1) {
    if (t < s) red[t] += red[t + s];
    __syncthreads();
  }
  float inv = 1.f / sqrtf(red[0] * (1.f / 256.f) + 1e-5f);
  g[(size_t)bg * 256 + t] = d * inv * w[t] + b[t];
}

__device__ __forceinline__ void bspline8(float x, const float* __restrict__ t,
                                         float* __restrict__ out) {
  float bs[11];
#pragma unroll
  for (int j = 0; j < 11; ++j) bs[j] = (x >= t[j] && x < t[j + 1]) ? 1.f : 0.f;
#pragma unroll
  for (int k = 1; k <= 3; ++k) {
    for (int j = 0; j < 11 - k; ++j) {
      bs[j] = (x - t[j]) / (t[j + k] - t[j]) * bs[j] +
              (t[j + k + 1] - x) / (t[j + k + 1] - t[j + 1]) * bs[j + 1];
    }
  }
#pragma unroll
  for (int j = 0; j < 8; ++j) out[j] = bs[j];
}

// ---- KAN1, K-chunked into fixed partial slots (deterministic) ----
__global__ __launch_bounds__(128) void kan1_part(
    const float* __restrict__ g, const float* __restrict__ bw,
    const float* __restrict__ sw, const float* __restrict__ sc,
    const float* __restrict__ grid, float* __restrict__ zpart) {
  int bg = blockIdx.x, ch = blockIdx.y, t = threadIdx.x;
  int base = ch * 32;
  __shared__ float B[32][8];
  __shared__ float sg[32];
  if (t < 32) {
    float x = g[(size_t)bg * 256 + base + t];
    sg[t] = x / (1.f + expf(-x));
    bspline8(x, grid + (size_t)(base + t) * 12, B[t]);
  }
  __syncthreads();
  float acc = 0.f;
  for (int i = 0; i < 32; ++i) {
    int col = base + i;
    acc += sg[i] * bw[(size_t)t * 256 + col];
    const float* swp = sw + ((size_t)t * 256 + col) * 8;
    float sp = 0.f;
#pragma unroll
    for (int k = 0; k < 8; ++k) sp += B[i][k] * swp[k];
    acc += sp * sc[(size_t)t * 256 + col];
  }
  zpart[((size_t)ch * NG + bg) * KH + t] = acc;
}

__global__ __launch_bounds__(128) void kan2(
    const float* __restrict__ zpart, const float* __restrict__ bw,
    const float* __restrict__ sw, const float* __restrict__ sc,
    const float* __restrict__ grid, float* __restrict__ out) {
  int bg = blockIdx.x, t = threadIdx.x;
  __shared__ float B[128][8];
  __shared__ float sz[128];
  float x = 0.f;
  for (int ch = 0; ch < 8; ++ch) x += zpart[((size_t)ch * NG + bg) * KH + t];
  sz[t] = x / (1.f + expf(-x));
  bspline8(x, grid + (size_t)t * 12, B[t]);
  __syncthreads();
  if (t < NC) {
    float acc = 0.f;
    for (int i = 0; i < 128; ++i) {
      acc += sz[i] * bw[(size_t)t * 128 + i];
      const float* swp = sw + ((size_t)t * 128 + i) * 8;
      float sp = 0.f;
#pragma unroll
      for (int k = 0; k < 8; ++k) sp += B[i][k] * swp[k];
      acc += sp * sc[(size_t)t * 128 + i];
    }
    out[(size_t)bg * NC + t] = acc;
  }
}

extern "C" void kernel_launch(void* const* d_in, const int* in_sizes, int n_in,
                              void* d_out, int out_size, void* d_ws, size_t ws_size,
                              hipStream_t stream) {
  const float* x       = (const float*)d_in[0];
  const float* eattr   = (const float*)d_in[1];
  const int*   idtok   = (const int*)d_in[2];
  const int*   ei      = (const int*)d_in[3];
  const int*   etype   = (const int*)d_in[4];
  const int*   batch   = (const int*)d_in[5];
  const float* idemb   = (const float*)d_in[6];
  const float* inw     = (const float*)d_in[7];
  const float* inb     = (const float*)d_in[8];
  const float* relemb  = (const float*)d_in[9];
  const float* linlw   = (const float*)d_in[10];
  const float* linlb   = (const float*)d_in[11];
  const float* linrw   = (const float*)d_in[12];
  const float* linrb   = (const float*)d_in[13];
  const float* linew   = (const float*)d_in[14];
  const float* attw    = (const float*)d_in[15];
  const float* convb   = (const float*)d_in[16];
  const float* relgate = (const float*)d_in[17];
  const float* n1w     = (const float*)d_in[18];
  const float* n1b     = (const float*)d_in[19];
  const float* n2w     = (const float*)d_in[20];
  const float* n2b     = (const float*)d_in[21];
  const float* f1w     = (const float*)d_in[22];
  const float* f1bias  = (const float*)d_in[23];
  const float* f2w     = (const float*)d_in[24];
  const float* f2bias  = (const float*)d_in[25];
  const float* rnw     = (const float*)d_in[26];
  const float* rnb     = (const float*)d_in[27];
  const float* bw1     = (const float*)d_in[28];
  const float* sw1     = (const float*)d_in[29];
  const float* sc1     = (const float*)d_in[30];
  const float* grid1   = (const float*)d_in[31];
  const float* bw2     = (const float*)d_in[32];
  const float* sw2     = (const float*)d_in[33];
  const float* sc2     = (const float*)d_in[34];
  const float* grid2   = (const float*)d_in[35];
  float* out = (float*)d_out;
  (void)in_sizes; (void)n_in; (void)out_size; (void)ws_size;

  char* p = (char*)d_ws;
  auto alloc = [&](size_t bytes) { void* q = (void*)p; p += (bytes + 255) & ~(size_t)255; return q; };
  float* h    = (float*)alloc((size_t)NN * HID * 4);
  unsigned short* hbf = (unsigned short*)alloc((size_t)NN * HID * 2);
  unsigned short* xlb = (unsigned short*)alloc((size_t)NR * CAPS * 512 * 2);  // 134.2MB
  unsigned short* xrh = (unsigned short*)alloc((size_t)NR * CAPH * 512 * 2);  // 37.7MB
  int* elist = (int*)alloc((size_t)NE * 4);
  int* rsrc  = (int*)alloc((size_t)NE * 4);
  int* rsrcx = (int*)alloc((size_t)NE * 4);
  float* eacsr = (float*)alloc((size_t)NE * NEA * 4);
  int* bcnt  = (int*)alloc((size_t)NBIN * 8 + 8);
  int* cur   = bcnt + NBIN;
  int* csroff = (int*)alloc((size_t)(NBIN + 1) * 4);
  int* srcpos = (int*)alloc((size_t)(NBIN + 1) * 4);
  int* bsum  = (int*)alloc((size_t)SCAN_BLK * 4);
  int* hotlist = (int*)alloc((size_t)NR * NN * 4);
  int* solosrc = (int*)alloc((size_t)NR * NN * 4);
  int* solodst = (int*)alloc((size_t)NR * NN * 4);
  int* srclist = (int*)alloc((size_t)NR * NN * 4);
  int* srcflag = (int*)alloc((size_t)NBIN * 4);
  int* srcmap  = (int*)alloc((size_t)NBIN * 4);
  int* cnts    = (int*)alloc(1024);
  int* nsolo   = cnts;
  int* nhot    = cnts + 64;
  int* nsrc    = cnts + 128;
  unsigned short* linlwb = (unsigned short*)alloc((size_t)NL * NR * 512 * 128 * 2);
  unsigned short* linrwb = (unsigned short*)alloc((size_t)NL * NR * 512 * 128 * 2);
  unsigned short* f1wb   = (unsigned short*)alloc((size_t)NL * 256 * 128 * 2);
  unsigned short* f2wb   = (unsigned short*)alloc((size_t)NL * 128 * 256 * 2);
  unsigned short* inwb   = (unsigned short*)alloc((size_t)128 * 96 * 2);
  unsigned short* wsumb  = (unsigned short*)alloc((size_t)NL * NR * 128 * 128 * 2);
  float* bsumf = (float*)alloc((size_t)NL * NR * 128 * 4);
  float* gate = (float*)alloc(NL * NR * 4);
  float* cb   = (float*)alloc(NL * HID * 4);
  int* gstart = (int*)alloc((size_t)(NG + 1) * 4);
  float* psum = (float*)alloc((size_t)NG * 8 * HID * 4);
  float* pmax = (float*)alloc((size_t)NG * 8 * HID * 4);
  float* zpart = (float*)alloc((size_t)8 * NG * KH * 4);
  float* g = (float*)alloc((size_t)NG * 256 * 4);
  unsigned short* xinbf = xlb;  // aliased: in-proj input staged before layer loop

  const int NB64 = (NN + 63) / 64;
  const int RPX = (NB64 + 7) / 8;

  {
    int n;
    n = NL * NR * 512 * 128 / 4;
    cvt_bf16<<<(n + 255) / 256, 256, 0, stream>>>(linlw, linlwb, n);
    cvt_bf16<<<(n + 255) / 256, 256, 0, stream>>>(linrw, linrwb, n);
    n = NL * 256 * 128 / 4;
    cvt_bf16<<<(n + 255) / 256, 256, 0, stream>>>(f1w, f1wb, n);
    cvt_bf16<<<(n + 255) / 256, 256, 0, stream>>>(f2w, f2wb, n);
    n = 128 * 96 / 4;
    cvt_bf16<<<(n + 255) / 256, 256, 0, stream>>>(inw, inwb, n);
  }
  wsum_build<<<(NL * NR * 128 * 128 + 255) / 256, 256, 0, stream>>>(linlw, linlb, wsumb, bsumf);

  hipMemsetAsync(bcnt, 0, (size_t)NBIN * 8 + 8, stream);
  hipMemsetAsync(srcflag, 0, (size_t)NBIN * 4, stream);
  hipMemsetAsync(cnts, 0, 1024, stream);
  hist_bin<<<(NE + 255) / 256, 256, 0, stream>>>(ei, etype, bcnt);
  scan1<<<SCAN_BLK, 256, 0, stream>>>(bcnt, csroff, bsum);
  scan2<<<1, 256, 0, stream>>>(bsum);
  scan3<<<(NBIN + 255) / 256, 256, 0, stream>>>(csroff, bsum, bcnt);
  scatter_bin<<<(NE + 255) / 256, 256, 0, stream>>>(ei, etype, csroff, cur, elist);
  sort_bins<<<(NBIN + 255) / 256, 256, 0, stream>>>(csroff, elist);
  gather_edge<<<(NE + 255) / 256, 256, 0, stream>>>(ei, etype, elist, csroff, eattr,
                                                    rsrc, eacsr, srcflag);
  scan1<<<SCAN_BLK, 256, 0, stream>>>(srcflag, srcpos, bsum);
  scan2<<<1, 256, 0, stream>>>(bsum);
  scan3<<<(NBIN + 255) / 256, 256, 0, stream>>>(srcpos, bsum, srcflag);
  build_src_o<<<(NBIN + 255) / 256, 256, 0, stream>>>(srcflag, srcpos, srclist, srcmap);
  fincnt<<<1, 64, 0, stream>>>(srcpos, nsrc);
  remap_rsrc<<<(NE + 255) / 256, 256, 0, stream>>>(csroff, rsrc, srcmap, rsrcx);
  build_hot<<<(NBIN + 255) / 256, 256, 0, stream>>>(csroff, rsrc, nsolo, nhot,
                                                    solosrc, solodst, hotlist);
  gate_cb_all<<<NL, 128, 0, stream>>>(relgate, convb, gate, cb);

  build_xin_bf<<<(NN * 96 + 255) / 256, 256, 0, stream>>>(x, idtok, idemb, xinbf);
  gemm_bf16_t<96><<<8 * RPX, 256, 0, stream>>>(xinbf, inwb, inb, h, hbf, NN, 128, 1, 1);

  for (int l = 0; l < NL; ++l) {
    conv_solo_all<<<4096, 256, 0, stream>>>(
        hbf, srclist, hotlist, cnts,
        linlwb + (size_t)l * NR * 512 * 128, linlb + (size_t)l * NR * 512,
        linrwb + (size_t)l * NR * 512 * 128, linrb + (size_t)l * NR * 512,
        xlb, xrh,
        solosrc, solodst,
        wsumb + (size_t)l * NR * 16384, bsumf + (size_t)l * NR * 128,
        gate + l * NR, h);
    edge_merged<<<4096, 256, 0, stream>>>(
        csroff, rsrcx, eacsr,
        relemb + (size_t)l * NR * RED,
        linew + (size_t)l * NR * 512 * 24,
        attw + (size_t)l * NR * 512,
        xlb, xrh, hotlist, nhot, h, gate + l * NR);
    layer_tail<<<8 * RPX, 256, 0, stream>>>(
        h, cb + l * HID, n1w + l * HID, n1b + l * HID,
        f1wb + (size_t)l * 256 * 128, f1bias + (size_t)l * 256,
        f2wb + (size_t)l * 128 * 256, f2bias + (size_t)l * 128,
        n2w + l * HID, n2b + l * HID, hbf);
  }

  group_bounds<<<1, 128, 0, stream>>>(batch, gstart);
  readout_part2<<<dim3(NG, 8), 128, 0, stream>>>(h, gstart, psum, pmax);
  readout_final<<<NG, 256, 0, stream>>>(gstart, psum, pmax, rnw, rnb, g);
  kan1_part<<<dim3(NG, 8), 128, 0, stream>>>(g, bw1, sw1, sc1, grid1, zpart);
  kan2<<<NG, 128, 0, stream>>>(zpart, bw2, sw2, sc2, grid2, out);
}